// Round 1
// baseline (1260.949 us; speedup 1.0000x reference)
//
#include <hip/hip_runtime.h>

#define BB 8
#define NN 2048
#define KK 16

__device__ __forceinline__ float4 f4max(float4 a, float4 b) {
  return make_float4(fmaxf(a.x, b.x), fmaxf(a.y, b.y), fmaxf(a.z, b.z), fmaxf(a.w, b.w));
}

// ---------------------------------------------------------------- kNN top-16
__global__ __launch_bounds__(64) void knn_kernel(const float* __restrict__ pts,
                                                 int* __restrict__ knn_idx) {
  __shared__ float px[NN], py[NN], pz[NN], sq[NN];
  const int b = blockIdx.x >> 5;    // 32 blocks per batch
  const int tile = blockIdx.x & 31;
  const int tid = threadIdx.x;
  for (int i = tid; i < NN; i += 64) {
    float x = pts[(size_t)(b * NN + i) * 3 + 0];
    float y = pts[(size_t)(b * NN + i) * 3 + 1];
    float z = pts[(size_t)(b * NN + i) * 3 + 2];
    px[i] = x; py[i] = y; pz[i] = z;
    sq[i] = x * x + y * y + z * z;
  }
  __syncthreads();
  const int n = tile * 64 + tid;
  const float xn = px[n], yn = py[n], zn = pz[n], sqn = sq[n];
  float vals[KK]; int ids[KK];
#pragma unroll
  for (int j = 0; j < KK; ++j) { vals[j] = -3.0e38f; ids[j] = 0; }
  for (int m = 0; m < NN; ++m) {
    float v = 2.0f * (xn * px[m] + yn * py[m] + zn * pz[m]) - sqn - sq[m];
    if (v > vals[KK - 1]) {
      vals[KK - 1] = v; ids[KK - 1] = m;
#pragma unroll
      for (int j = KK - 1; j > 0; --j) {
        if (vals[j] > vals[j - 1]) {
          float tv = vals[j]; vals[j] = vals[j - 1]; vals[j - 1] = tv;
          int ti = ids[j]; ids[j] = ids[j - 1]; ids[j - 1] = ti;
        }
      }
    }
  }
#pragma unroll
  for (int j = 0; j < KK; ++j) knn_idx[(size_t)(b * NN + n) * KK + j] = ids[j];
}

// ------------------------------------------- features (pts + cov) + mlp1 x3
__global__ __launch_bounds__(64) void mlp1_kernel(
    const float* __restrict__ pts, const int* __restrict__ knn_idx,
    const float* __restrict__ w1a, const float* __restrict__ b1a,
    const float* __restrict__ w1b, const float* __restrict__ b1b,
    const float* __restrict__ w1c, const float* __restrict__ b1c,
    float* __restrict__ f1) {
  const int bn = blockIdx.x * 64 + threadIdx.x;  // 0..16383
  const int b = bn >> 11;
  const int n0 = knn_idx[(size_t)bn * KK + 0];
  const int n1 = knn_idx[(size_t)bn * KK + 1];
  const float* p  = &pts[(size_t)bn * 3];
  const float* p0 = &pts[((size_t)(b << 11) + n0) * 3];
  const float* p1 = &pts[((size_t)(b << 11) + n1) * 3];
  float in[12];
  in[0] = p[0]; in[1] = p[1]; in[2] = p[2];
  float a0 = p0[0], a1 = p0[1], a2 = p0[2];
  float c0 = p1[0], c1 = p1[1], c2 = p1[2];
  in[3] = a0 * c0; in[4]  = a0 * c1; in[5]  = a0 * c2;
  in[6] = a1 * c0; in[7]  = a1 * c1; in[8]  = a1 * c2;
  in[9] = a2 * c0; in[10] = a2 * c1; in[11] = a2 * c2;

  float h1[64], h2[64];
#pragma unroll
  for (int o = 0; o < 64; ++o) {
    float a = b1a[o];
#pragma unroll
    for (int c = 0; c < 12; ++c) a += w1a[o * 12 + c] * in[c];
    h1[o] = fmaxf(a, 0.f);
  }
#pragma unroll
  for (int o = 0; o < 64; ++o) {
    float a = b1b[o];
#pragma unroll
    for (int c = 0; c < 64; ++c) a += w1b[o * 64 + c] * h1[c];
    h2[o] = fmaxf(a, 0.f);
  }
#pragma unroll
  for (int o = 0; o < 64; ++o) {
    float a = b1c[o];
#pragma unroll
    for (int c = 0; c < 64; ++c) a += w1c[o * 64 + c] * h2[c];
    f1[(size_t)bn * 64 + o] = fmaxf(a, 0.f);
  }
}

// ---------------------------------------- maxpool(16) + lin1 + conv1 + relu
__global__ __launch_bounds__(64) void gconv1_kernel(
    const float* __restrict__ f1, const int* __restrict__ knn_idx,
    const float* __restrict__ lin1_w, const float* __restrict__ lin1_b,
    const float* __restrict__ conv1_w, const float* __restrict__ conv1_b,
    float* __restrict__ f2) {
  const int bn = blockIdx.x * 64 + threadIdx.x;
  const int b = bn >> 11;
  float4 m[16];
#pragma unroll
  for (int q = 0; q < 16; ++q) m[q] = make_float4(-3e38f, -3e38f, -3e38f, -3e38f);
  for (int j = 0; j < KK; ++j) {
    const int nb = knn_idx[(size_t)bn * KK + j];
    const float4* v = (const float4*)&f1[((size_t)(b << 11) + nb) * 64];
#pragma unroll
    for (int q = 0; q < 16; ++q) m[q] = f4max(m[q], v[q]);
  }
  float y[64];
#pragma unroll
  for (int o = 0; o < 64; ++o) {
    float a = lin1_b[o];
#pragma unroll
    for (int q = 0; q < 16; ++q) {
      a += lin1_w[o * 64 + q * 4 + 0] * m[q].x;
      a += lin1_w[o * 64 + q * 4 + 1] * m[q].y;
      a += lin1_w[o * 64 + q * 4 + 2] * m[q].z;
      a += lin1_w[o * 64 + q * 4 + 3] * m[q].w;
    }
    y[o] = a;  // no relu on lin1
  }
#pragma unroll
  for (int o = 0; o < 128; ++o) {
    float a = conv1_b[o];
#pragma unroll
    for (int c = 0; c < 64; ++c) a += conv1_w[o * 64 + c] * y[c];
    f2[(size_t)bn * 128 + o] = fmaxf(a, 0.f);
  }
}

// ------------------------------------------------- maxpool(16) + lin2
__global__ __launch_bounds__(64) void gconv2_kernel(
    const float* __restrict__ f2, const int* __restrict__ knn_idx,
    const float* __restrict__ lin2_w, const float* __restrict__ lin2_b,
    float* __restrict__ f3) {
  const int bn = blockIdx.x * 64 + threadIdx.x;
  const int b = bn >> 11;
  float4 m[32];
#pragma unroll
  for (int q = 0; q < 32; ++q) m[q] = make_float4(-3e38f, -3e38f, -3e38f, -3e38f);
  for (int j = 0; j < KK; ++j) {
    const int nb = knn_idx[(size_t)bn * KK + j];
    const float4* v = (const float4*)&f2[((size_t)(b << 11) + nb) * 128];
#pragma unroll
    for (int q = 0; q < 32; ++q) m[q] = f4max(m[q], v[q]);
  }
#pragma unroll
  for (int og = 0; og < 4; ++og) {
#pragma unroll
    for (int oi = 0; oi < 32; ++oi) {
      const int o = og * 32 + oi;
      float a = lin2_b[o];
#pragma unroll
      for (int q = 0; q < 32; ++q) {
        a += lin2_w[o * 128 + q * 4 + 0] * m[q].x;
        a += lin2_w[o * 128 + q * 4 + 1] * m[q].y;
        a += lin2_w[o * 128 + q * 4 + 2] * m[q].z;
        a += lin2_w[o * 128 + q * 4 + 3] * m[q].w;
      }
      f3[(size_t)bn * 128 + o] = a;  // no relu on lin2
    }
  }
}

// ------------------------------- conv2 (128->1024) fused with global max(n)
__global__ __launch_bounds__(256) void conv2max_kernel(
    const float* __restrict__ f3, const float* __restrict__ conv2_w,
    const float* __restrict__ conv2_b, float* __restrict__ pmax) {
  const int bi = blockIdx.x;        // 512 = 8 b * 8 otile * 8 ngroup
  const int b  = bi >> 6;
  const int ot = (bi >> 3) & 7;     // 8 o-tiles of 128
  const int ng = bi & 7;            // 8 n-groups of 256
  const int tid = threadIdx.x;
  const int n = ng * 256 + tid;

  float x[128];
  const float4* xp = (const float4*)&f3[((size_t)b * NN + n) * 128];
#pragma unroll
  for (int q = 0; q < 32; ++q) {
    float4 v = xp[q];
    x[q * 4 + 0] = v.x; x[q * 4 + 1] = v.y; x[q * 4 + 2] = v.z; x[q * 4 + 3] = v.w;
  }

  __shared__ float red[16][4][8];
  const int wid = tid >> 6, lane = tid & 63;
  for (int chunk = 0; chunk < 16; ++chunk) {
    float v[8];
#pragma unroll
    for (int i = 0; i < 8; ++i) {
      const int oo = ot * 128 + chunk * 8 + i;
      const float* w = &conv2_w[(size_t)oo * 128];
      float a = conv2_b[oo];
#pragma unroll
      for (int c = 0; c < 128; ++c) a += w[c] * x[c];
      v[i] = a;
    }
#pragma unroll
    for (int i = 0; i < 8; ++i) {
#pragma unroll
      for (int s = 32; s >= 1; s >>= 1) v[i] = fmaxf(v[i], __shfl_xor(v[i], s, 64));
    }
    if (lane == 0) {
#pragma unroll
      for (int i = 0; i < 8; ++i) red[chunk][wid][i] = v[i];
    }
  }
  __syncthreads();
  if (tid < 128) {
    const int chunk = tid >> 3, i = tid & 7;
    float a = fmaxf(fmaxf(red[chunk][0][i], red[chunk][1][i]),
                    fmaxf(red[chunk][2][i], red[chunk][3][i]));
    const int oo = ot * 128 + chunk * 8 + i;
    pmax[((size_t)b * 1024 + oo) * 8 + ng] = a;
  }
}

// ----------------------------------------- reduce partials + mlp2 head
__global__ __launch_bounds__(256) void head_kernel(
    const float* __restrict__ pmax,
    const float* __restrict__ w2a, const float* __restrict__ b2a,
    const float* __restrict__ w2b, const float* __restrict__ b2b,
    float* __restrict__ out) {
  const int b = blockIdx.x;
  const int tid = threadIdx.x;
  __shared__ __align__(16) float g[1024];
  __shared__ __align__(16) float h[512];
  for (int o = tid; o < 1024; o += 256) {
    const float* p = &pmax[((size_t)b * 1024 + o) * 8];
    float a = p[0];
#pragma unroll
    for (int gi = 1; gi < 8; ++gi) a = fmaxf(a, p[gi]);
    g[o] = a;
  }
  __syncthreads();
#pragma unroll
  for (int r = 0; r < 2; ++r) {
    const int k = r * 256 + tid;
    float a = b2a[k];
    const float4* wr = (const float4*)&w2a[(size_t)k * 1024];
    const float4* gv = (const float4*)g;
    for (int c = 0; c < 256; ++c) {
      float4 w = wr[c], xx = gv[c];
      a += w.x * xx.x + w.y * xx.y + w.z * xx.z + w.w * xx.w;
    }
    h[k] = fmaxf(a, 0.f);
  }
  __syncthreads();
#pragma unroll
  for (int r = 0; r < 2; ++r) {
    const int j = r * 256 + tid;
    float a = b2b[j];
    const float4* wr = (const float4*)&w2b[(size_t)j * 512];
    const float4* hv = (const float4*)h;
    for (int c = 0; c < 128; ++c) {
      float4 w = wr[c], xx = hv[c];
      a += w.x * xx.x + w.y * xx.y + w.z * xx.z + w.w * xx.w;
    }
    out[(size_t)b * 512 + j] = a;
  }
}

extern "C" void kernel_launch(void* const* d_in, const int* in_sizes, int n_in,
                              void* d_out, int out_size, void* d_ws, size_t ws_size,
                              hipStream_t stream) {
  const float* pts     = (const float*)d_in[0];
  const float* w1a     = (const float*)d_in[1];
  const float* b1a     = (const float*)d_in[2];
  const float* w1b     = (const float*)d_in[3];
  const float* b1b     = (const float*)d_in[4];
  const float* w1c     = (const float*)d_in[5];
  const float* b1c     = (const float*)d_in[6];
  const float* lin1_w  = (const float*)d_in[7];
  const float* lin1_b  = (const float*)d_in[8];
  const float* conv1_w = (const float*)d_in[9];
  const float* conv1_b = (const float*)d_in[10];
  const float* lin2_w  = (const float*)d_in[11];
  const float* lin2_b  = (const float*)d_in[12];
  const float* conv2_w = (const float*)d_in[13];
  const float* conv2_b = (const float*)d_in[14];
  const float* w2a     = (const float*)d_in[15];
  const float* b2a     = (const float*)d_in[16];
  const float* w2b     = (const float*)d_in[17];
  const float* b2b     = (const float*)d_in[18];

  char* ws = (char*)d_ws;
  int*   knn_idx = (int*)ws;                       // 1 MB
  float* f1 = (float*)(ws + (1u << 20));           // 4 MB   (region A)
  float* f2 = (float*)(ws + (9u << 20));           // 8 MB   (region B)
  float* f3 = (float*)(ws + (1u << 20));           // 8 MB   (region A reuse; f1 dead)
  float* pm = (float*)(ws + (17u << 20));          // 256 KB

  knn_kernel   <<<256, 64, 0, stream>>>(pts, knn_idx);
  mlp1_kernel  <<<256, 64, 0, stream>>>(pts, knn_idx, w1a, b1a, w1b, b1b, w1c, b1c, f1);
  gconv1_kernel<<<256, 64, 0, stream>>>(f1, knn_idx, lin1_w, lin1_b, conv1_w, conv1_b, f2);
  gconv2_kernel<<<256, 64, 0, stream>>>(f2, knn_idx, lin2_w, lin2_b, f3);
  conv2max_kernel<<<512, 256, 0, stream>>>(f3, conv2_w, conv2_b, pm);
  head_kernel  <<<8, 256, 0, stream>>>(pm, w2a, b2a, w2b, b2b, (float*)d_out);
}

// Round 2
// 791.606 us; speedup vs baseline: 1.5929x; 1.5929x over previous
//
#include <hip/hip_runtime.h>

#define BB 8
#define NN 2048
#define KK 16

__device__ __forceinline__ float4 f4max(float4 a, float4 b) {
  return make_float4(fmaxf(a.x, b.x), fmaxf(a.y, b.y), fmaxf(a.z, b.z), fmaxf(a.w, b.w));
}

// ---------------------------------------------------------------- kNN top-16
// block = 256 threads: 4 waves x 64 query points; wave g scans candidate
// slice [g*512, (g+1)*512); partial top-16 lists merged stably by wave 0.
__global__ __launch_bounds__(256) void knn_kernel(const float* __restrict__ pts,
                                                  int* __restrict__ knn_idx) {
  __shared__ float px[NN], py[NN], pz[NN], sq[NN];          // 32 KB
  __shared__ float pval[4][64][KK];                          // 16 KB
  __shared__ int   pidx[4][64][KK];                          // 16 KB
  const int b = blockIdx.x >> 5;     // 32 blocks per batch
  const int tile = blockIdx.x & 31;
  const int tid = threadIdx.x;
  const int p = tid & 63;            // query point within tile
  const int g = tid >> 6;            // candidate group (wave id)

  for (int i = tid; i < NN; i += 256) {
    float x = pts[(size_t)(b * NN + i) * 3 + 0];
    float y = pts[(size_t)(b * NN + i) * 3 + 1];
    float z = pts[(size_t)(b * NN + i) * 3 + 2];
    px[i] = x; py[i] = y; pz[i] = z;
    sq[i] = x * x + y * y + z * z;
  }
  __syncthreads();

  const int n = tile * 64 + p;
  const float xn = px[n], yn = py[n], zn = pz[n], sqn = sq[n];
  float vals[KK]; int ids[KK];
#pragma unroll
  for (int j = 0; j < KK; ++j) { vals[j] = -3.0e38f; ids[j] = 0; }
  const int m0 = g * (NN / 4);
  for (int mm = 0; mm < NN / 4; ++mm) {
    const int m = m0 + mm;
    float v = 2.0f * (xn * px[m] + yn * py[m] + zn * pz[m]) - sqn - sq[m];
    if (v > vals[KK - 1]) {
      vals[KK - 1] = v; ids[KK - 1] = m;
#pragma unroll
      for (int j = KK - 1; j > 0; --j) {
        if (vals[j] > vals[j - 1]) {
          float tv = vals[j]; vals[j] = vals[j - 1]; vals[j - 1] = tv;
          int ti = ids[j]; ids[j] = ids[j - 1]; ids[j - 1] = ti;
        }
      }
    }
  }
#pragma unroll
  for (int j = 0; j < KK; ++j) { pval[g][p][j] = vals[j]; pidx[g][p][j] = ids[j]; }
  __syncthreads();

  if (tid < 64) {
    float mv[KK]; int mi[KK];
#pragma unroll
    for (int j = 0; j < KK; ++j) { mv[j] = -3.0e38f; mi[j] = 0; }
    // groups in ascending index order; strict > keeps lower-index-first ties
    for (int g2 = 0; g2 < 4; ++g2) {
#pragma unroll
      for (int j = 0; j < KK; ++j) {
        float v = pval[g2][tid][j]; int id = pidx[g2][tid][j];
        if (v > mv[KK - 1]) {
          mv[KK - 1] = v; mi[KK - 1] = id;
#pragma unroll
          for (int q = KK - 1; q > 0; --q) {
            if (mv[q] > mv[q - 1]) {
              float tv = mv[q]; mv[q] = mv[q - 1]; mv[q - 1] = tv;
              int ti = mi[q]; mi[q] = mi[q - 1]; mi[q - 1] = ti;
            }
          }
        }
      }
    }
    const int nq = tile * 64 + tid;
#pragma unroll
    for (int j = 0; j < KK; ++j) knn_idx[(size_t)(b * NN + nq) * KK + j] = mi[j];
  }
}

// ------------------------------------------- features (pts + cov) + mlp1 x3
// block = 256: thread (p = tid&63, ch = tid>>6); wave-uniform weight rows.
__global__ __launch_bounds__(256) void mlp1_kernel(
    const float* __restrict__ pts, const int* __restrict__ knn_idx,
    const float* __restrict__ w1a, const float* __restrict__ b1a,
    const float* __restrict__ w1b, const float* __restrict__ b1b,
    const float* __restrict__ w1c, const float* __restrict__ b1c,
    float* __restrict__ f1) {
  __shared__ float h1[64][64];   // [chan][point]
  __shared__ float h2[64][64];
  const int tid = threadIdx.x;
  const int p = tid & 63;
  const int ch = tid >> 6;
  const int base = blockIdx.x * 64;
  const int bn = base + p;
  const int b = bn >> 11;

  const int n0 = knn_idx[(size_t)bn * KK + 0];
  const int n1 = knn_idx[(size_t)bn * KK + 1];
  const float* pp = &pts[(size_t)bn * 3];
  const float* p0 = &pts[((size_t)(b << 11) + n0) * 3];
  const float* p1 = &pts[((size_t)(b << 11) + n1) * 3];
  float in[12];
  in[0] = pp[0]; in[1] = pp[1]; in[2] = pp[2];
  {
    float a0 = p0[0], a1 = p0[1], a2 = p0[2];
    float c0 = p1[0], c1 = p1[1], c2 = p1[2];
    in[3] = a0 * c0; in[4]  = a0 * c1; in[5]  = a0 * c2;
    in[6] = a1 * c0; in[7]  = a1 * c1; in[8]  = a1 * c2;
    in[9] = a2 * c0; in[10] = a2 * c1; in[11] = a2 * c2;
  }

  // layer a: 16 outputs per thread
#pragma unroll 4
  for (int oi = 0; oi < 16; ++oi) {
    const int o = ch * 16 + oi;
    float a = b1a[o];
#pragma unroll
    for (int c = 0; c < 12; ++c) a += w1a[o * 12 + c] * in[c];
    h1[o][p] = fmaxf(a, 0.f);
  }
  __syncthreads();

  float xr[64];
#pragma unroll
  for (int c = 0; c < 64; ++c) xr[c] = h1[c][p];
#pragma unroll 4
  for (int oi = 0; oi < 16; ++oi) {
    const int o = ch * 16 + oi;
    float a = b1b[o];
#pragma unroll
    for (int c = 0; c < 64; ++c) a += w1b[o * 64 + c] * xr[c];
    h2[o][p] = fmaxf(a, 0.f);
  }
  __syncthreads();

#pragma unroll
  for (int c = 0; c < 64; ++c) xr[c] = h2[c][p];
#pragma unroll 4
  for (int oi = 0; oi < 16; ++oi) {
    const int o = ch * 16 + oi;
    float a = b1c[o];
#pragma unroll
    for (int c = 0; c < 64; ++c) a += w1c[o * 64 + c] * xr[c];
    f1[(size_t)bn * 64 + o] = fmaxf(a, 0.f);
  }
}

// ---------------------------------------- maxpool(16) + lin1 + conv1 + relu
__global__ __launch_bounds__(256) void gconv1_kernel(
    const float* __restrict__ f1, const int* __restrict__ knn_idx,
    const float* __restrict__ lin1_w, const float* __restrict__ lin1_b,
    const float* __restrict__ conv1_w, const float* __restrict__ conv1_b,
    float* __restrict__ f2) {
  __shared__ float ms[64][64];   // maxpooled [chan][point]
  __shared__ float ys[64][64];   // lin1 out  [chan][point]
  const int tid = threadIdx.x;
  const int p = tid & 63;
  const int ch = tid >> 6;
  const int bn = blockIdx.x * 64 + p;
  const int b = bn >> 11;

  // phase 1: gather-maxpool channels [ch*16, ch*16+16)
  const int4* idr = (const int4*)&knn_idx[(size_t)bn * KK];
  int4 nb4[4];
#pragma unroll
  for (int q = 0; q < 4; ++q) nb4[q] = idr[q];
  float4 mx[4];
#pragma unroll
  for (int q = 0; q < 4; ++q) mx[q] = make_float4(-3e38f, -3e38f, -3e38f, -3e38f);
#pragma unroll
  for (int j = 0; j < KK; ++j) {
    const int nb = (j & 3) == 0 ? nb4[j >> 2].x : (j & 3) == 1 ? nb4[j >> 2].y
                 : (j & 3) == 2 ? nb4[j >> 2].z : nb4[j >> 2].w;
    const float4* v = (const float4*)&f1[((size_t)(b << 11) + nb) * 64 + ch * 16];
#pragma unroll
    for (int q = 0; q < 4; ++q) mx[q] = f4max(mx[q], v[q]);
  }
#pragma unroll
  for (int q = 0; q < 4; ++q) {
    ms[ch * 16 + q * 4 + 0][p] = mx[q].x;
    ms[ch * 16 + q * 4 + 1][p] = mx[q].y;
    ms[ch * 16 + q * 4 + 2][p] = mx[q].z;
    ms[ch * 16 + q * 4 + 3][p] = mx[q].w;
  }
  __syncthreads();

  // phase 2: lin1 (no relu), 16 outputs per thread
  float xr[64];
#pragma unroll
  for (int c = 0; c < 64; ++c) xr[c] = ms[c][p];
#pragma unroll 4
  for (int oi = 0; oi < 16; ++oi) {
    const int o = ch * 16 + oi;
    float a = lin1_b[o];
#pragma unroll
    for (int c = 0; c < 64; ++c) a += lin1_w[o * 64 + c] * xr[c];
    ys[o][p] = a;
  }
  __syncthreads();

  // phase 3: conv1 + relu, 32 outputs per thread
#pragma unroll
  for (int c = 0; c < 64; ++c) xr[c] = ys[c][p];
#pragma unroll 2
  for (int oi = 0; oi < 32; ++oi) {
    const int o = ch * 32 + oi;
    float a = conv1_b[o];
#pragma unroll
    for (int c = 0; c < 64; ++c) a += conv1_w[o * 64 + c] * xr[c];
    f2[(size_t)bn * 128 + o] = fmaxf(a, 0.f);
  }
}

// ------------------------------------------------- maxpool(16) + lin2
__global__ __launch_bounds__(256) void gconv2_kernel(
    const float* __restrict__ f2, const int* __restrict__ knn_idx,
    const float* __restrict__ lin2_w, const float* __restrict__ lin2_b,
    float* __restrict__ f3) {
  __shared__ float ms[128][64];   // 32 KB
  const int tid = threadIdx.x;
  const int p = tid & 63;
  const int ch = tid >> 6;
  const int bn = blockIdx.x * 64 + p;
  const int b = bn >> 11;

  // phase 1: gather-maxpool channels [ch*32, ch*32+32)
  const int4* idr = (const int4*)&knn_idx[(size_t)bn * KK];
  int4 nb4[4];
#pragma unroll
  for (int q = 0; q < 4; ++q) nb4[q] = idr[q];
  float4 mx[8];
#pragma unroll
  for (int q = 0; q < 8; ++q) mx[q] = make_float4(-3e38f, -3e38f, -3e38f, -3e38f);
#pragma unroll
  for (int j = 0; j < KK; ++j) {
    const int nb = (j & 3) == 0 ? nb4[j >> 2].x : (j & 3) == 1 ? nb4[j >> 2].y
                 : (j & 3) == 2 ? nb4[j >> 2].z : nb4[j >> 2].w;
    const float4* v = (const float4*)&f2[((size_t)(b << 11) + nb) * 128 + ch * 32];
#pragma unroll
    for (int q = 0; q < 8; ++q) mx[q] = f4max(mx[q], v[q]);
  }
#pragma unroll
  for (int q = 0; q < 8; ++q) {
    ms[ch * 32 + q * 4 + 0][p] = mx[q].x;
    ms[ch * 32 + q * 4 + 1][p] = mx[q].y;
    ms[ch * 32 + q * 4 + 2][p] = mx[q].z;
    ms[ch * 32 + q * 4 + 3][p] = mx[q].w;
  }
  __syncthreads();

  // phase 2: lin2 (no relu), 32 outputs per thread, x fully in regs
  float xr[128];
#pragma unroll
  for (int c = 0; c < 128; ++c) xr[c] = ms[c][p];
#pragma unroll 1
  for (int oi = 0; oi < 32; ++oi) {
    const int o = ch * 32 + oi;
    float a = lin2_b[o];
#pragma unroll
    for (int c = 0; c < 128; ++c) a += lin2_w[o * 128 + c] * xr[c];
    f3[(size_t)bn * 128 + o] = a;
  }
}

// ------------------------------- conv2 (128->1024) fused with global max(n)
__global__ __launch_bounds__(256) void conv2max_kernel(
    const float* __restrict__ f3, const float* __restrict__ conv2_w,
    const float* __restrict__ conv2_b, float* __restrict__ pmax) {
  const int bi = blockIdx.x;        // 512 = 8 b * 8 otile * 8 ngroup
  const int b  = bi >> 6;
  const int ot = (bi >> 3) & 7;     // 8 o-tiles of 128
  const int ng = bi & 7;            // 8 n-groups of 256
  const int tid = threadIdx.x;
  const int n = ng * 256 + tid;

  float x[128];
  const float4* xp = (const float4*)&f3[((size_t)b * NN + n) * 128];
#pragma unroll
  for (int q = 0; q < 32; ++q) {
    float4 v = xp[q];
    x[q * 4 + 0] = v.x; x[q * 4 + 1] = v.y; x[q * 4 + 2] = v.z; x[q * 4 + 3] = v.w;
  }

  __shared__ float red[16][4][8];
  const int wid = tid >> 6, lane = tid & 63;
  for (int chunk = 0; chunk < 16; ++chunk) {
    float v[8];
#pragma unroll
    for (int i = 0; i < 8; ++i) {
      const int oo = ot * 128 + chunk * 8 + i;
      const float* w = &conv2_w[(size_t)oo * 128];
      float a = conv2_b[oo];
#pragma unroll
      for (int c = 0; c < 128; ++c) a += w[c] * x[c];
      v[i] = a;
    }
#pragma unroll
    for (int i = 0; i < 8; ++i) {
#pragma unroll
      for (int s = 32; s >= 1; s >>= 1) v[i] = fmaxf(v[i], __shfl_xor(v[i], s, 64));
    }
    if (lane == 0) {
#pragma unroll
      for (int i = 0; i < 8; ++i) red[chunk][wid][i] = v[i];
    }
  }
  __syncthreads();
  if (tid < 128) {
    const int chunk = tid >> 3, i = tid & 7;
    float a = fmaxf(fmaxf(red[chunk][0][i], red[chunk][1][i]),
                    fmaxf(red[chunk][2][i], red[chunk][3][i]));
    const int oo = ot * 128 + chunk * 8 + i;
    pmax[((size_t)b * 1024 + oo) * 8 + ng] = a;
  }
}

// ----------------------------------------- reduce partials + mlp2 head
__global__ __launch_bounds__(256) void head_kernel(
    const float* __restrict__ pmax,
    const float* __restrict__ w2a, const float* __restrict__ b2a,
    const float* __restrict__ w2b, const float* __restrict__ b2b,
    float* __restrict__ out) {
  const int b = blockIdx.x;
  const int tid = threadIdx.x;
  __shared__ __align__(16) float g[1024];
  __shared__ __align__(16) float h[512];
  for (int o = tid; o < 1024; o += 256) {
    const float* p = &pmax[((size_t)b * 1024 + o) * 8];
    float a = p[0];
#pragma unroll
    for (int gi = 1; gi < 8; ++gi) a = fmaxf(a, p[gi]);
    g[o] = a;
  }
  __syncthreads();
#pragma unroll
  for (int r = 0; r < 2; ++r) {
    const int k = r * 256 + tid;
    float a = b2a[k];
    const float4* wr = (const float4*)&w2a[(size_t)k * 1024];
    const float4* gv = (const float4*)g;
    for (int c = 0; c < 256; ++c) {
      float4 w = wr[c], xx = gv[c];
      a += w.x * xx.x + w.y * xx.y + w.z * xx.z + w.w * xx.w;
    }
    h[k] = fmaxf(a, 0.f);
  }
  __syncthreads();
#pragma unroll
  for (int r = 0; r < 2; ++r) {
    const int j = r * 256 + tid;
    float a = b2b[j];
    const float4* wr = (const float4*)&w2b[(size_t)j * 512];
    const float4* hv = (const float4*)h;
    for (int c = 0; c < 128; ++c) {
      float4 w = wr[c], xx = hv[c];
      a += w.x * xx.x + w.y * xx.y + w.z * xx.z + w.w * xx.w;
    }
    out[(size_t)b * 512 + j] = a;
  }
}

extern "C" void kernel_launch(void* const* d_in, const int* in_sizes, int n_in,
                              void* d_out, int out_size, void* d_ws, size_t ws_size,
                              hipStream_t stream) {
  const float* pts     = (const float*)d_in[0];
  const float* w1a     = (const float*)d_in[1];
  const float* b1a     = (const float*)d_in[2];
  const float* w1b     = (const float*)d_in[3];
  const float* b1b     = (const float*)d_in[4];
  const float* w1c     = (const float*)d_in[5];
  const float* b1c     = (const float*)d_in[6];
  const float* lin1_w  = (const float*)d_in[7];
  const float* lin1_b  = (const float*)d_in[8];
  const float* conv1_w = (const float*)d_in[9];
  const float* conv1_b = (const float*)d_in[10];
  const float* lin2_w  = (const float*)d_in[11];
  const float* lin2_b  = (const float*)d_in[12];
  const float* conv2_w = (const float*)d_in[13];
  const float* conv2_b = (const float*)d_in[14];
  const float* w2a     = (const float*)d_in[15];
  const float* b2a     = (const float*)d_in[16];
  const float* w2b     = (const float*)d_in[17];
  const float* b2b     = (const float*)d_in[18];

  char* ws = (char*)d_ws;
  int*   knn_idx = (int*)ws;                       // 1 MB
  float* f1 = (float*)(ws + (1u << 20));           // 4 MB   (region A)
  float* f2 = (float*)(ws + (9u << 20));           // 8 MB   (region B)
  float* f3 = (float*)(ws + (1u << 20));           // 8 MB   (region A reuse; f1 dead)
  float* pm = (float*)(ws + (17u << 20));          // 256 KB

  knn_kernel   <<<256, 256, 0, stream>>>(pts, knn_idx);
  mlp1_kernel  <<<256, 256, 0, stream>>>(pts, knn_idx, w1a, b1a, w1b, b1b, w1c, b1c, f1);
  gconv1_kernel<<<256, 256, 0, stream>>>(f1, knn_idx, lin1_w, lin1_b, conv1_w, conv1_b, f2);
  gconv2_kernel<<<256, 256, 0, stream>>>(f2, knn_idx, lin2_w, lin2_b, f3);
  conv2max_kernel<<<512, 256, 0, stream>>>(f3, conv2_w, conv2_b, pm);
  head_kernel  <<<8, 256, 0, stream>>>(pm, w2a, b2a, w2b, b2b, (float*)d_out);
}

// Round 3
// 508.615 us; speedup vs baseline: 2.4792x; 1.5564x over previous
//
#include <hip/hip_runtime.h>

#define BB 8
#define NN 2048
#define KK 16
#define QT 32   // kNN queries per block

__device__ __forceinline__ float4 f4max(float4 a, float4 b) {
  return make_float4(fmaxf(a.x, b.x), fmaxf(a.y, b.y), fmaxf(a.z, b.z), fmaxf(a.w, b.w));
}

// ---------------------------------------------------------------- kNN top-16
// 512 blocks = 8 batches x 64 tiles of 32 queries. 256 threads: thread
// (q = tid&31, s = tid>>5) scans candidate slice s (256 candidates) for
// query q. Partial top-16 INDICES stored in LDS (ushort, padded); 32-lane
// merge recomputes distances (deterministic => identical values/order).
__global__ __launch_bounds__(256) void knn_kernel(const float* __restrict__ pts,
                                                  int* __restrict__ knn_idx) {
  __shared__ float4 sp[NN];                       // 32 KB (x,y,z,|p|^2)
  __shared__ unsigned short pidx[8][QT][17];      // 8.7 KB, pad -> conflict-free
  const int b = blockIdx.x >> 6;
  const int tile = blockIdx.x & 63;
  const int tid = threadIdx.x;
  const int q = tid & 31;
  const int s = tid >> 5;

  for (int i = tid; i < NN; i += 256) {
    float x = pts[(size_t)(b * NN + i) * 3 + 0];
    float y = pts[(size_t)(b * NN + i) * 3 + 1];
    float z = pts[(size_t)(b * NN + i) * 3 + 2];
    sp[i] = make_float4(x, y, z, x * x + y * y + z * z);
  }
  __syncthreads();

  const int n = tile * QT + q;
  const float4 pq = sp[n];
  float vals[KK]; int ids[KK];
#pragma unroll
  for (int j = 0; j < KK; ++j) { vals[j] = -3.0e38f; ids[j] = 0; }

  const int m0 = s * (NN / 8);
  for (int mb = 0; mb < NN / 8; mb += 8) {
    float4 c[8];
#pragma unroll
    for (int u = 0; u < 8; ++u) c[u] = sp[m0 + mb + u];
#pragma unroll
    for (int u = 0; u < 8; ++u) {
      float v = 2.0f * (pq.x * c[u].x + pq.y * c[u].y + pq.z * c[u].z) - pq.w - c[u].w;
      if (v > vals[KK - 1]) {
        vals[KK - 1] = v; ids[KK - 1] = m0 + mb + u;
#pragma unroll
        for (int j = KK - 1; j > 0; --j) {
          if (vals[j] > vals[j - 1]) {
            float tv = vals[j]; vals[j] = vals[j - 1]; vals[j - 1] = tv;
            int ti = ids[j]; ids[j] = ids[j - 1]; ids[j - 1] = ti;
          }
        }
      }
    }
  }
#pragma unroll
  for (int j = 0; j < KK; ++j) pidx[s][q][j] = (unsigned short)ids[j];
  __syncthreads();

  if (tid < QT) {
    float mv[KK]; int mi[KK];
#pragma unroll
    for (int j = 0; j < KK; ++j) { mv[j] = -3.0e38f; mi[j] = 0; }
    const float4 pm = sp[tile * QT + tid];
    // lists in ascending slice order; within a list sorted desc (stable) ->
    // strict-> insert reproduces top_k's lower-index-first tie-break.
    for (int s2 = 0; s2 < 8; ++s2) {
#pragma unroll 1
      for (int j = 0; j < KK; ++j) {
        const int id = pidx[s2][tid][j];
        const float4 c = sp[id];
        const float v = 2.0f * (pm.x * c.x + pm.y * c.y + pm.z * c.z) - pm.w - c.w;
        if (v <= mv[KK - 1]) break;   // list sorted desc: rest can't insert
        mv[KK - 1] = v; mi[KK - 1] = id;
#pragma unroll
        for (int t = KK - 1; t > 0; --t) {
          if (mv[t] > mv[t - 1]) {
            float tv = mv[t]; mv[t] = mv[t - 1]; mv[t - 1] = tv;
            int ti = mi[t]; mi[t] = mi[t - 1]; mi[t - 1] = ti;
          }
        }
      }
    }
    const int nq = tile * QT + tid;
#pragma unroll
    for (int j = 0; j < KK; ++j) knn_idx[(size_t)(b * NN + nq) * KK + j] = mi[j];
  }
}

// ------------------------------------------- features (pts + cov) + mlp1 x3
__global__ __launch_bounds__(256) void mlp1_kernel(
    const float* __restrict__ pts, const int* __restrict__ knn_idx,
    const float* __restrict__ w1a, const float* __restrict__ b1a,
    const float* __restrict__ w1b, const float* __restrict__ b1b,
    const float* __restrict__ w1c, const float* __restrict__ b1c,
    float* __restrict__ f1) {
  __shared__ float h1[64][64];
  __shared__ float h2[64][64];
  const int tid = threadIdx.x;
  const int p = tid & 63;
  const int ch = tid >> 6;
  const int bn = blockIdx.x * 64 + p;
  const int b = bn >> 11;

  const int n0 = knn_idx[(size_t)bn * KK + 0];
  const int n1 = knn_idx[(size_t)bn * KK + 1];
  const float* pp = &pts[(size_t)bn * 3];
  const float* p0 = &pts[((size_t)(b << 11) + n0) * 3];
  const float* p1 = &pts[((size_t)(b << 11) + n1) * 3];
  float in[12];
  in[0] = pp[0]; in[1] = pp[1]; in[2] = pp[2];
  {
    float a0 = p0[0], a1 = p0[1], a2 = p0[2];
    float c0 = p1[0], c1 = p1[1], c2 = p1[2];
    in[3] = a0 * c0; in[4]  = a0 * c1; in[5]  = a0 * c2;
    in[6] = a1 * c0; in[7]  = a1 * c1; in[8]  = a1 * c2;
    in[9] = a2 * c0; in[10] = a2 * c1; in[11] = a2 * c2;
  }

#pragma unroll 4
  for (int oi = 0; oi < 16; ++oi) {
    const int o = ch * 16 + oi;
    float a = b1a[o];
#pragma unroll
    for (int c = 0; c < 12; ++c) a += w1a[o * 12 + c] * in[c];
    h1[o][p] = fmaxf(a, 0.f);
  }
  __syncthreads();

  float xr[64];
#pragma unroll
  for (int c = 0; c < 64; ++c) xr[c] = h1[c][p];
#pragma unroll 4
  for (int oi = 0; oi < 16; ++oi) {
    const int o = ch * 16 + oi;
    float a = b1b[o];
#pragma unroll
    for (int c = 0; c < 64; ++c) a += w1b[o * 64 + c] * xr[c];
    h2[o][p] = fmaxf(a, 0.f);
  }
  __syncthreads();

#pragma unroll
  for (int c = 0; c < 64; ++c) xr[c] = h2[c][p];
#pragma unroll 4
  for (int oi = 0; oi < 16; ++oi) {
    const int o = ch * 16 + oi;
    float a = b1c[o];
#pragma unroll
    for (int c = 0; c < 64; ++c) a += w1c[o * 64 + c] * xr[c];
    f1[(size_t)bn * 64 + o] = fmaxf(a, 0.f);
  }
}

// ---------------------------------------- maxpool(16) + lin1 + conv1 + relu
__global__ __launch_bounds__(256) void gconv1_kernel(
    const float* __restrict__ f1, const int* __restrict__ knn_idx,
    const float* __restrict__ lin1_w, const float* __restrict__ lin1_b,
    const float* __restrict__ conv1_w, const float* __restrict__ conv1_b,
    float* __restrict__ f2) {
  __shared__ float ms[64][64];
  __shared__ float ys[64][64];
  const int tid = threadIdx.x;
  const int p = tid & 63;
  const int ch = tid >> 6;
  const int bn = blockIdx.x * 64 + p;
  const int b = bn >> 11;

  const int4* idr = (const int4*)&knn_idx[(size_t)bn * KK];
  int4 nb4[4];
#pragma unroll
  for (int q = 0; q < 4; ++q) nb4[q] = idr[q];
  float4 mx[4];
#pragma unroll
  for (int q = 0; q < 4; ++q) mx[q] = make_float4(-3e38f, -3e38f, -3e38f, -3e38f);
#pragma unroll
  for (int j = 0; j < KK; ++j) {
    const int nb = (j & 3) == 0 ? nb4[j >> 2].x : (j & 3) == 1 ? nb4[j >> 2].y
                 : (j & 3) == 2 ? nb4[j >> 2].z : nb4[j >> 2].w;
    const float4* v = (const float4*)&f1[((size_t)(b << 11) + nb) * 64 + ch * 16];
#pragma unroll
    for (int q = 0; q < 4; ++q) mx[q] = f4max(mx[q], v[q]);
  }
#pragma unroll
  for (int q = 0; q < 4; ++q) {
    ms[ch * 16 + q * 4 + 0][p] = mx[q].x;
    ms[ch * 16 + q * 4 + 1][p] = mx[q].y;
    ms[ch * 16 + q * 4 + 2][p] = mx[q].z;
    ms[ch * 16 + q * 4 + 3][p] = mx[q].w;
  }
  __syncthreads();

  float xr[64];
#pragma unroll
  for (int c = 0; c < 64; ++c) xr[c] = ms[c][p];
#pragma unroll 4
  for (int oi = 0; oi < 16; ++oi) {
    const int o = ch * 16 + oi;
    float a = lin1_b[o];
#pragma unroll
    for (int c = 0; c < 64; ++c) a += lin1_w[o * 64 + c] * xr[c];
    ys[o][p] = a;
  }
  __syncthreads();

#pragma unroll
  for (int c = 0; c < 64; ++c) xr[c] = ys[c][p];
#pragma unroll 2
  for (int oi = 0; oi < 32; ++oi) {
    const int o = ch * 32 + oi;
    float a = conv1_b[o];
#pragma unroll
    for (int c = 0; c < 64; ++c) a += conv1_w[o * 64 + c] * xr[c];
    f2[(size_t)bn * 128 + o] = fmaxf(a, 0.f);
  }
}

// ------------------------------------------------- maxpool(16) + lin2
__global__ __launch_bounds__(256) void gconv2_kernel(
    const float* __restrict__ f2, const int* __restrict__ knn_idx,
    const float* __restrict__ lin2_w, const float* __restrict__ lin2_b,
    float* __restrict__ f3) {
  __shared__ float ms[128][64];
  const int tid = threadIdx.x;
  const int p = tid & 63;
  const int ch = tid >> 6;
  const int bn = blockIdx.x * 64 + p;
  const int b = bn >> 11;

  const int4* idr = (const int4*)&knn_idx[(size_t)bn * KK];
  int4 nb4[4];
#pragma unroll
  for (int q = 0; q < 4; ++q) nb4[q] = idr[q];
  float4 mx[8];
#pragma unroll
  for (int q = 0; q < 8; ++q) mx[q] = make_float4(-3e38f, -3e38f, -3e38f, -3e38f);
#pragma unroll
  for (int j = 0; j < KK; ++j) {
    const int nb = (j & 3) == 0 ? nb4[j >> 2].x : (j & 3) == 1 ? nb4[j >> 2].y
                 : (j & 3) == 2 ? nb4[j >> 2].z : nb4[j >> 2].w;
    const float4* v = (const float4*)&f2[((size_t)(b << 11) + nb) * 128 + ch * 32];
#pragma unroll
    for (int q = 0; q < 8; ++q) mx[q] = f4max(mx[q], v[q]);
  }
#pragma unroll
  for (int q = 0; q < 8; ++q) {
    ms[ch * 32 + q * 4 + 0][p] = mx[q].x;
    ms[ch * 32 + q * 4 + 1][p] = mx[q].y;
    ms[ch * 32 + q * 4 + 2][p] = mx[q].z;
    ms[ch * 32 + q * 4 + 3][p] = mx[q].w;
  }
  __syncthreads();

  float xr[128];
#pragma unroll
  for (int c = 0; c < 128; ++c) xr[c] = ms[c][p];
#pragma unroll 1
  for (int oi = 0; oi < 32; ++oi) {
    const int o = ch * 32 + oi;
    float a = lin2_b[o];
#pragma unroll
    for (int c = 0; c < 128; ++c) a += lin2_w[o * 128 + c] * xr[c];
    f3[(size_t)bn * 128 + o] = a;
  }
}

// ------------------------------- conv2 (128->1024) fused with global max(n)
// 1024 blocks = 8 b x 16 o-tiles(64) x 8 n-groups(256). x held in VGPRs
// (launch_bounds min-waves=2 -> 256-VGPR cap prevents the round-2 spill).
__global__ __launch_bounds__(256, 2) void conv2max_kernel(
    const float* __restrict__ f3, const float* __restrict__ conv2_w,
    const float* __restrict__ conv2_b, float* __restrict__ pmax) {
  const int bi = blockIdx.x;
  const int b  = bi >> 7;
  const int ot = (bi >> 3) & 15;
  const int ng = bi & 7;
  const int tid = threadIdx.x;
  const int n = ng * 256 + tid;

  float4 xr[32];
  const float4* xp = (const float4*)&f3[((size_t)b * NN + n) * 128];
#pragma unroll
  for (int c = 0; c < 32; ++c) xr[c] = xp[c];

  __shared__ float red[4][64];
  const int wid = tid >> 6, lane = tid & 63;

#pragma unroll 1
  for (int og = 0; og < 16; ++og) {
    const int o0 = ot * 64 + og * 4;
    const float4* w0 = (const float4*)&conv2_w[(size_t)(o0 + 0) * 128];
    const float4* w1 = (const float4*)&conv2_w[(size_t)(o0 + 1) * 128];
    const float4* w2 = (const float4*)&conv2_w[(size_t)(o0 + 2) * 128];
    const float4* w3 = (const float4*)&conv2_w[(size_t)(o0 + 3) * 128];
    float a0 = conv2_b[o0 + 0], a1 = conv2_b[o0 + 1];
    float a2 = conv2_b[o0 + 2], a3 = conv2_b[o0 + 3];
#pragma unroll
    for (int c = 0; c < 32; ++c) {
      const float4 x4 = xr[c];
      float4 w;
      w = w0[c]; a0 += w.x * x4.x + w.y * x4.y + w.z * x4.z + w.w * x4.w;
      w = w1[c]; a1 += w.x * x4.x + w.y * x4.y + w.z * x4.z + w.w * x4.w;
      w = w2[c]; a2 += w.x * x4.x + w.y * x4.y + w.z * x4.z + w.w * x4.w;
      w = w3[c]; a3 += w.x * x4.x + w.y * x4.y + w.z * x4.z + w.w * x4.w;
    }
    float v[4] = {a0, a1, a2, a3};
#pragma unroll
    for (int i = 0; i < 4; ++i) {
#pragma unroll
      for (int st = 32; st >= 1; st >>= 1) v[i] = fmaxf(v[i], __shfl_xor(v[i], st, 64));
    }
    if (lane == 0) {
#pragma unroll
      for (int i = 0; i < 4; ++i) red[wid][og * 4 + i] = v[i];
    }
  }
  __syncthreads();
  if (tid < 64) {
    float a = fmaxf(fmaxf(red[0][tid], red[1][tid]), fmaxf(red[2][tid], red[3][tid]));
    pmax[((size_t)b * 1024 + ot * 64 + tid) * 8 + ng] = a;
  }
}

// ----------------------------------------- reduce partials + mlp2 head
__global__ __launch_bounds__(256) void head_kernel(
    const float* __restrict__ pmax,
    const float* __restrict__ w2a, const float* __restrict__ b2a,
    const float* __restrict__ w2b, const float* __restrict__ b2b,
    float* __restrict__ out) {
  const int b = blockIdx.x;
  const int tid = threadIdx.x;
  __shared__ __align__(16) float g[1024];
  __shared__ __align__(16) float h[512];
  for (int o = tid; o < 1024; o += 256) {
    const float* p = &pmax[((size_t)b * 1024 + o) * 8];
    float a = p[0];
#pragma unroll
    for (int gi = 1; gi < 8; ++gi) a = fmaxf(a, p[gi]);
    g[o] = a;
  }
  __syncthreads();
#pragma unroll
  for (int r = 0; r < 2; ++r) {
    const int k = r * 256 + tid;
    float a = b2a[k];
    const float4* wr = (const float4*)&w2a[(size_t)k * 1024];
    const float4* gv = (const float4*)g;
    for (int c = 0; c < 256; ++c) {
      float4 w = wr[c], xx = gv[c];
      a += w.x * xx.x + w.y * xx.y + w.z * xx.z + w.w * xx.w;
    }
    h[k] = fmaxf(a, 0.f);
  }
  __syncthreads();
#pragma unroll
  for (int r = 0; r < 2; ++r) {
    const int j = r * 256 + tid;
    float a = b2b[j];
    const float4* wr = (const float4*)&w2b[(size_t)j * 512];
    const float4* hv = (const float4*)h;
    for (int c = 0; c < 128; ++c) {
      float4 w = wr[c], xx = hv[c];
      a += w.x * xx.x + w.y * xx.y + w.z * xx.z + w.w * xx.w;
    }
    out[(size_t)b * 512 + j] = a;
  }
}

extern "C" void kernel_launch(void* const* d_in, const int* in_sizes, int n_in,
                              void* d_out, int out_size, void* d_ws, size_t ws_size,
                              hipStream_t stream) {
  const float* pts     = (const float*)d_in[0];
  const float* w1a     = (const float*)d_in[1];
  const float* b1a     = (const float*)d_in[2];
  const float* w1b     = (const float*)d_in[3];
  const float* b1b     = (const float*)d_in[4];
  const float* w1c     = (const float*)d_in[5];
  const float* b1c     = (const float*)d_in[6];
  const float* lin1_w  = (const float*)d_in[7];
  const float* lin1_b  = (const float*)d_in[8];
  const float* conv1_w = (const float*)d_in[9];
  const float* conv1_b = (const float*)d_in[10];
  const float* lin2_w  = (const float*)d_in[11];
  const float* lin2_b  = (const float*)d_in[12];
  const float* conv2_w = (const float*)d_in[13];
  const float* conv2_b = (const float*)d_in[14];
  const float* w2a     = (const float*)d_in[15];
  const float* b2a     = (const float*)d_in[16];
  const float* w2b     = (const float*)d_in[17];
  const float* b2b     = (const float*)d_in[18];

  char* ws = (char*)d_ws;
  int*   knn_idx = (int*)ws;                       // 1 MB
  float* f1 = (float*)(ws + (1u << 20));           // 4 MB   (region A)
  float* f2 = (float*)(ws + (9u << 20));           // 8 MB   (region B)
  float* f3 = (float*)(ws + (1u << 20));           // 8 MB   (region A reuse; f1 dead)
  float* pm = (float*)(ws + (17u << 20));          // 256 KB

  knn_kernel   <<<512, 256, 0, stream>>>(pts, knn_idx);
  mlp1_kernel  <<<256, 256, 0, stream>>>(pts, knn_idx, w1a, b1a, w1b, b1b, w1c, b1c, f1);
  gconv1_kernel<<<256, 256, 0, stream>>>(f1, knn_idx, lin1_w, lin1_b, conv1_w, conv1_b, f2);
  gconv2_kernel<<<256, 256, 0, stream>>>(f2, knn_idx, lin2_w, lin2_b, f3);
  conv2max_kernel<<<1024, 256, 0, stream>>>(f3, conv2_w, conv2_b, pm);
  head_kernel  <<<8, 256, 0, stream>>>(pm, w2a, b2a, w2b, b2b, (float*)d_out);
}

// Round 4
// 392.759 us; speedup vs baseline: 3.2105x; 1.2950x over previous
//
#include <hip/hip_runtime.h>

#define BB 8
#define NN 2048
#define KK 16
#define QT 32   // kNN queries per block

typedef short bf16x8 __attribute__((ext_vector_type(8)));
typedef float f32x4 __attribute__((ext_vector_type(4)));
typedef unsigned short ushort8v __attribute__((ext_vector_type(8)));

__device__ __forceinline__ float4 f4max(float4 a, float4 b) {
  return make_float4(fmaxf(a.x, b.x), fmaxf(a.y, b.y), fmaxf(a.z, b.z), fmaxf(a.w, b.w));
}

__device__ __forceinline__ unsigned short f2bf(float x) {  // f32 -> bf16 bits, RNE
  union { float f; unsigned u; } v; v.f = x;
  unsigned r = v.u + 0x7fffu + ((v.u >> 16) & 1u);
  return (unsigned short)(r >> 16);
}
__device__ __forceinline__ float bf2f(unsigned short h) {
  union { unsigned u; float f; } v; v.u = ((unsigned)h) << 16;
  return v.f;
}

// ---------------------------------------------------------------- kNN top-16
__global__ __launch_bounds__(256) void knn_kernel(const float* __restrict__ pts,
                                                  int* __restrict__ knn_idx) {
  __shared__ float4 sp[NN];                       // 32 KB (x,y,z,|p|^2)
  __shared__ unsigned short pidx[8][QT][17];      // pad -> conflict-free
  const int b = blockIdx.x >> 6;
  const int tile = blockIdx.x & 63;
  const int tid = threadIdx.x;
  const int q = tid & 31;
  const int s = tid >> 5;

  for (int i = tid; i < NN; i += 256) {
    float x = pts[(size_t)(b * NN + i) * 3 + 0];
    float y = pts[(size_t)(b * NN + i) * 3 + 1];
    float z = pts[(size_t)(b * NN + i) * 3 + 2];
    sp[i] = make_float4(x, y, z, x * x + y * y + z * z);
  }
  __syncthreads();

  const int n = tile * QT + q;
  const float4 pq = sp[n];
  float vals[KK]; int ids[KK];
#pragma unroll
  for (int j = 0; j < KK; ++j) { vals[j] = -3.0e38f; ids[j] = 0; }

  const int m0 = s * (NN / 8);
  for (int mb = 0; mb < NN / 8; mb += 8) {
    float4 c[8];
#pragma unroll
    for (int u = 0; u < 8; ++u) c[u] = sp[m0 + mb + u];
#pragma unroll
    for (int u = 0; u < 8; ++u) {
      float v = 2.0f * (pq.x * c[u].x + pq.y * c[u].y + pq.z * c[u].z) - pq.w - c[u].w;
      if (v > vals[KK - 1]) {
        vals[KK - 1] = v; ids[KK - 1] = m0 + mb + u;
#pragma unroll
        for (int j = KK - 1; j > 0; --j) {
          if (vals[j] > vals[j - 1]) {
            float tv = vals[j]; vals[j] = vals[j - 1]; vals[j - 1] = tv;
            int ti = ids[j]; ids[j] = ids[j - 1]; ids[j - 1] = ti;
          }
        }
      }
    }
  }
#pragma unroll
  for (int j = 0; j < KK; ++j) pidx[s][q][j] = (unsigned short)ids[j];
  __syncthreads();

  if (tid < QT) {
    float mv[KK]; int mi[KK];
#pragma unroll
    for (int j = 0; j < KK; ++j) { mv[j] = -3.0e38f; mi[j] = 0; }
    const float4 pm = sp[tile * QT + tid];
    for (int s2 = 0; s2 < 8; ++s2) {
#pragma unroll 1
      for (int j = 0; j < KK; ++j) {
        const int id = pidx[s2][tid][j];
        const float4 c = sp[id];
        const float v = 2.0f * (pm.x * c.x + pm.y * c.y + pm.z * c.z) - pm.w - c.w;
        if (v <= mv[KK - 1]) break;   // list sorted desc: rest can't insert
        mv[KK - 1] = v; mi[KK - 1] = id;
#pragma unroll
        for (int t = KK - 1; t > 0; --t) {
          if (mv[t] > mv[t - 1]) {
            float tv = mv[t]; mv[t] = mv[t - 1]; mv[t - 1] = tv;
            int ti = mi[t]; mi[t] = mi[t - 1]; mi[t - 1] = ti;
          }
        }
      }
    }
    const int nq = tile * QT + tid;
#pragma unroll
    for (int j = 0; j < KK; ++j) knn_idx[(size_t)(b * NN + nq) * KK + j] = mi[j];
  }
}

// ------------------------------------------- features (pts + cov) + mlp1 x3
__global__ __launch_bounds__(256) void mlp1_kernel(
    const float* __restrict__ pts, const int* __restrict__ knn_idx,
    const float* __restrict__ w1a, const float* __restrict__ b1a,
    const float* __restrict__ w1b, const float* __restrict__ b1b,
    const float* __restrict__ w1c, const float* __restrict__ b1c,
    float* __restrict__ f1) {
  __shared__ float h1[64][64];
  __shared__ float h2[64][64];
  const int tid = threadIdx.x;
  const int p = tid & 63;
  const int ch = tid >> 6;
  const int bn = blockIdx.x * 64 + p;
  const int b = bn >> 11;

  const int n0 = knn_idx[(size_t)bn * KK + 0];
  const int n1 = knn_idx[(size_t)bn * KK + 1];
  const float* pp = &pts[(size_t)bn * 3];
  const float* p0 = &pts[((size_t)(b << 11) + n0) * 3];
  const float* p1 = &pts[((size_t)(b << 11) + n1) * 3];
  float in[12];
  in[0] = pp[0]; in[1] = pp[1]; in[2] = pp[2];
  {
    float a0 = p0[0], a1 = p0[1], a2 = p0[2];
    float c0 = p1[0], c1 = p1[1], c2 = p1[2];
    in[3] = a0 * c0; in[4]  = a0 * c1; in[5]  = a0 * c2;
    in[6] = a1 * c0; in[7]  = a1 * c1; in[8]  = a1 * c2;
    in[9] = a2 * c0; in[10] = a2 * c1; in[11] = a2 * c2;
  }

#pragma unroll 4
  for (int oi = 0; oi < 16; ++oi) {
    const int o = ch * 16 + oi;
    float a = b1a[o];
#pragma unroll
    for (int c = 0; c < 12; ++c) a += w1a[o * 12 + c] * in[c];
    h1[o][p] = fmaxf(a, 0.f);
  }
  __syncthreads();

  float xr[64];
#pragma unroll
  for (int c = 0; c < 64; ++c) xr[c] = h1[c][p];
#pragma unroll 4
  for (int oi = 0; oi < 16; ++oi) {
    const int o = ch * 16 + oi;
    float a = b1b[o];
#pragma unroll
    for (int c = 0; c < 64; ++c) a += w1b[o * 64 + c] * xr[c];
    h2[o][p] = fmaxf(a, 0.f);
  }
  __syncthreads();

#pragma unroll
  for (int c = 0; c < 64; ++c) xr[c] = h2[c][p];
#pragma unroll 4
  for (int oi = 0; oi < 16; ++oi) {
    const int o = ch * 16 + oi;
    float a = b1c[o];
#pragma unroll
    for (int c = 0; c < 64; ++c) a += w1c[o * 64 + c] * xr[c];
    f1[(size_t)bn * 64 + o] = fmaxf(a, 0.f);
  }
}

// ---------------------------------------- maxpool(16) + lin1 + conv1 + relu
__global__ __launch_bounds__(256) void gconv1_kernel(
    const float* __restrict__ f1, const int* __restrict__ knn_idx,
    const float* __restrict__ lin1_w, const float* __restrict__ lin1_b,
    const float* __restrict__ conv1_w, const float* __restrict__ conv1_b,
    float* __restrict__ f2) {
  __shared__ float ms[64][64];
  __shared__ float ys[64][64];
  const int tid = threadIdx.x;
  const int p = tid & 63;
  const int ch = tid >> 6;
  const int bn = blockIdx.x * 64 + p;
  const int b = bn >> 11;

  const int4* idr = (const int4*)&knn_idx[(size_t)bn * KK];
  int4 nb4[4];
#pragma unroll
  for (int q = 0; q < 4; ++q) nb4[q] = idr[q];
  float4 mx[4];
#pragma unroll
  for (int q = 0; q < 4; ++q) mx[q] = make_float4(-3e38f, -3e38f, -3e38f, -3e38f);
#pragma unroll
  for (int j = 0; j < KK; ++j) {
    const int nb = (j & 3) == 0 ? nb4[j >> 2].x : (j & 3) == 1 ? nb4[j >> 2].y
                 : (j & 3) == 2 ? nb4[j >> 2].z : nb4[j >> 2].w;
    const float4* v = (const float4*)&f1[((size_t)(b << 11) + nb) * 64 + ch * 16];
#pragma unroll
    for (int q = 0; q < 4; ++q) mx[q] = f4max(mx[q], v[q]);
  }
#pragma unroll
  for (int q = 0; q < 4; ++q) {
    ms[ch * 16 + q * 4 + 0][p] = mx[q].x;
    ms[ch * 16 + q * 4 + 1][p] = mx[q].y;
    ms[ch * 16 + q * 4 + 2][p] = mx[q].z;
    ms[ch * 16 + q * 4 + 3][p] = mx[q].w;
  }
  __syncthreads();

  float xr[64];
#pragma unroll
  for (int c = 0; c < 64; ++c) xr[c] = ms[c][p];
#pragma unroll 4
  for (int oi = 0; oi < 16; ++oi) {
    const int o = ch * 16 + oi;
    float a = lin1_b[o];
#pragma unroll
    for (int c = 0; c < 64; ++c) a += lin1_w[o * 64 + c] * xr[c];
    ys[o][p] = a;
  }
  __syncthreads();

#pragma unroll
  for (int c = 0; c < 64; ++c) xr[c] = ys[c][p];
#pragma unroll 2
  for (int oi = 0; oi < 32; ++oi) {
    const int o = ch * 32 + oi;
    float a = conv1_b[o];
#pragma unroll
    for (int c = 0; c < 64; ++c) a += conv1_w[o * 64 + c] * xr[c];
    f2[(size_t)bn * 128 + o] = fmaxf(a, 0.f);
  }
}

// ------------------------------------------------- maxpool(16) + lin2
__global__ __launch_bounds__(256) void gconv2_kernel(
    const float* __restrict__ f2, const int* __restrict__ knn_idx,
    const float* __restrict__ lin2_w, const float* __restrict__ lin2_b,
    float* __restrict__ f3) {
  __shared__ float ms[128][64];
  const int tid = threadIdx.x;
  const int p = tid & 63;
  const int ch = tid >> 6;
  const int bn = blockIdx.x * 64 + p;
  const int b = bn >> 11;

  const int4* idr = (const int4*)&knn_idx[(size_t)bn * KK];
  int4 nb4[4];
#pragma unroll
  for (int q = 0; q < 4; ++q) nb4[q] = idr[q];
  float4 mx[8];
#pragma unroll
  for (int q = 0; q < 8; ++q) mx[q] = make_float4(-3e38f, -3e38f, -3e38f, -3e38f);
#pragma unroll
  for (int j = 0; j < KK; ++j) {
    const int nb = (j & 3) == 0 ? nb4[j >> 2].x : (j & 3) == 1 ? nb4[j >> 2].y
                 : (j & 3) == 2 ? nb4[j >> 2].z : nb4[j >> 2].w;
    const float4* v = (const float4*)&f2[((size_t)(b << 11) + nb) * 128 + ch * 32];
#pragma unroll
    for (int q = 0; q < 8; ++q) mx[q] = f4max(mx[q], v[q]);
  }
#pragma unroll
  for (int q = 0; q < 8; ++q) {
    ms[ch * 32 + q * 4 + 0][p] = mx[q].x;
    ms[ch * 32 + q * 4 + 1][p] = mx[q].y;
    ms[ch * 32 + q * 4 + 2][p] = mx[q].z;
    ms[ch * 32 + q * 4 + 3][p] = mx[q].w;
  }
  __syncthreads();

  float xr[128];
#pragma unroll
  for (int c = 0; c < 128; ++c) xr[c] = ms[c][p];
#pragma unroll 1
  for (int oi = 0; oi < 32; ++oi) {
    const int o = ch * 32 + oi;
    float a = lin2_b[o];
#pragma unroll
    for (int c = 0; c < 128; ++c) a += lin2_w[o * 128 + c] * xr[c];
    f3[(size_t)bn * 128 + o] = a;
  }
}

// ---------------------- conv2_w f32 -> bf16 hi/lo split (1024x128 = 131072)
__global__ __launch_bounds__(256) void wcvt_kernel(const float* __restrict__ w,
                                                   unsigned short* __restrict__ whi,
                                                   unsigned short* __restrict__ wlo) {
  const int i = blockIdx.x * 256 + threadIdx.x;
  const float x = w[i];
  const unsigned short h = f2bf(x);
  whi[i] = h;
  wlo[i] = f2bf(x - bf2f(h));
}

// ---------------- conv2 (128->1024) via bf16-split MFMA, fused global max(n)
// 256 blocks = 8 b x 32 chunks of 64 points. Wave w owns o-range [w*256,+256).
// X split-converted to LDS (16B-slot XOR swizzle -> conflict-free frag reads).
// x*w = xh*wh + xh*wl + xl*wh  (lo*lo dropped, ~2^-18 rel).
__global__ __launch_bounds__(256, 2) void conv2max_kernel(
    const float* __restrict__ f3, const unsigned short* __restrict__ whi,
    const unsigned short* __restrict__ wlo, float* __restrict__ pmax) {
  __shared__ __align__(16) unsigned short xls[2][64][128];   // 32 KB hi|lo
  const int bi = blockIdx.x;
  const int b = bi >> 5, nc = bi & 31;
  const int tid = threadIdx.x;
  const int lane = tid & 63, wv = tid >> 6;

  // stage + split-convert 64x128 f32 -> bf16 hi/lo (swizzled 16B slots)
  {
    const int n = tid >> 2, cq = (tid & 3) * 32;
    const float4* src = (const float4*)&f3[((size_t)(b * NN + nc * 64 + n)) * 128 + cq];
    char* basep = (char*)&xls[0][0][0];
#pragma unroll
    for (int s = 0; s < 4; ++s) {
      float4 u = src[s * 2], v2 = src[s * 2 + 1];
      float xv[8] = {u.x, u.y, u.z, u.w, v2.x, v2.y, v2.z, v2.w};
      ushort8v hw, lw;
#pragma unroll
      for (int j = 0; j < 8; ++j) {
        unsigned short h = f2bf(xv[j]);
        hw[j] = h;
        lw[j] = f2bf(xv[j] - bf2f(h));
      }
      const int slot = (cq >> 3) + s;
      const int swz = slot ^ (n & 15);
      char* dst = basep + n * 256 + swz * 16;
      *(ushort8v*)dst = hw;
      *(ushort8v*)(dst + 16384) = lw;
    }
  }
  __syncthreads();

  const int g = lane >> 4, r = lane & 15;
  const char* basep = (const char*)&xls[0][0][0];
  float omax[16];
#pragma unroll
  for (int ot = 0; ot < 16; ++ot) omax[ot] = -3e38f;

#pragma unroll
  for (int mg = 0; mg < 2; ++mg) {
    bf16x8 ah[2][4], al[2][4];
#pragma unroll
    for (int m = 0; m < 2; ++m) {
      const int row = (mg * 2 + m) * 16 + r;
#pragma unroll
      for (int kt = 0; kt < 4; ++kt) {
        const int swz = (kt * 4 + g) ^ (row & 15);
        const char* p = basep + row * 256 + swz * 16;
        ah[m][kt] = *(const bf16x8*)p;
        al[m][kt] = *(const bf16x8*)(p + 16384);
      }
    }
#pragma unroll 1
    for (int ot = 0; ot < 16; ++ot) {
      const int o = wv * 256 + ot * 16 + r;
      const char* wb = (const char*)whi + (size_t)o * 256 + g * 16;
      const char* lb = (const char*)wlo + (size_t)o * 256 + g * 16;
      bf16x8 bh[4], bl[4];
#pragma unroll
      for (int kt = 0; kt < 4; ++kt) {
        bh[kt] = *(const bf16x8*)(wb + kt * 64);
        bl[kt] = *(const bf16x8*)(lb + kt * 64);
      }
      f32x4 acc0 = {0.f, 0.f, 0.f, 0.f}, acc1 = {0.f, 0.f, 0.f, 0.f};
#pragma unroll
      for (int kt = 0; kt < 4; ++kt) {
        acc0 = __builtin_amdgcn_mfma_f32_16x16x32_bf16(ah[0][kt], bh[kt], acc0, 0, 0, 0);
        acc1 = __builtin_amdgcn_mfma_f32_16x16x32_bf16(ah[1][kt], bh[kt], acc1, 0, 0, 0);
        acc0 = __builtin_amdgcn_mfma_f32_16x16x32_bf16(ah[0][kt], bl[kt], acc0, 0, 0, 0);
        acc1 = __builtin_amdgcn_mfma_f32_16x16x32_bf16(ah[1][kt], bl[kt], acc1, 0, 0, 0);
        acc0 = __builtin_amdgcn_mfma_f32_16x16x32_bf16(al[0][kt], bh[kt], acc0, 0, 0, 0);
        acc1 = __builtin_amdgcn_mfma_f32_16x16x32_bf16(al[1][kt], bh[kt], acc1, 0, 0, 0);
      }
      float mx = fmaxf(fmaxf(fmaxf(acc0[0], acc0[1]), fmaxf(acc0[2], acc0[3])),
                       fmaxf(fmaxf(acc1[0], acc1[1]), fmaxf(acc1[2], acc1[3])));
      omax[ot] = fmaxf(omax[ot], mx);
    }
  }
#pragma unroll
  for (int ot = 0; ot < 16; ++ot) {
    float v = omax[ot];
    v = fmaxf(v, __shfl_xor(v, 16, 64));
    v = fmaxf(v, __shfl_xor(v, 32, 64));
    omax[ot] = v;
  }
  if (lane < 16) {
#pragma unroll
    for (int ot = 0; ot < 16; ++ot) {
      const int o = wv * 256 + ot * 16 + lane;
      pmax[((size_t)b * 1024 + o) * 32 + nc] = omax[ot];
    }
  }
}

// ----------------------------------------- reduce partials + bias + mlp2 head
__global__ __launch_bounds__(256) void head_kernel(
    const float* __restrict__ pmax, const float* __restrict__ conv2_b,
    const float* __restrict__ w2a, const float* __restrict__ b2a,
    const float* __restrict__ w2b, const float* __restrict__ b2b,
    float* __restrict__ out) {
  const int b = blockIdx.x;
  const int tid = threadIdx.x;
  __shared__ __align__(16) float g[1024];
  __shared__ __align__(16) float h[512];
  for (int o = tid; o < 1024; o += 256) {
    const float4* p = (const float4*)&pmax[((size_t)b * 1024 + o) * 32];
    float4 a4 = p[0];
#pragma unroll
    for (int gi = 1; gi < 8; ++gi) a4 = f4max(a4, p[gi]);
    g[o] = fmaxf(fmaxf(a4.x, a4.y), fmaxf(a4.z, a4.w)) + conv2_b[o];
  }
  __syncthreads();
#pragma unroll
  for (int r = 0; r < 2; ++r) {
    const int k = r * 256 + tid;
    float a = b2a[k];
    const float4* wr = (const float4*)&w2a[(size_t)k * 1024];
    const float4* gv = (const float4*)g;
    for (int c = 0; c < 256; ++c) {
      float4 w = wr[c], xx = gv[c];
      a += w.x * xx.x + w.y * xx.y + w.z * xx.z + w.w * xx.w;
    }
    h[k] = fmaxf(a, 0.f);
  }
  __syncthreads();
#pragma unroll
  for (int r = 0; r < 2; ++r) {
    const int j = r * 256 + tid;
    float a = b2b[j];
    const float4* wr = (const float4*)&w2b[(size_t)j * 512];
    const float4* hv = (const float4*)h;
    for (int c = 0; c < 128; ++c) {
      float4 w = wr[c], xx = hv[c];
      a += w.x * xx.x + w.y * xx.y + w.z * xx.z + w.w * xx.w;
    }
    out[(size_t)b * 512 + j] = a;
  }
}

extern "C" void kernel_launch(void* const* d_in, const int* in_sizes, int n_in,
                              void* d_out, int out_size, void* d_ws, size_t ws_size,
                              hipStream_t stream) {
  const float* pts     = (const float*)d_in[0];
  const float* w1a     = (const float*)d_in[1];
  const float* b1a     = (const float*)d_in[2];
  const float* w1b     = (const float*)d_in[3];
  const float* b1b     = (const float*)d_in[4];
  const float* w1c     = (const float*)d_in[5];
  const float* b1c     = (const float*)d_in[6];
  const float* lin1_w  = (const float*)d_in[7];
  const float* lin1_b  = (const float*)d_in[8];
  const float* conv1_w = (const float*)d_in[9];
  const float* conv1_b = (const float*)d_in[10];
  const float* lin2_w  = (const float*)d_in[11];
  const float* lin2_b  = (const float*)d_in[12];
  const float* conv2_w = (const float*)d_in[13];
  const float* conv2_b = (const float*)d_in[14];
  const float* w2a     = (const float*)d_in[15];
  const float* b2a     = (const float*)d_in[16];
  const float* w2b     = (const float*)d_in[17];
  const float* b2b     = (const float*)d_in[18];

  char* ws = (char*)d_ws;
  int*   knn_idx = (int*)ws;                            // 1 MB
  float* f1 = (float*)(ws + (1u << 20));                // 4 MB   (region A)
  float* f2 = (float*)(ws + (9u << 20));                // 8 MB   (region B)
  float* f3 = (float*)(ws + (1u << 20));                // 8 MB   (region A reuse)
  unsigned short* whi = (unsigned short*)(ws + (17u << 20));            // 256 KB
  unsigned short* wlo = (unsigned short*)(ws + (17u << 20) + (1u << 18)); // 256 KB
  float* pm = (float*)(ws + (17u << 20) + (2u << 18));  // 1 MB

  knn_kernel   <<<512, 256, 0, stream>>>(pts, knn_idx);
  mlp1_kernel  <<<256, 256, 0, stream>>>(pts, knn_idx, w1a, b1a, w1b, b1b, w1c, b1c, f1);
  gconv1_kernel<<<256, 256, 0, stream>>>(f1, knn_idx, lin1_w, lin1_b, conv1_w, conv1_b, f2);
  gconv2_kernel<<<256, 256, 0, stream>>>(f2, knn_idx, lin2_w, lin2_b, f3);
  wcvt_kernel  <<<512, 256, 0, stream>>>(conv2_w, whi, wlo);
  conv2max_kernel<<<256, 256, 0, stream>>>(f3, whi, wlo, pm);
  head_kernel  <<<8, 256, 0, stream>>>(pm, conv2_b, w2a, b2a, w2b, b2b, (float*)d_out);
}

// Round 5
// 377.943 us; speedup vs baseline: 3.3363x; 1.0392x over previous
//
#include <hip/hip_runtime.h>

#define BB 8
#define NN 2048
#define KK 16
#define QT 32      // kNN queries per block
#define NSLICE 8
#define SLEN 256   // NN / NSLICE
#define KP 18      // packed keep-depth per slice (pool safety margin)

typedef short bf16x8 __attribute__((ext_vector_type(8)));
typedef float f32x4 __attribute__((ext_vector_type(4)));
typedef unsigned short ushort8v __attribute__((ext_vector_type(8)));

__device__ __forceinline__ float4 f4max(float4 a, float4 b) {
  return make_float4(fmaxf(a.x, b.x), fmaxf(a.y, b.y), fmaxf(a.z, b.z), fmaxf(a.w, b.w));
}

__device__ __forceinline__ unsigned short f2bf(float x) {  // f32 -> bf16 bits, RNE
  union { float f; unsigned u; } v; v.f = x;
  unsigned r = v.u + 0x7fffu + ((v.u >> 16) & 1u);
  return (unsigned short)(r >> 16);
}
__device__ __forceinline__ float bf2f(unsigned short h) {
  union { unsigned u; float f; } v; v.u = ((unsigned)h) << 16;
  return v.f;
}

// ---------------------------------------------------------------- kNN top-16
// 512 blocks = 8 b x 64 tiles of 32 queries; 256 threads = (q = tid&31,
// s = tid>>5). Scan: branchless packed-u32 top-18 per 256-cand slice
// (24-bit monotone key | 8-bit ~local-idx -> min/max chain, 2 instr/level).
// Merge: exact re-rank of the 8x18 pool (recomputed f32 distances, stable
// strict-> insertion) in two parallel stages -> exact top-16 incl. ties.
__global__ __launch_bounds__(256) void knn_kernel(const float* __restrict__ pts,
                                                  int* __restrict__ knn_idx) {
  __shared__ float4 sp[NN];                         // 32 KB (x,y,z,|p|^2)
  __shared__ unsigned pk[NSLICE][QT][KP];           // 18 KB packed lists
  __shared__ float          s1v[4][QT][16];         // 8 KB stage-1 vals
  __shared__ unsigned short s1i[4][QT][16];         // 4 KB stage-1 ids
  const int b = blockIdx.x >> 6;
  const int tile = blockIdx.x & 63;
  const int tid = threadIdx.x;
  const int q = tid & 31;
  const int s = tid >> 5;

  for (int i = tid; i < NN; i += 256) {
    float x = pts[(size_t)(b * NN + i) * 3 + 0];
    float y = pts[(size_t)(b * NN + i) * 3 + 1];
    float z = pts[(size_t)(b * NN + i) * 3 + 2];
    sp[i] = make_float4(x, y, z, x * x + y * y + z * z);
  }
  __syncthreads();

  // ---- packed scan of slice s for query q
  {
    const float4 pq = sp[tile * QT + q];
    unsigned qk[KP];
#pragma unroll
    for (int j = 0; j < KP; ++j) qk[j] = 0u;
    const int m0 = s * SLEN;
    for (int mb = 0; mb < SLEN; mb += 8) {
      float4 c[8];
#pragma unroll
      for (int u = 0; u < 8; ++u) c[u] = sp[m0 + mb + u];
#pragma unroll
      for (int u = 0; u < 8; ++u) {
        const float v = 2.0f * (pq.x * c[u].x + pq.y * c[u].y + pq.z * c[u].z)
                        - pq.w - c[u].w;
        unsigned uu = __float_as_uint(v);
        unsigned key = uu ^ ((unsigned)(((int)uu) >> 31) | 0x80000000u);
        unsigned run = (key & 0xFFFFFF00u) | (unsigned)(255 - (mb + u));
#pragma unroll
        for (int j = 0; j < KP; ++j) {          // branchless sorted insert
          const unsigned hi = max(qk[j], run);
          const unsigned lo = min(qk[j], run);
          qk[j] = hi; run = lo;
        }
      }
    }
#pragma unroll
    for (int j = 0; j < KP; ++j) pk[s][q][j] = qk[j];
  }
  __syncthreads();

  // ---- stage 1: exact merge of slice pairs (128 threads: q2, pr in 0..3)
  if (tid < 128) {
    const int q2 = tid & 31, pr = tid >> 5;
    const float4 pm = sp[tile * QT + q2];
    float mv[16]; int mi[16];
#pragma unroll
    for (int j = 0; j < 16; ++j) { mv[j] = -3.0e38f; mi[j] = 0; }
#pragma unroll 1
    for (int ss = 2 * pr; ss <= 2 * pr + 1; ++ss) {
      const int base = ss * SLEN;
#pragma unroll 1
      for (int j = 0; j < KP; ++j) {
        const unsigned pkd = pk[ss][q2][j];
        const int id = base + 255 - (int)(pkd & 0xFFu);
        const float4 c = sp[id];
        const float v = 2.0f * (pm.x * c.x + pm.y * c.y + pm.z * c.z) - pm.w - c.w;
        if (v > mv[15]) {
          mv[15] = v; mi[15] = id;
#pragma unroll
          for (int t = 15; t > 0; --t) {
            if (mv[t] > mv[t - 1]) {
              float tv = mv[t]; mv[t] = mv[t - 1]; mv[t - 1] = tv;
              int ti = mi[t]; mi[t] = mi[t - 1]; mi[t - 1] = ti;
            }
          }
        }
      }
    }
#pragma unroll
    for (int j = 0; j < 16; ++j) {
      s1v[pr][q2][j] = mv[j];
      s1i[pr][q2][j] = (unsigned short)mi[j];
    }
  }
  __syncthreads();

  // ---- stage 2: exact merge of 4 sorted lists (32 threads), early-break safe
  if (tid < QT) {
    float mv[16]; int mi[16];
#pragma unroll
    for (int j = 0; j < 16; ++j) { mv[j] = -3.0e38f; mi[j] = 0; }
#pragma unroll 1
    for (int pr = 0; pr < 4; ++pr) {
#pragma unroll 1
      for (int j = 0; j < 16; ++j) {
        const float v = s1v[pr][tid][j];
        if (v <= mv[15]) break;                 // exact-sorted: rest can't insert
        const int id = s1i[pr][tid][j];
        mv[15] = v; mi[15] = id;
#pragma unroll
        for (int t = 15; t > 0; --t) {
          if (mv[t] > mv[t - 1]) {
            float tv = mv[t]; mv[t] = mv[t - 1]; mv[t - 1] = tv;
            int ti = mi[t]; mi[t] = mi[t - 1]; mi[t - 1] = ti;
          }
        }
      }
    }
    const int nq = tile * QT + tid;
#pragma unroll
    for (int j = 0; j < 16; ++j) knn_idx[(size_t)(b * NN + nq) * KK + j] = mi[j];
  }
}

// ------------------------------------------- features (pts + cov) + mlp1 x3
// 512 threads: (p = tid&63, ch = tid>>6 of 8 chunks) — wave-uniform rows.
__global__ __launch_bounds__(512, 2) void mlp1_kernel(
    const float* __restrict__ pts, const int* __restrict__ knn_idx,
    const float* __restrict__ w1a, const float* __restrict__ b1a,
    const float* __restrict__ w1b, const float* __restrict__ b1b,
    const float* __restrict__ w1c, const float* __restrict__ b1c,
    float* __restrict__ f1) {
  __shared__ float h1[64][64];
  __shared__ float h2[64][64];
  const int tid = threadIdx.x;
  const int p = tid & 63;
  const int ch = tid >> 6;
  const int bn = blockIdx.x * 64 + p;
  const int b = bn >> 11;

  const int n0 = knn_idx[(size_t)bn * KK + 0];
  const int n1 = knn_idx[(size_t)bn * KK + 1];
  const float* pp = &pts[(size_t)bn * 3];
  const float* p0 = &pts[((size_t)(b << 11) + n0) * 3];
  const float* p1 = &pts[((size_t)(b << 11) + n1) * 3];
  float in[12];
  in[0] = pp[0]; in[1] = pp[1]; in[2] = pp[2];
  {
    float a0 = p0[0], a1 = p0[1], a2 = p0[2];
    float c0 = p1[0], c1 = p1[1], c2 = p1[2];
    in[3] = a0 * c0; in[4]  = a0 * c1; in[5]  = a0 * c2;
    in[6] = a1 * c0; in[7]  = a1 * c1; in[8]  = a1 * c2;
    in[9] = a2 * c0; in[10] = a2 * c1; in[11] = a2 * c2;
  }

#pragma unroll
  for (int oi = 0; oi < 8; ++oi) {
    const int o = ch * 8 + oi;
    float a = b1a[o];
#pragma unroll
    for (int c = 0; c < 12; ++c) a += w1a[o * 12 + c] * in[c];
    h1[o][p] = fmaxf(a, 0.f);
  }
  __syncthreads();

  float xr[64];
#pragma unroll
  for (int c = 0; c < 64; ++c) xr[c] = h1[c][p];
#pragma unroll 4
  for (int oi = 0; oi < 8; ++oi) {
    const int o = ch * 8 + oi;
    float a = b1b[o];
#pragma unroll
    for (int c = 0; c < 64; ++c) a += w1b[o * 64 + c] * xr[c];
    h2[o][p] = fmaxf(a, 0.f);
  }
  __syncthreads();

#pragma unroll
  for (int c = 0; c < 64; ++c) xr[c] = h2[c][p];
#pragma unroll 4
  for (int oi = 0; oi < 8; ++oi) {
    const int o = ch * 8 + oi;
    float a = b1c[o];
#pragma unroll
    for (int c = 0; c < 64; ++c) a += w1c[o * 64 + c] * xr[c];
    f1[(size_t)bn * 64 + o] = fmaxf(a, 0.f);
  }
}

// ---------------------------------------- maxpool(16) + lin1 + conv1 + relu
__global__ __launch_bounds__(512, 2) void gconv1_kernel(
    const float* __restrict__ f1, const int* __restrict__ knn_idx,
    const float* __restrict__ lin1_w, const float* __restrict__ lin1_b,
    const float* __restrict__ conv1_w, const float* __restrict__ conv1_b,
    float* __restrict__ f2) {
  __shared__ float ms[64][64];
  __shared__ float ys[64][64];
  const int tid = threadIdx.x;
  const int p = tid & 63;
  const int ch = tid >> 6;
  const int bn = blockIdx.x * 64 + p;
  const int b = bn >> 11;

  // phase 1: gather-maxpool channels [ch*8, ch*8+8)
  const int4* idr = (const int4*)&knn_idx[(size_t)bn * KK];
  int4 nb4[4];
#pragma unroll
  for (int q = 0; q < 4; ++q) nb4[q] = idr[q];
  float4 mx[2];
#pragma unroll
  for (int q = 0; q < 2; ++q) mx[q] = make_float4(-3e38f, -3e38f, -3e38f, -3e38f);
#pragma unroll
  for (int j = 0; j < KK; ++j) {
    const int nb = (j & 3) == 0 ? nb4[j >> 2].x : (j & 3) == 1 ? nb4[j >> 2].y
                 : (j & 3) == 2 ? nb4[j >> 2].z : nb4[j >> 2].w;
    const float4* v = (const float4*)&f1[((size_t)(b << 11) + nb) * 64 + ch * 8];
#pragma unroll
    for (int q = 0; q < 2; ++q) mx[q] = f4max(mx[q], v[q]);
  }
#pragma unroll
  for (int q = 0; q < 2; ++q) {
    ms[ch * 8 + q * 4 + 0][p] = mx[q].x;
    ms[ch * 8 + q * 4 + 1][p] = mx[q].y;
    ms[ch * 8 + q * 4 + 2][p] = mx[q].z;
    ms[ch * 8 + q * 4 + 3][p] = mx[q].w;
  }
  __syncthreads();

  // phase 2: lin1 (no relu), 8 outputs per thread
  float xr[64];
#pragma unroll
  for (int c = 0; c < 64; ++c) xr[c] = ms[c][p];
#pragma unroll 4
  for (int oi = 0; oi < 8; ++oi) {
    const int o = ch * 8 + oi;
    float a = lin1_b[o];
#pragma unroll
    for (int c = 0; c < 64; ++c) a += lin1_w[o * 64 + c] * xr[c];
    ys[o][p] = a;
  }
  __syncthreads();

  // phase 3: conv1 + relu, 16 outputs per thread
#pragma unroll
  for (int c = 0; c < 64; ++c) xr[c] = ys[c][p];
#pragma unroll 2
  for (int oi = 0; oi < 16; ++oi) {
    const int o = ch * 16 + oi;
    float a = conv1_b[o];
#pragma unroll
    for (int c = 0; c < 64; ++c) a += conv1_w[o * 64 + c] * xr[c];
    f2[(size_t)bn * 128 + o] = fmaxf(a, 0.f);
  }
}

// ------------------------------------------------- maxpool(16) + lin2
__global__ __launch_bounds__(512, 2) void gconv2_kernel(
    const float* __restrict__ f2, const int* __restrict__ knn_idx,
    const float* __restrict__ lin2_w, const float* __restrict__ lin2_b,
    float* __restrict__ f3) {
  __shared__ float ms[128][64];
  const int tid = threadIdx.x;
  const int p = tid & 63;
  const int ch = tid >> 6;
  const int bn = blockIdx.x * 64 + p;
  const int b = bn >> 11;

  // phase 1: gather-maxpool channels [ch*16, ch*16+16)
  const int4* idr = (const int4*)&knn_idx[(size_t)bn * KK];
  int4 nb4[4];
#pragma unroll
  for (int q = 0; q < 4; ++q) nb4[q] = idr[q];
  float4 mx[4];
#pragma unroll
  for (int q = 0; q < 4; ++q) mx[q] = make_float4(-3e38f, -3e38f, -3e38f, -3e38f);
#pragma unroll
  for (int j = 0; j < KK; ++j) {
    const int nb = (j & 3) == 0 ? nb4[j >> 2].x : (j & 3) == 1 ? nb4[j >> 2].y
                 : (j & 3) == 2 ? nb4[j >> 2].z : nb4[j >> 2].w;
    const float4* v = (const float4*)&f2[((size_t)(b << 11) + nb) * 128 + ch * 16];
#pragma unroll
    for (int q = 0; q < 4; ++q) mx[q] = f4max(mx[q], v[q]);
  }
#pragma unroll
  for (int q = 0; q < 4; ++q) {
    ms[ch * 16 + q * 4 + 0][p] = mx[q].x;
    ms[ch * 16 + q * 4 + 1][p] = mx[q].y;
    ms[ch * 16 + q * 4 + 2][p] = mx[q].z;
    ms[ch * 16 + q * 4 + 3][p] = mx[q].w;
  }
  __syncthreads();

  // phase 2: lin2 (no relu), 16 outputs per thread, x fully in regs
  float xr[128];
#pragma unroll
  for (int c = 0; c < 128; ++c) xr[c] = ms[c][p];
#pragma unroll 1
  for (int oi = 0; oi < 16; ++oi) {
    const int o = ch * 16 + oi;
    float a = lin2_b[o];
#pragma unroll
    for (int c = 0; c < 128; ++c) a += lin2_w[o * 128 + c] * xr[c];
    f3[(size_t)bn * 128 + o] = a;
  }
}

// ---------------------- conv2_w f32 -> bf16 hi/lo split (1024x128 = 131072)
__global__ __launch_bounds__(256) void wcvt_kernel(const float* __restrict__ w,
                                                   unsigned short* __restrict__ whi,
                                                   unsigned short* __restrict__ wlo) {
  const int i = blockIdx.x * 256 + threadIdx.x;
  const float x = w[i];
  const unsigned short h = f2bf(x);
  whi[i] = h;
  wlo[i] = f2bf(x - bf2f(h));
}

// ---------------- conv2 (128->1024) via bf16-split MFMA, fused global max(n)
__global__ __launch_bounds__(256, 2) void conv2max_kernel(
    const float* __restrict__ f3, const unsigned short* __restrict__ whi,
    const unsigned short* __restrict__ wlo, float* __restrict__ pmax) {
  __shared__ __align__(16) unsigned short xls[2][64][128];   // 32 KB hi|lo
  const int bi = blockIdx.x;
  const int b = bi >> 5, nc = bi & 31;
  const int tid = threadIdx.x;
  const int lane = tid & 63, wv = tid >> 6;

  // stage + split-convert 64x128 f32 -> bf16 hi/lo (swizzled 16B slots)
  {
    const int n = tid >> 2, cq = (tid & 3) * 32;
    const float4* src = (const float4*)&f3[((size_t)(b * NN + nc * 64 + n)) * 128 + cq];
    char* basep = (char*)&xls[0][0][0];
#pragma unroll
    for (int s = 0; s < 4; ++s) {
      float4 u = src[s * 2], v2 = src[s * 2 + 1];
      float xv[8] = {u.x, u.y, u.z, u.w, v2.x, v2.y, v2.z, v2.w};
      ushort8v hw, lw;
#pragma unroll
      for (int j = 0; j < 8; ++j) {
        unsigned short h = f2bf(xv[j]);
        hw[j] = h;
        lw[j] = f2bf(xv[j] - bf2f(h));
      }
      const int slot = (cq >> 3) + s;
      const int swz = slot ^ (n & 15);
      char* dst = basep + n * 256 + swz * 16;
      *(ushort8v*)dst = hw;
      *(ushort8v*)(dst + 16384) = lw;
    }
  }
  __syncthreads();

  const int g = lane >> 4, r = lane & 15;
  const char* basep = (const char*)&xls[0][0][0];
  float omax[16];
#pragma unroll
  for (int ot = 0; ot < 16; ++ot) omax[ot] = -3e38f;

#pragma unroll
  for (int mg = 0; mg < 2; ++mg) {
    bf16x8 ah[2][4], al[2][4];
#pragma unroll
    for (int m = 0; m < 2; ++m) {
      const int row = (mg * 2 + m) * 16 + r;
#pragma unroll
      for (int kt = 0; kt < 4; ++kt) {
        const int swz = (kt * 4 + g) ^ (row & 15);
        const char* p = basep + row * 256 + swz * 16;
        ah[m][kt] = *(const bf16x8*)p;
        al[m][kt] = *(const bf16x8*)(p + 16384);
      }
    }
#pragma unroll 1
    for (int ot = 0; ot < 16; ++ot) {
      const int o = wv * 256 + ot * 16 + r;
      const char* wb = (const char*)whi + (size_t)o * 256 + g * 16;
      const char* lb = (const char*)wlo + (size_t)o * 256 + g * 16;
      bf16x8 bh[4], bl[4];
#pragma unroll
      for (int kt = 0; kt < 4; ++kt) {
        bh[kt] = *(const bf16x8*)(wb + kt * 64);
        bl[kt] = *(const bf16x8*)(lb + kt * 64);
      }
      f32x4 acc0 = {0.f, 0.f, 0.f, 0.f}, acc1 = {0.f, 0.f, 0.f, 0.f};
#pragma unroll
      for (int kt = 0; kt < 4; ++kt) {
        acc0 = __builtin_amdgcn_mfma_f32_16x16x32_bf16(ah[0][kt], bh[kt], acc0, 0, 0, 0);
        acc1 = __builtin_amdgcn_mfma_f32_16x16x32_bf16(ah[1][kt], bh[kt], acc1, 0, 0, 0);
        acc0 = __builtin_amdgcn_mfma_f32_16x16x32_bf16(ah[0][kt], bl[kt], acc0, 0, 0, 0);
        acc1 = __builtin_amdgcn_mfma_f32_16x16x32_bf16(ah[1][kt], bl[kt], acc1, 0, 0, 0);
        acc0 = __builtin_amdgcn_mfma_f32_16x16x32_bf16(al[0][kt], bh[kt], acc0, 0, 0, 0);
        acc1 = __builtin_amdgcn_mfma_f32_16x16x32_bf16(al[1][kt], bh[kt], acc1, 0, 0, 0);
      }
      float mx = fmaxf(fmaxf(fmaxf(acc0[0], acc0[1]), fmaxf(acc0[2], acc0[3])),
                       fmaxf(fmaxf(acc1[0], acc1[1]), fmaxf(acc1[2], acc1[3])));
      omax[ot] = fmaxf(omax[ot], mx);
    }
  }
#pragma unroll
  for (int ot = 0; ot < 16; ++ot) {
    float v = omax[ot];
    v = fmaxf(v, __shfl_xor(v, 16, 64));
    v = fmaxf(v, __shfl_xor(v, 32, 64));
    omax[ot] = v;
  }
  if (lane < 16) {
#pragma unroll
    for (int ot = 0; ot < 16; ++ot) {
      const int o = wv * 256 + ot * 16 + lane;
      pmax[((size_t)b * 1024 + o) * 32 + nc] = omax[ot];
    }
  }
}

// ----------------------------------------- reduce partials + bias + mlp2 head
__global__ __launch_bounds__(256) void head_kernel(
    const float* __restrict__ pmax, const float* __restrict__ conv2_b,
    const float* __restrict__ w2a, const float* __restrict__ b2a,
    const float* __restrict__ w2b, const float* __restrict__ b2b,
    float* __restrict__ out) {
  const int b = blockIdx.x;
  const int tid = threadIdx.x;
  __shared__ __align__(16) float g[1024];
  __shared__ __align__(16) float h[512];
  for (int o = tid; o < 1024; o += 256) {
    const float4* p = (const float4*)&pmax[((size_t)b * 1024 + o) * 32];
    float4 a4 = p[0];
#pragma unroll
    for (int gi = 1; gi < 8; ++gi) a4 = f4max(a4, p[gi]);
    g[o] = fmaxf(fmaxf(a4.x, a4.y), fmaxf(a4.z, a4.w)) + conv2_b[o];
  }
  __syncthreads();
#pragma unroll
  for (int r = 0; r < 2; ++r) {
    const int k = r * 256 + tid;
    float a = b2a[k];
    const float4* wr = (const float4*)&w2a[(size_t)k * 1024];
    const float4* gv = (const float4*)g;
    for (int c = 0; c < 256; ++c) {
      float4 w = wr[c], xx = gv[c];
      a += w.x * xx.x + w.y * xx.y + w.z * xx.z + w.w * xx.w;
    }
    h[k] = fmaxf(a, 0.f);
  }
  __syncthreads();
#pragma unroll
  for (int r = 0; r < 2; ++r) {
    const int j = r * 256 + tid;
    float a = b2b[j];
    const float4* wr = (const float4*)&w2b[(size_t)j * 512];
    const float4* hv = (const float4*)h;
    for (int c = 0; c < 128; ++c) {
      float4 w = wr[c], xx = hv[c];
      a += w.x * xx.x + w.y * xx.y + w.z * xx.z + w.w * xx.w;
    }
    out[(size_t)b * 512 + j] = a;
  }
}

extern "C" void kernel_launch(void* const* d_in, const int* in_sizes, int n_in,
                              void* d_out, int out_size, void* d_ws, size_t ws_size,
                              hipStream_t stream) {
  const float* pts     = (const float*)d_in[0];
  const float* w1a     = (const float*)d_in[1];
  const float* b1a     = (const float*)d_in[2];
  const float* w1b     = (const float*)d_in[3];
  const float* b1b     = (const float*)d_in[4];
  const float* w1c     = (const float*)d_in[5];
  const float* b1c     = (const float*)d_in[6];
  const float* lin1_w  = (const float*)d_in[7];
  const float* lin1_b  = (const float*)d_in[8];
  const float* conv1_w = (const float*)d_in[9];
  const float* conv1_b = (const float*)d_in[10];
  const float* lin2_w  = (const float*)d_in[11];
  const float* lin2_b  = (const float*)d_in[12];
  const float* conv2_w = (const float*)d_in[13];
  const float* conv2_b = (const float*)d_in[14];
  const float* w2a     = (const float*)d_in[15];
  const float* b2a     = (const float*)d_in[16];
  const float* w2b     = (const float*)d_in[17];
  const float* b2b     = (const float*)d_in[18];

  char* ws = (char*)d_ws;
  int*   knn_idx = (int*)ws;                            // 1 MB
  float* f1 = (float*)(ws + (1u << 20));                // 4 MB   (region A)
  float* f2 = (float*)(ws + (9u << 20));                // 8 MB   (region B)
  float* f3 = (float*)(ws + (1u << 20));                // 8 MB   (region A reuse)
  unsigned short* whi = (unsigned short*)(ws + (17u << 20));              // 256 KB
  unsigned short* wlo = (unsigned short*)(ws + (17u << 20) + (1u << 18)); // 256 KB
  float* pm = (float*)(ws + (17u << 20) + (2u << 18));  // 1 MB

  wcvt_kernel  <<<512, 256, 0, stream>>>(conv2_w, whi, wlo);
  knn_kernel   <<<512, 256, 0, stream>>>(pts, knn_idx);
  mlp1_kernel  <<<256, 512, 0, stream>>>(pts, knn_idx, w1a, b1a, w1b, b1b, w1c, b1c, f1);
  gconv1_kernel<<<256, 512, 0, stream>>>(f1, knn_idx, lin1_w, lin1_b, conv1_w, conv1_b, f2);
  gconv2_kernel<<<256, 512, 0, stream>>>(f2, knn_idx, lin2_w, lin2_b, f3);
  conv2max_kernel<<<256, 256, 0, stream>>>(f3, whi, wlo, pm);
  head_kernel  <<<8, 256, 0, stream>>>(pm, conv2_b, w2a, b2a, w2b, b2b, (float*)d_out);
}

// Round 6
// 372.774 us; speedup vs baseline: 3.3826x; 1.0139x over previous
//
#include <hip/hip_runtime.h>

#define BB 8
#define NN 2048
#define KK 16
#define QT 32      // kNN queries per block
#define NSLICE 8
#define SLEN 256   // NN / NSLICE
#define KP 18      // packed keep-depth per slice (pool safety margin)

typedef short bf16x8 __attribute__((ext_vector_type(8)));
typedef float f32x4 __attribute__((ext_vector_type(4)));
typedef unsigned short ushort8v __attribute__((ext_vector_type(8)));

__device__ __forceinline__ float4 f4max(float4 a, float4 b) {
  return make_float4(fmaxf(a.x, b.x), fmaxf(a.y, b.y), fmaxf(a.z, b.z), fmaxf(a.w, b.w));
}

__device__ __forceinline__ unsigned short f2bf(float x) {  // f32 -> bf16 bits, RNE
  union { float f; unsigned u; } v; v.f = x;
  unsigned r = v.u + 0x7fffu + ((v.u >> 16) & 1u);
  return (unsigned short)(r >> 16);
}
__device__ __forceinline__ float bf2f(unsigned short h) {
  union { unsigned u; float f; } v; v.u = ((unsigned)h) << 16;
  return v.f;
}

// NOTE batch->XCD swizzle everywhere: batch = blockIdx & 7 so all blocks of a
// batch land on one XCD (round-robin dispatch) -> per-XCD gather working set
// ~1 MB, L2-resident (was 8 MB across 8 batches -> 92 MB HBM thrash).

// ---------------------------------------------------------------- kNN top-16
__global__ __launch_bounds__(256) void knn_kernel(const float* __restrict__ pts,
                                                  int* __restrict__ knn_idx) {
  __shared__ float4 sp[NN];                         // 32 KB (x,y,z,|p|^2)
  __shared__ unsigned pk[NSLICE][QT][KP];           // 18 KB packed lists
  __shared__ float          s1v[4][QT][16];         // 8 KB stage-1 vals
  __shared__ unsigned short s1i[4][QT][16];         // 4 KB stage-1 ids
  const int b = blockIdx.x & 7;
  const int tile = blockIdx.x >> 3;
  const int tid = threadIdx.x;
  const int q = tid & 31;
  const int s = tid >> 5;

  for (int i = tid; i < NN; i += 256) {
    float x = pts[(size_t)(b * NN + i) * 3 + 0];
    float y = pts[(size_t)(b * NN + i) * 3 + 1];
    float z = pts[(size_t)(b * NN + i) * 3 + 2];
    sp[i] = make_float4(x, y, z, x * x + y * y + z * z);
  }
  __syncthreads();

  // ---- packed scan of slice s for query q
  {
    const float4 pq = sp[tile * QT + q];
    unsigned qk[KP];
#pragma unroll
    for (int j = 0; j < KP; ++j) qk[j] = 0u;
    const int m0 = s * SLEN;
    for (int mb = 0; mb < SLEN; mb += 8) {
      float4 c[8];
#pragma unroll
      for (int u = 0; u < 8; ++u) c[u] = sp[m0 + mb + u];
#pragma unroll
      for (int u = 0; u < 8; ++u) {
        const float v = 2.0f * (pq.x * c[u].x + pq.y * c[u].y + pq.z * c[u].z)
                        - pq.w - c[u].w;
        unsigned uu = __float_as_uint(v);
        unsigned key = uu ^ ((unsigned)(((int)uu) >> 31) | 0x80000000u);
        unsigned run = (key & 0xFFFFFF00u) | (unsigned)(255 - (mb + u));
#pragma unroll
        for (int j = 0; j < KP; ++j) {          // branchless sorted insert
          const unsigned hi = max(qk[j], run);
          const unsigned lo = min(qk[j], run);
          qk[j] = hi; run = lo;
        }
      }
    }
#pragma unroll
    for (int j = 0; j < KP; ++j) pk[s][q][j] = qk[j];
  }
  __syncthreads();

  // ---- stage 1: exact merge of slice pairs (128 threads: q2, pr in 0..3)
  if (tid < 128) {
    const int q2 = tid & 31, pr = tid >> 5;
    const float4 pm = sp[tile * QT + q2];
    float mv[16]; int mi[16];
#pragma unroll
    for (int j = 0; j < 16; ++j) { mv[j] = -3.0e38f; mi[j] = 0; }
#pragma unroll 1
    for (int ss = 2 * pr; ss <= 2 * pr + 1; ++ss) {
      const int base = ss * SLEN;
#pragma unroll 1
      for (int j = 0; j < KP; ++j) {
        const unsigned pkd = pk[ss][q2][j];
        const int id = base + 255 - (int)(pkd & 0xFFu);
        const float4 c = sp[id];
        const float v = 2.0f * (pm.x * c.x + pm.y * c.y + pm.z * c.z) - pm.w - c.w;
        if (v > mv[15]) {
          mv[15] = v; mi[15] = id;
#pragma unroll
          for (int t = 15; t > 0; --t) {
            if (mv[t] > mv[t - 1]) {
              float tv = mv[t]; mv[t] = mv[t - 1]; mv[t - 1] = tv;
              int ti = mi[t]; mi[t] = mi[t - 1]; mi[t - 1] = ti;
            }
          }
        }
      }
    }
#pragma unroll
    for (int j = 0; j < 16; ++j) {
      s1v[pr][q2][j] = mv[j];
      s1i[pr][q2][j] = (unsigned short)mi[j];
    }
  }
  __syncthreads();

  // ---- stage 2: exact merge of 4 sorted lists (32 threads), early-break safe
  if (tid < QT) {
    float mv[16]; int mi[16];
#pragma unroll
    for (int j = 0; j < 16; ++j) { mv[j] = -3.0e38f; mi[j] = 0; }
#pragma unroll 1
    for (int pr = 0; pr < 4; ++pr) {
#pragma unroll 1
      for (int j = 0; j < 16; ++j) {
        const float v = s1v[pr][tid][j];
        if (v <= mv[15]) break;                 // exact-sorted: rest can't insert
        const int id = s1i[pr][tid][j];
        mv[15] = v; mi[15] = id;
#pragma unroll
        for (int t = 15; t > 0; --t) {
          if (mv[t] > mv[t - 1]) {
            float tv = mv[t]; mv[t] = mv[t - 1]; mv[t - 1] = tv;
            int ti = mi[t]; mi[t] = mi[t - 1]; mi[t - 1] = ti;
          }
        }
      }
    }
    const int nq = tile * QT + tid;
#pragma unroll
    for (int j = 0; j < 16; ++j) knn_idx[(size_t)(b * NN + nq) * KK + j] = mi[j];
  }
}

// ------------------------------------------- features (pts + cov) + mlp1 x3
__global__ __launch_bounds__(512, 2) void mlp1_kernel(
    const float* __restrict__ pts, const int* __restrict__ knn_idx,
    const float* __restrict__ w1a, const float* __restrict__ b1a,
    const float* __restrict__ w1b, const float* __restrict__ b1b,
    const float* __restrict__ w1c, const float* __restrict__ b1c,
    float* __restrict__ f1) {
  __shared__ float h1[64][64];
  __shared__ float h2[64][64];
  const int tid = threadIdx.x;
  const int p = tid & 63;
  const int ch = tid >> 6;
  const int b = blockIdx.x & 7;
  const int nc = blockIdx.x >> 3;
  const int bn = b * NN + nc * 64 + p;

  const int n0 = knn_idx[(size_t)bn * KK + 0];
  const int n1 = knn_idx[(size_t)bn * KK + 1];
  const float* pp = &pts[(size_t)bn * 3];
  const float* p0 = &pts[((size_t)(b << 11) + n0) * 3];
  const float* p1 = &pts[((size_t)(b << 11) + n1) * 3];
  float in[12];
  in[0] = pp[0]; in[1] = pp[1]; in[2] = pp[2];
  {
    float a0 = p0[0], a1 = p0[1], a2 = p0[2];
    float c0 = p1[0], c1 = p1[1], c2 = p1[2];
    in[3] = a0 * c0; in[4]  = a0 * c1; in[5]  = a0 * c2;
    in[6] = a1 * c0; in[7]  = a1 * c1; in[8]  = a1 * c2;
    in[9] = a2 * c0; in[10] = a2 * c1; in[11] = a2 * c2;
  }

#pragma unroll
  for (int oi = 0; oi < 8; ++oi) {
    const int o = ch * 8 + oi;
    float a = b1a[o];
#pragma unroll
    for (int c = 0; c < 12; ++c) a += w1a[o * 12 + c] * in[c];
    h1[o][p] = fmaxf(a, 0.f);
  }
  __syncthreads();

  float xr[64];
#pragma unroll
  for (int c = 0; c < 64; ++c) xr[c] = h1[c][p];
#pragma unroll 4
  for (int oi = 0; oi < 8; ++oi) {
    const int o = ch * 8 + oi;
    float a = b1b[o];
#pragma unroll
    for (int c = 0; c < 64; ++c) a += w1b[o * 64 + c] * xr[c];
    h2[o][p] = fmaxf(a, 0.f);
  }
  __syncthreads();

#pragma unroll
  for (int c = 0; c < 64; ++c) xr[c] = h2[c][p];
#pragma unroll 4
  for (int oi = 0; oi < 8; ++oi) {
    const int o = ch * 8 + oi;
    float a = b1c[o];
#pragma unroll
    for (int c = 0; c < 64; ++c) a += w1c[o * 64 + c] * xr[c];
    f1[(size_t)bn * 64 + o] = fmaxf(a, 0.f);
  }
}

// ---------------------------------------- maxpool(16) + lin1 + conv1 + relu
__global__ __launch_bounds__(512, 2) void gconv1_kernel(
    const float* __restrict__ f1, const int* __restrict__ knn_idx,
    const float* __restrict__ lin1_w, const float* __restrict__ lin1_b,
    const float* __restrict__ conv1_w, const float* __restrict__ conv1_b,
    float* __restrict__ f2) {
  __shared__ float ms[64][64];
  __shared__ float ys[64][64];
  const int tid = threadIdx.x;
  const int p = tid & 63;
  const int ch = tid >> 6;
  const int b = blockIdx.x & 7;
  const int nc = blockIdx.x >> 3;
  const int bn = b * NN + nc * 64 + p;

  // phase 1: gather-maxpool channels [ch*8, ch*8+8)
  const int4* idr = (const int4*)&knn_idx[(size_t)bn * KK];
  int4 nb4[4];
#pragma unroll
  for (int q = 0; q < 4; ++q) nb4[q] = idr[q];
  float4 mx[2];
#pragma unroll
  for (int q = 0; q < 2; ++q) mx[q] = make_float4(-3e38f, -3e38f, -3e38f, -3e38f);
#pragma unroll
  for (int j = 0; j < KK; ++j) {
    const int nb = (j & 3) == 0 ? nb4[j >> 2].x : (j & 3) == 1 ? nb4[j >> 2].y
                 : (j & 3) == 2 ? nb4[j >> 2].z : nb4[j >> 2].w;
    const float4* v = (const float4*)&f1[((size_t)(b << 11) + nb) * 64 + ch * 8];
#pragma unroll
    for (int q = 0; q < 2; ++q) mx[q] = f4max(mx[q], v[q]);
  }
#pragma unroll
  for (int q = 0; q < 2; ++q) {
    ms[ch * 8 + q * 4 + 0][p] = mx[q].x;
    ms[ch * 8 + q * 4 + 1][p] = mx[q].y;
    ms[ch * 8 + q * 4 + 2][p] = mx[q].z;
    ms[ch * 8 + q * 4 + 3][p] = mx[q].w;
  }
  __syncthreads();

  // phase 2: lin1 (no relu), 8 outputs per thread
  float xr[64];
#pragma unroll
  for (int c = 0; c < 64; ++c) xr[c] = ms[c][p];
#pragma unroll 4
  for (int oi = 0; oi < 8; ++oi) {
    const int o = ch * 8 + oi;
    float a = lin1_b[o];
#pragma unroll
    for (int c = 0; c < 64; ++c) a += lin1_w[o * 64 + c] * xr[c];
    ys[o][p] = a;
  }
  __syncthreads();

  // phase 3: conv1 + relu, 16 outputs per thread
#pragma unroll
  for (int c = 0; c < 64; ++c) xr[c] = ys[c][p];
#pragma unroll 2
  for (int oi = 0; oi < 16; ++oi) {
    const int o = ch * 16 + oi;
    float a = conv1_b[o];
#pragma unroll
    for (int c = 0; c < 64; ++c) a += conv1_w[o * 64 + c] * xr[c];
    f2[(size_t)bn * 128 + o] = fmaxf(a, 0.f);
  }
}

// ------------------------------------------------- maxpool(16) + lin2
__global__ __launch_bounds__(512, 2) void gconv2_kernel(
    const float* __restrict__ f2, const int* __restrict__ knn_idx,
    const float* __restrict__ lin2_w, const float* __restrict__ lin2_b,
    float* __restrict__ f3) {
  __shared__ float ms[128][64];
  const int tid = threadIdx.x;
  const int p = tid & 63;
  const int ch = tid >> 6;
  const int b = blockIdx.x & 7;
  const int nc = blockIdx.x >> 3;
  const int bn = b * NN + nc * 64 + p;

  // phase 1: gather-maxpool channels [ch*16, ch*16+16)
  const int4* idr = (const int4*)&knn_idx[(size_t)bn * KK];
  int4 nb4[4];
#pragma unroll
  for (int q = 0; q < 4; ++q) nb4[q] = idr[q];
  float4 mx[4];
#pragma unroll
  for (int q = 0; q < 4; ++q) mx[q] = make_float4(-3e38f, -3e38f, -3e38f, -3e38f);
#pragma unroll
  for (int j = 0; j < KK; ++j) {
    const int nb = (j & 3) == 0 ? nb4[j >> 2].x : (j & 3) == 1 ? nb4[j >> 2].y
                 : (j & 3) == 2 ? nb4[j >> 2].z : nb4[j >> 2].w;
    const float4* v = (const float4*)&f2[((size_t)(b << 11) + nb) * 128 + ch * 16];
#pragma unroll
    for (int q = 0; q < 4; ++q) mx[q] = f4max(mx[q], v[q]);
  }
#pragma unroll
  for (int q = 0; q < 4; ++q) {
    ms[ch * 16 + q * 4 + 0][p] = mx[q].x;
    ms[ch * 16 + q * 4 + 1][p] = mx[q].y;
    ms[ch * 16 + q * 4 + 2][p] = mx[q].z;
    ms[ch * 16 + q * 4 + 3][p] = mx[q].w;
  }
  __syncthreads();

  // phase 2: lin2 (no relu), 16 outputs per thread, x fully in regs
  float xr[128];
#pragma unroll
  for (int c = 0; c < 128; ++c) xr[c] = ms[c][p];
#pragma unroll 1
  for (int oi = 0; oi < 16; ++oi) {
    const int o = ch * 16 + oi;
    float a = lin2_b[o];
#pragma unroll
    for (int c = 0; c < 128; ++c) a += lin2_w[o * 128 + c] * xr[c];
    f3[(size_t)bn * 128 + o] = a;
  }
}

// ---------------------- conv2_w f32 -> bf16 hi/lo split (1024x128 = 131072)
__global__ __launch_bounds__(256) void wcvt_kernel(const float* __restrict__ w,
                                                   unsigned short* __restrict__ whi,
                                                   unsigned short* __restrict__ wlo) {
  const int i = blockIdx.x * 256 + threadIdx.x;
  const float x = w[i];
  const unsigned short h = f2bf(x);
  whi[i] = h;
  wlo[i] = f2bf(x - bf2f(h));
}

// ---------------- conv2 (128->1024) via bf16-split MFMA, fused global max(n)
__global__ __launch_bounds__(256, 2) void conv2max_kernel(
    const float* __restrict__ f3, const unsigned short* __restrict__ whi,
    const unsigned short* __restrict__ wlo, float* __restrict__ pmax) {
  __shared__ __align__(16) unsigned short xls[2][64][128];   // 32 KB hi|lo
  const int bi = blockIdx.x;
  const int b = bi & 7, nc = bi >> 3;
  const int tid = threadIdx.x;
  const int lane = tid & 63, wv = tid >> 6;

  // stage + split-convert 64x128 f32 -> bf16 hi/lo (swizzled 16B slots)
  {
    const int n = tid >> 2, cq = (tid & 3) * 32;
    const float4* src = (const float4*)&f3[((size_t)(b * NN + nc * 64 + n)) * 128 + cq];
    char* basep = (char*)&xls[0][0][0];
#pragma unroll
    for (int s = 0; s < 4; ++s) {
      float4 u = src[s * 2], v2 = src[s * 2 + 1];
      float xv[8] = {u.x, u.y, u.z, u.w, v2.x, v2.y, v2.z, v2.w};
      ushort8v hw, lw;
#pragma unroll
      for (int j = 0; j < 8; ++j) {
        unsigned short h = f2bf(xv[j]);
        hw[j] = h;
        lw[j] = f2bf(xv[j] - bf2f(h));
      }
      const int slot = (cq >> 3) + s;
      const int swz = slot ^ (n & 15);
      char* dst = basep + n * 256 + swz * 16;
      *(ushort8v*)dst = hw;
      *(ushort8v*)(dst + 16384) = lw;
    }
  }
  __syncthreads();

  const int g = lane >> 4, r = lane & 15;
  const char* basep = (const char*)&xls[0][0][0];
  float omax[16];
#pragma unroll
  for (int ot = 0; ot < 16; ++ot) omax[ot] = -3e38f;

#pragma unroll
  for (int mg = 0; mg < 2; ++mg) {
    bf16x8 ah[2][4], al[2][4];
#pragma unroll
    for (int m = 0; m < 2; ++m) {
      const int row = (mg * 2 + m) * 16 + r;
#pragma unroll
      for (int kt = 0; kt < 4; ++kt) {
        const int swz = (kt * 4 + g) ^ (row & 15);
        const char* p = basep + row * 256 + swz * 16;
        ah[m][kt] = *(const bf16x8*)p;
        al[m][kt] = *(const bf16x8*)(p + 16384);
      }
    }
#pragma unroll 1
    for (int ot = 0; ot < 16; ++ot) {
      const int o = wv * 256 + ot * 16 + r;
      const char* wb = (const char*)whi + (size_t)o * 256 + g * 16;
      const char* lb = (const char*)wlo + (size_t)o * 256 + g * 16;
      bf16x8 bh[4], bl[4];
#pragma unroll
      for (int kt = 0; kt < 4; ++kt) {
        bh[kt] = *(const bf16x8*)(wb + kt * 64);
        bl[kt] = *(const bf16x8*)(lb + kt * 64);
      }
      f32x4 acc0 = {0.f, 0.f, 0.f, 0.f}, acc1 = {0.f, 0.f, 0.f, 0.f};
#pragma unroll
      for (int kt = 0; kt < 4; ++kt) {
        acc0 = __builtin_amdgcn_mfma_f32_16x16x32_bf16(ah[0][kt], bh[kt], acc0, 0, 0, 0);
        acc1 = __builtin_amdgcn_mfma_f32_16x16x32_bf16(ah[1][kt], bh[kt], acc1, 0, 0, 0);
        acc0 = __builtin_amdgcn_mfma_f32_16x16x32_bf16(ah[0][kt], bl[kt], acc0, 0, 0, 0);
        acc1 = __builtin_amdgcn_mfma_f32_16x16x32_bf16(ah[1][kt], bl[kt], acc1, 0, 0, 0);
        acc0 = __builtin_amdgcn_mfma_f32_16x16x32_bf16(al[0][kt], bh[kt], acc0, 0, 0, 0);
        acc1 = __builtin_amdgcn_mfma_f32_16x16x32_bf16(al[1][kt], bh[kt], acc1, 0, 0, 0);
      }
      float mx = fmaxf(fmaxf(fmaxf(acc0[0], acc0[1]), fmaxf(acc0[2], acc0[3])),
                       fmaxf(fmaxf(acc1[0], acc1[1]), fmaxf(acc1[2], acc1[3])));
      omax[ot] = fmaxf(omax[ot], mx);
    }
  }
#pragma unroll
  for (int ot = 0; ot < 16; ++ot) {
    float v = omax[ot];
    v = fmaxf(v, __shfl_xor(v, 16, 64));
    v = fmaxf(v, __shfl_xor(v, 32, 64));
    omax[ot] = v;
  }
  if (lane < 16) {
#pragma unroll
    for (int ot = 0; ot < 16; ++ot) {
      const int o = wv * 256 + ot * 16 + lane;
      pmax[((size_t)b * 1024 + o) * 32 + nc] = omax[ot];
    }
  }
}

// ----------------------------------------- reduce partials + bias + mlp2 head
__global__ __launch_bounds__(256) void head_kernel(
    const float* __restrict__ pmax, const float* __restrict__ conv2_b,
    const float* __restrict__ w2a, const float* __restrict__ b2a,
    const float* __restrict__ w2b, const float* __restrict__ b2b,
    float* __restrict__ out) {
  const int b = blockIdx.x;
  const int tid = threadIdx.x;
  __shared__ __align__(16) float g[1024];
  __shared__ __align__(16) float h[512];
  for (int o = tid; o < 1024; o += 256) {
    const float4* p = (const float4*)&pmax[((size_t)b * 1024 + o) * 32];
    float4 a4 = p[0];
#pragma unroll
    for (int gi = 1; gi < 8; ++gi) a4 = f4max(a4, p[gi]);
    g[o] = fmaxf(fmaxf(a4.x, a4.y), fmaxf(a4.z, a4.w)) + conv2_b[o];
  }
  __syncthreads();
#pragma unroll
  for (int r = 0; r < 2; ++r) {
    const int k = r * 256 + tid;
    float a = b2a[k];
    const float4* wr = (const float4*)&w2a[(size_t)k * 1024];
    const float4* gv = (const float4*)g;
    for (int c = 0; c < 256; ++c) {
      float4 w = wr[c], xx = gv[c];
      a += w.x * xx.x + w.y * xx.y + w.z * xx.z + w.w * xx.w;
    }
    h[k] = fmaxf(a, 0.f);
  }
  __syncthreads();
#pragma unroll
  for (int r = 0; r < 2; ++r) {
    const int j = r * 256 + tid;
    float a = b2b[j];
    const float4* wr = (const float4*)&w2b[(size_t)j * 512];
    const float4* hv = (const float4*)h;
    for (int c = 0; c < 128; ++c) {
      float4 w = wr[c], xx = hv[c];
      a += w.x * xx.x + w.y * xx.y + w.z * xx.z + w.w * xx.w;
    }
    out[(size_t)b * 512 + j] = a;
  }
}

extern "C" void kernel_launch(void* const* d_in, const int* in_sizes, int n_in,
                              void* d_out, int out_size, void* d_ws, size_t ws_size,
                              hipStream_t stream) {
  const float* pts     = (const float*)d_in[0];
  const float* w1a     = (const float*)d_in[1];
  const float* b1a     = (const float*)d_in[2];
  const float* w1b     = (const float*)d_in[3];
  const float* b1b     = (const float*)d_in[4];
  const float* w1c     = (const float*)d_in[5];
  const float* b1c     = (const float*)d_in[6];
  const float* lin1_w  = (const float*)d_in[7];
  const float* lin1_b  = (const float*)d_in[8];
  const float* conv1_w = (const float*)d_in[9];
  const float* conv1_b = (const float*)d_in[10];
  const float* lin2_w  = (const float*)d_in[11];
  const float* lin2_b  = (const float*)d_in[12];
  const float* conv2_w = (const float*)d_in[13];
  const float* conv2_b = (const float*)d_in[14];
  const float* w2a     = (const float*)d_in[15];
  const float* b2a     = (const float*)d_in[16];
  const float* w2b     = (const float*)d_in[17];
  const float* b2b     = (const float*)d_in[18];

  char* ws = (char*)d_ws;
  int*   knn_idx = (int*)ws;                            // 1 MB
  float* f1 = (float*)(ws + (1u << 20));                // 4 MB   (region A)
  float* f2 = (float*)(ws + (9u << 20));                // 8 MB   (region B)
  float* f3 = (float*)(ws + (1u << 20));                // 8 MB   (region A reuse)
  unsigned short* whi = (unsigned short*)(ws + (17u << 20));              // 256 KB
  unsigned short* wlo = (unsigned short*)(ws + (17u << 20) + (1u << 18)); // 256 KB
  float* pm = (float*)(ws + (17u << 20) + (2u << 18));  // 1 MB

  wcvt_kernel  <<<512, 256, 0, stream>>>(conv2_w, whi, wlo);
  knn_kernel   <<<512, 256, 0, stream>>>(pts, knn_idx);
  mlp1_kernel  <<<256, 512, 0, stream>>>(pts, knn_idx, w1a, b1a, w1b, b1b, w1c, b1c, f1);
  gconv1_kernel<<<256, 512, 0, stream>>>(f1, knn_idx, lin1_w, lin1_b, conv1_w, conv1_b, f2);
  gconv2_kernel<<<256, 512, 0, stream>>>(f2, knn_idx, lin2_w, lin2_b, f3);
  conv2max_kernel<<<256, 256, 0, stream>>>(f3, whi, wlo, pm);
  head_kernel  <<<8, 256, 0, stream>>>(pm, conv2_b, w2a, b2a, w2b, b2b, (float*)d_out);
}

// Round 7
// 362.168 us; speedup vs baseline: 3.4817x; 1.0293x over previous
//
#include <hip/hip_runtime.h>

#define BB 8
#define NN 2048
#define KK 16
#define QT 32      // kNN queries per block
#define NSLICE 8
#define SLEN 256   // NN / NSLICE
#define KP 18      // packed keep-depth per slice (pool safety margin)

typedef short bf16x8 __attribute__((ext_vector_type(8)));
typedef float f32x4 __attribute__((ext_vector_type(4)));
typedef unsigned short ushort8v __attribute__((ext_vector_type(8)));

__device__ __forceinline__ float4 f4max(float4 a, float4 b) {
  return make_float4(fmaxf(a.x, b.x), fmaxf(a.y, b.y), fmaxf(a.z, b.z), fmaxf(a.w, b.w));
}

__device__ __forceinline__ unsigned short f2bf(float x) {  // f32 -> bf16 bits, RNE
  union { float f; unsigned u; } v; v.f = x;
  unsigned r = v.u + 0x7fffu + ((v.u >> 16) & 1u);
  return (unsigned short)(r >> 16);
}
__device__ __forceinline__ float bf2f(unsigned short h) {
  union { unsigned u; float f; } v; v.u = ((unsigned)h) << 16;
  return v.f;
}

// ---------------------------------------------------------------- kNN top-16
__global__ __launch_bounds__(256) void knn_kernel(const float* __restrict__ pts,
                                                  int* __restrict__ knn_idx) {
  __shared__ float4 sp[NN];                         // 32 KB (x,y,z,|p|^2)
  __shared__ unsigned pk[NSLICE][QT][KP];           // 18 KB packed lists
  __shared__ float          s1v[4][QT][16];         // 8 KB stage-1 vals
  __shared__ unsigned short s1i[4][QT][16];         // 4 KB stage-1 ids
  const int b = blockIdx.x & 7;
  const int tile = blockIdx.x >> 3;
  const int tid = threadIdx.x;
  const int q = tid & 31;
  const int s = tid >> 5;

  for (int i = tid; i < NN; i += 256) {
    float x = pts[(size_t)(b * NN + i) * 3 + 0];
    float y = pts[(size_t)(b * NN + i) * 3 + 1];
    float z = pts[(size_t)(b * NN + i) * 3 + 2];
    sp[i] = make_float4(x, y, z, x * x + y * y + z * z);
  }
  __syncthreads();

  // ---- packed scan of slice s for query q
  {
    const float4 pq = sp[tile * QT + q];
    unsigned qk[KP];
#pragma unroll
    for (int j = 0; j < KP; ++j) qk[j] = 0u;
    const int m0 = s * SLEN;
    for (int mb = 0; mb < SLEN; mb += 8) {
      float4 c[8];
#pragma unroll
      for (int u = 0; u < 8; ++u) c[u] = sp[m0 + mb + u];
#pragma unroll
      for (int u = 0; u < 8; ++u) {
        const float v = 2.0f * (pq.x * c[u].x + pq.y * c[u].y + pq.z * c[u].z)
                        - pq.w - c[u].w;
        unsigned uu = __float_as_uint(v);
        unsigned key = uu ^ ((unsigned)(((int)uu) >> 31) | 0x80000000u);
        unsigned run = (key & 0xFFFFFF00u) | (unsigned)(255 - (mb + u));
#pragma unroll
        for (int j = 0; j < KP; ++j) {          // branchless sorted insert
          const unsigned hi = max(qk[j], run);
          const unsigned lo = min(qk[j], run);
          qk[j] = hi; run = lo;
        }
      }
    }
#pragma unroll
    for (int j = 0; j < KP; ++j) pk[s][q][j] = qk[j];
  }
  __syncthreads();

  // ---- stage 1: exact merge of slice pairs (128 threads: q2, pr in 0..3)
  if (tid < 128) {
    const int q2 = tid & 31, pr = tid >> 5;
    const float4 pm = sp[tile * QT + q2];
    float mv[16]; int mi[16];
#pragma unroll
    for (int j = 0; j < 16; ++j) { mv[j] = -3.0e38f; mi[j] = 0; }
#pragma unroll 1
    for (int ss = 2 * pr; ss <= 2 * pr + 1; ++ss) {
      const int base = ss * SLEN;
#pragma unroll 1
      for (int j = 0; j < KP; ++j) {
        const unsigned pkd = pk[ss][q2][j];
        const int id = base + 255 - (int)(pkd & 0xFFu);
        const float4 c = sp[id];
        const float v = 2.0f * (pm.x * c.x + pm.y * c.y + pm.z * c.z) - pm.w - c.w;
        if (v > mv[15]) {
          mv[15] = v; mi[15] = id;
#pragma unroll
          for (int t = 15; t > 0; --t) {
            if (mv[t] > mv[t - 1]) {
              float tv = mv[t]; mv[t] = mv[t - 1]; mv[t - 1] = tv;
              int ti = mi[t]; mi[t] = mi[t - 1]; mi[t - 1] = ti;
            }
          }
        }
      }
    }
#pragma unroll
    for (int j = 0; j < 16; ++j) {
      s1v[pr][q2][j] = mv[j];
      s1i[pr][q2][j] = (unsigned short)mi[j];
    }
  }
  __syncthreads();

  // ---- stage 2: exact merge of 4 sorted lists (32 threads), early-break safe
  if (tid < QT) {
    float mv[16]; int mi[16];
#pragma unroll
    for (int j = 0; j < 16; ++j) { mv[j] = -3.0e38f; mi[j] = 0; }
#pragma unroll 1
    for (int pr = 0; pr < 4; ++pr) {
#pragma unroll 1
      for (int j = 0; j < 16; ++j) {
        const float v = s1v[pr][tid][j];
        if (v <= mv[15]) break;                 // exact-sorted: rest can't insert
        const int id = s1i[pr][tid][j];
        mv[15] = v; mi[15] = id;
#pragma unroll
        for (int t = 15; t > 0; --t) {
          if (mv[t] > mv[t - 1]) {
            float tv = mv[t]; mv[t] = mv[t - 1]; mv[t - 1] = tv;
            int ti = mi[t]; mi[t] = mi[t - 1]; mi[t - 1] = ti;
          }
        }
      }
    }
    const int nq = tile * QT + tid;
#pragma unroll
    for (int j = 0; j < 16; ++j) knn_idx[(size_t)(b * NN + nq) * KK + j] = mi[j];
  }
}

// ------------------------------------------- features (pts + cov) + mlp1 x3
// chunked-register accumulation: acc[8] live, input streamed via xr[32]
// (no big per-thread arrays -> no scratch spill; weights s_load'd).
__global__ __launch_bounds__(512, 2) void mlp1_kernel(
    const float* __restrict__ pts, const int* __restrict__ knn_idx,
    const float* __restrict__ w1a, const float* __restrict__ b1a,
    const float* __restrict__ w1b, const float* __restrict__ b1b,
    const float* __restrict__ w1c, const float* __restrict__ b1c,
    float* __restrict__ f1) {
  __shared__ float h1[64][64];
  __shared__ float h2[64][64];
  const int tid = threadIdx.x;
  const int p = tid & 63;
  const int ch = tid >> 6;
  const int b = blockIdx.x & 7;
  const int nc = blockIdx.x >> 3;
  const int bn = b * NN + nc * 64 + p;

  const int n0 = knn_idx[(size_t)bn * KK + 0];
  const int n1 = knn_idx[(size_t)bn * KK + 1];
  const float* pp = &pts[(size_t)bn * 3];
  const float* p0 = &pts[((size_t)(b << 11) + n0) * 3];
  const float* p1 = &pts[((size_t)(b << 11) + n1) * 3];
  float in[12];
  in[0] = pp[0]; in[1] = pp[1]; in[2] = pp[2];
  {
    float a0 = p0[0], a1 = p0[1], a2 = p0[2];
    float c0 = p1[0], c1 = p1[1], c2 = p1[2];
    in[3] = a0 * c0; in[4]  = a0 * c1; in[5]  = a0 * c2;
    in[6] = a1 * c0; in[7]  = a1 * c1; in[8]  = a1 * c2;
    in[9] = a2 * c0; in[10] = a2 * c1; in[11] = a2 * c2;
  }

#pragma unroll
  for (int oi = 0; oi < 8; ++oi) {
    const int o = ch * 8 + oi;
    float a = b1a[o];
#pragma unroll
    for (int c = 0; c < 12; ++c) a += w1a[o * 12 + c] * in[c];
    h1[o][p] = fmaxf(a, 0.f);
  }
  __syncthreads();

  {
    float acc[8];
#pragma unroll
    for (int oi = 0; oi < 8; ++oi) acc[oi] = b1b[ch * 8 + oi];
#pragma unroll
    for (int cc = 0; cc < 64; cc += 32) {
      float xr[32];
#pragma unroll
      for (int c = 0; c < 32; ++c) xr[c] = h1[cc + c][p];
#pragma unroll
      for (int oi = 0; oi < 8; ++oi) {
        const int o = ch * 8 + oi;
#pragma unroll
        for (int c = 0; c < 32; ++c) acc[oi] += w1b[o * 64 + cc + c] * xr[c];
      }
    }
    __syncthreads();   // h1 consumed by all before h2 writes (h1/h2 distinct; safe order)
#pragma unroll
    for (int oi = 0; oi < 8; ++oi) h2[ch * 8 + oi][p] = fmaxf(acc[oi], 0.f);
  }
  __syncthreads();

  {
    float acc[8];
#pragma unroll
    for (int oi = 0; oi < 8; ++oi) acc[oi] = b1c[ch * 8 + oi];
#pragma unroll
    for (int cc = 0; cc < 64; cc += 32) {
      float xr[32];
#pragma unroll
      for (int c = 0; c < 32; ++c) xr[c] = h2[cc + c][p];
#pragma unroll
      for (int oi = 0; oi < 8; ++oi) {
        const int o = ch * 8 + oi;
#pragma unroll
        for (int c = 0; c < 32; ++c) acc[oi] += w1c[o * 64 + cc + c] * xr[c];
      }
    }
#pragma unroll
    for (int oi = 0; oi < 8; ++oi)
      f1[(size_t)bn * 64 + ch * 8 + oi] = fmaxf(acc[oi], 0.f);
  }
}

// ---------------------------------------- maxpool(16) + lin1 + conv1 + relu
__global__ __launch_bounds__(512, 2) void gconv1_kernel(
    const float* __restrict__ f1, const int* __restrict__ knn_idx,
    const float* __restrict__ lin1_w, const float* __restrict__ lin1_b,
    const float* __restrict__ conv1_w, const float* __restrict__ conv1_b,
    float* __restrict__ f2) {
  __shared__ float ms[64][64];
  __shared__ float ys[64][64];
  const int tid = threadIdx.x;
  const int p = tid & 63;
  const int ch = tid >> 6;
  const int b = blockIdx.x & 7;
  const int nc = blockIdx.x >> 3;
  const int bn = b * NN + nc * 64 + p;

  // phase 1: gather-maxpool channels [ch*8, ch*8+8)
  const int4* idr = (const int4*)&knn_idx[(size_t)bn * KK];
  int4 nb4[4];
#pragma unroll
  for (int q = 0; q < 4; ++q) nb4[q] = idr[q];
  float4 mx[2];
#pragma unroll
  for (int q = 0; q < 2; ++q) mx[q] = make_float4(-3e38f, -3e38f, -3e38f, -3e38f);
#pragma unroll
  for (int j = 0; j < KK; ++j) {
    const int nb = (j & 3) == 0 ? nb4[j >> 2].x : (j & 3) == 1 ? nb4[j >> 2].y
                 : (j & 3) == 2 ? nb4[j >> 2].z : nb4[j >> 2].w;
    const float4* v = (const float4*)&f1[((size_t)(b << 11) + nb) * 64 + ch * 8];
#pragma unroll
    for (int q = 0; q < 2; ++q) mx[q] = f4max(mx[q], v[q]);
  }
#pragma unroll
  for (int q = 0; q < 2; ++q) {
    ms[ch * 8 + q * 4 + 0][p] = mx[q].x;
    ms[ch * 8 + q * 4 + 1][p] = mx[q].y;
    ms[ch * 8 + q * 4 + 2][p] = mx[q].z;
    ms[ch * 8 + q * 4 + 3][p] = mx[q].w;
  }
  __syncthreads();

  // phase 2: lin1 (no relu), 8 outputs, chunked input
  {
    float acc[8];
#pragma unroll
    for (int oi = 0; oi < 8; ++oi) acc[oi] = lin1_b[ch * 8 + oi];
#pragma unroll
    for (int cc = 0; cc < 64; cc += 32) {
      float xr[32];
#pragma unroll
      for (int c = 0; c < 32; ++c) xr[c] = ms[cc + c][p];
#pragma unroll
      for (int oi = 0; oi < 8; ++oi) {
        const int o = ch * 8 + oi;
#pragma unroll
        for (int c = 0; c < 32; ++c) acc[oi] += lin1_w[o * 64 + cc + c] * xr[c];
      }
    }
    __syncthreads();
#pragma unroll
    for (int oi = 0; oi < 8; ++oi) ys[ch * 8 + oi][p] = acc[oi];
  }
  __syncthreads();

  // phase 3: conv1 + relu, 16 outputs, chunked input
  {
    float acc[16];
#pragma unroll
    for (int oi = 0; oi < 16; ++oi) acc[oi] = conv1_b[ch * 16 + oi];
#pragma unroll
    for (int cc = 0; cc < 64; cc += 32) {
      float xr[32];
#pragma unroll
      for (int c = 0; c < 32; ++c) xr[c] = ys[cc + c][p];
#pragma unroll
      for (int oi = 0; oi < 16; ++oi) {
        const int o = ch * 16 + oi;
#pragma unroll
        for (int c = 0; c < 32; ++c) acc[oi] += conv1_w[o * 64 + cc + c] * xr[c];
      }
    }
#pragma unroll
    for (int oi = 0; oi < 16; ++oi)
      f2[(size_t)bn * 128 + ch * 16 + oi] = fmaxf(acc[oi], 0.f);
  }
}

// ------------------------------------------------- maxpool(16) + lin2
__global__ __launch_bounds__(512, 2) void gconv2_kernel(
    const float* __restrict__ f2, const int* __restrict__ knn_idx,
    const float* __restrict__ lin2_w, const float* __restrict__ lin2_b,
    float* __restrict__ f3) {
  __shared__ float ms[128][64];
  const int tid = threadIdx.x;
  const int p = tid & 63;
  const int ch = tid >> 6;
  const int b = blockIdx.x & 7;
  const int nc = blockIdx.x >> 3;
  const int bn = b * NN + nc * 64 + p;

  // phase 1: gather-maxpool channels [ch*16, ch*16+16)
  const int4* idr = (const int4*)&knn_idx[(size_t)bn * KK];
  int4 nb4[4];
#pragma unroll
  for (int q = 0; q < 4; ++q) nb4[q] = idr[q];
  float4 mx[4];
#pragma unroll
  for (int q = 0; q < 4; ++q) mx[q] = make_float4(-3e38f, -3e38f, -3e38f, -3e38f);
#pragma unroll
  for (int j = 0; j < KK; ++j) {
    const int nb = (j & 3) == 0 ? nb4[j >> 2].x : (j & 3) == 1 ? nb4[j >> 2].y
                 : (j & 3) == 2 ? nb4[j >> 2].z : nb4[j >> 2].w;
    const float4* v = (const float4*)&f2[((size_t)(b << 11) + nb) * 128 + ch * 16];
#pragma unroll
    for (int q = 0; q < 4; ++q) mx[q] = f4max(mx[q], v[q]);
  }
#pragma unroll
  for (int q = 0; q < 4; ++q) {
    ms[ch * 16 + q * 4 + 0][p] = mx[q].x;
    ms[ch * 16 + q * 4 + 1][p] = mx[q].y;
    ms[ch * 16 + q * 4 + 2][p] = mx[q].z;
    ms[ch * 16 + q * 4 + 3][p] = mx[q].w;
  }
  __syncthreads();

  // phase 2: lin2 (no relu), 16 outputs, input streamed via xr[32] chunks
  {
    float acc[16];
#pragma unroll
    for (int oi = 0; oi < 16; ++oi) acc[oi] = lin2_b[ch * 16 + oi];
#pragma unroll
    for (int cc = 0; cc < 128; cc += 32) {
      float xr[32];
#pragma unroll
      for (int c = 0; c < 32; ++c) xr[c] = ms[cc + c][p];
#pragma unroll
      for (int oi = 0; oi < 16; ++oi) {
        const int o = ch * 16 + oi;
#pragma unroll
        for (int c = 0; c < 32; ++c) acc[oi] += lin2_w[o * 128 + cc + c] * xr[c];
      }
    }
#pragma unroll
    for (int oi = 0; oi < 16; ++oi)
      f3[(size_t)bn * 128 + ch * 16 + oi] = acc[oi];
  }
}

// ---------------------- conv2_w f32 -> bf16 hi/lo split (1024x128 = 131072)
__global__ __launch_bounds__(256) void wcvt_kernel(const float* __restrict__ w,
                                                   unsigned short* __restrict__ whi,
                                                   unsigned short* __restrict__ wlo) {
  const int i = blockIdx.x * 256 + threadIdx.x;
  const float x = w[i];
  const unsigned short h = f2bf(x);
  whi[i] = h;
  wlo[i] = f2bf(x - bf2f(h));
}

// ---------------- conv2 (128->1024) via bf16-split MFMA, fused global max(n)
__global__ __launch_bounds__(256, 2) void conv2max_kernel(
    const float* __restrict__ f3, const unsigned short* __restrict__ whi,
    const unsigned short* __restrict__ wlo, float* __restrict__ pmax) {
  __shared__ __align__(16) unsigned short xls[2][64][128];   // 32 KB hi|lo
  const int bi = blockIdx.x;
  const int b = bi & 7, nc = bi >> 3;
  const int tid = threadIdx.x;
  const int lane = tid & 63, wv = tid >> 6;

  // stage + split-convert 64x128 f32 -> bf16 hi/lo (swizzled 16B slots)
  {
    const int n = tid >> 2, cq = (tid & 3) * 32;
    const float4* src = (const float4*)&f3[((size_t)(b * NN + nc * 64 + n)) * 128 + cq];
    char* basep = (char*)&xls[0][0][0];
#pragma unroll
    for (int s = 0; s < 4; ++s) {
      float4 u = src[s * 2], v2 = src[s * 2 + 1];
      float xv[8] = {u.x, u.y, u.z, u.w, v2.x, v2.y, v2.z, v2.w};
      ushort8v hw, lw;
#pragma unroll
      for (int j = 0; j < 8; ++j) {
        unsigned short h = f2bf(xv[j]);
        hw[j] = h;
        lw[j] = f2bf(xv[j] - bf2f(h));
      }
      const int slot = (cq >> 3) + s;
      const int swz = slot ^ (n & 15);
      char* dst = basep + n * 256 + swz * 16;
      *(ushort8v*)dst = hw;
      *(ushort8v*)(dst + 16384) = lw;
    }
  }
  __syncthreads();

  const int g = lane >> 4, r = lane & 15;
  const char* basep = (const char*)&xls[0][0][0];
  float omax[16];
#pragma unroll
  for (int ot = 0; ot < 16; ++ot) omax[ot] = -3e38f;

#pragma unroll
  for (int mg = 0; mg < 2; ++mg) {
    bf16x8 ah[2][4], al[2][4];
#pragma unroll
    for (int m = 0; m < 2; ++m) {
      const int row = (mg * 2 + m) * 16 + r;
#pragma unroll
      for (int kt = 0; kt < 4; ++kt) {
        const int swz = (kt * 4 + g) ^ (row & 15);
        const char* p = basep + row * 256 + swz * 16;
        ah[m][kt] = *(const bf16x8*)p;
        al[m][kt] = *(const bf16x8*)(p + 16384);
      }
    }
#pragma unroll 1
    for (int ot = 0; ot < 16; ++ot) {
      const int o = wv * 256 + ot * 16 + r;
      const char* wb = (const char*)whi + (size_t)o * 256 + g * 16;
      const char* lb = (const char*)wlo + (size_t)o * 256 + g * 16;
      bf16x8 bh[4], bl[4];
#pragma unroll
      for (int kt = 0; kt < 4; ++kt) {
        bh[kt] = *(const bf16x8*)(wb + kt * 64);
        bl[kt] = *(const bf16x8*)(lb + kt * 64);
      }
      f32x4 acc0 = {0.f, 0.f, 0.f, 0.f}, acc1 = {0.f, 0.f, 0.f, 0.f};
#pragma unroll
      for (int kt = 0; kt < 4; ++kt) {
        acc0 = __builtin_amdgcn_mfma_f32_16x16x32_bf16(ah[0][kt], bh[kt], acc0, 0, 0, 0);
        acc1 = __builtin_amdgcn_mfma_f32_16x16x32_bf16(ah[1][kt], bh[kt], acc1, 0, 0, 0);
        acc0 = __builtin_amdgcn_mfma_f32_16x16x32_bf16(ah[0][kt], bl[kt], acc0, 0, 0, 0);
        acc1 = __builtin_amdgcn_mfma_f32_16x16x32_bf16(ah[1][kt], bl[kt], acc1, 0, 0, 0);
        acc0 = __builtin_amdgcn_mfma_f32_16x16x32_bf16(al[0][kt], bh[kt], acc0, 0, 0, 0);
        acc1 = __builtin_amdgcn_mfma_f32_16x16x32_bf16(al[1][kt], bh[kt], acc1, 0, 0, 0);
      }
      float mx = fmaxf(fmaxf(fmaxf(acc0[0], acc0[1]), fmaxf(acc0[2], acc0[3])),
                       fmaxf(fmaxf(acc1[0], acc1[1]), fmaxf(acc1[2], acc1[3])));
      omax[ot] = fmaxf(omax[ot], mx);
    }
  }
#pragma unroll
  for (int ot = 0; ot < 16; ++ot) {
    float v = omax[ot];
    v = fmaxf(v, __shfl_xor(v, 16, 64));
    v = fmaxf(v, __shfl_xor(v, 32, 64));
    omax[ot] = v;
  }
  if (lane < 16) {
#pragma unroll
    for (int ot = 0; ot < 16; ++ot) {
      const int o = wv * 256 + ot * 16 + lane;
      pmax[((size_t)b * 1024 + o) * 32 + nc] = omax[ot];
    }
  }
}

// ----------------------------------------- reduce partials + bias + mlp2 head
__global__ __launch_bounds__(256) void head_kernel(
    const float* __restrict__ pmax, const float* __restrict__ conv2_b,
    const float* __restrict__ w2a, const float* __restrict__ b2a,
    const float* __restrict__ w2b, const float* __restrict__ b2b,
    float* __restrict__ out) {
  const int b = blockIdx.x;
  const int tid = threadIdx.x;
  __shared__ __align__(16) float g[1024];
  __shared__ __align__(16) float h[512];
  for (int o = tid; o < 1024; o += 256) {
    const float4* p = (const float4*)&pmax[((size_t)b * 1024 + o) * 32];
    float4 a4 = p[0];
#pragma unroll
    for (int gi = 1; gi < 8; ++gi) a4 = f4max(a4, p[gi]);
    g[o] = fmaxf(fmaxf(a4.x, a4.y), fmaxf(a4.z, a4.w)) + conv2_b[o];
  }
  __syncthreads();
#pragma unroll
  for (int r = 0; r < 2; ++r) {
    const int k = r * 256 + tid;
    float a = b2a[k];
    const float4* wr = (const float4*)&w2a[(size_t)k * 1024];
    const float4* gv = (const float4*)g;
    for (int c = 0; c < 256; ++c) {
      float4 w = wr[c], xx = gv[c];
      a += w.x * xx.x + w.y * xx.y + w.z * xx.z + w.w * xx.w;
    }
    h[k] = fmaxf(a, 0.f);
  }
  __syncthreads();
#pragma unroll
  for (int r = 0; r < 2; ++r) {
    const int j = r * 256 + tid;
    float a = b2b[j];
    const float4* wr = (const float4*)&w2b[(size_t)j * 512];
    const float4* hv = (const float4*)h;
    for (int c = 0; c < 128; ++c) {
      float4 w = wr[c], xx = hv[c];
      a += w.x * xx.x + w.y * xx.y + w.z * xx.z + w.w * xx.w;
    }
    out[(size_t)b * 512 + j] = a;
  }
}

extern "C" void kernel_launch(void* const* d_in, const int* in_sizes, int n_in,
                              void* d_out, int out_size, void* d_ws, size_t ws_size,
                              hipStream_t stream) {
  const float* pts     = (const float*)d_in[0];
  const float* w1a     = (const float*)d_in[1];
  const float* b1a     = (const float*)d_in[2];
  const float* w1b     = (const float*)d_in[3];
  const float* b1b     = (const float*)d_in[4];
  const float* w1c     = (const float*)d_in[5];
  const float* b1c     = (const float*)d_in[6];
  const float* lin1_w  = (const float*)d_in[7];
  const float* lin1_b  = (const float*)d_in[8];
  const float* conv1_w = (const float*)d_in[9];
  const float* conv1_b = (const float*)d_in[10];
  const float* lin2_w  = (const float*)d_in[11];
  const float* lin2_b  = (const float*)d_in[12];
  const float* conv2_w = (const float*)d_in[13];
  const float* conv2_b = (const float*)d_in[14];
  const float* w2a     = (const float*)d_in[15];
  const float* b2a     = (const float*)d_in[16];
  const float* w2b     = (const float*)d_in[17];
  const float* b2b     = (const float*)d_in[18];

  char* ws = (char*)d_ws;
  int*   knn_idx = (int*)ws;                            // 1 MB
  float* f1 = (float*)(ws + (1u << 20));                // 4 MB   (region A)
  float* f2 = (float*)(ws + (9u << 20));                // 8 MB   (region B)
  float* f3 = (float*)(ws + (1u << 20));                // 8 MB   (region A reuse)
  unsigned short* whi = (unsigned short*)(ws + (17u << 20));              // 256 KB
  unsigned short* wlo = (unsigned short*)(ws + (17u << 20) + (1u << 18)); // 256 KB
  float* pm = (float*)(ws + (17u << 20) + (2u << 18));  // 1 MB

  wcvt_kernel  <<<512, 256, 0, stream>>>(conv2_w, whi, wlo);
  knn_kernel   <<<512, 256, 0, stream>>>(pts, knn_idx);
  mlp1_kernel  <<<256, 512, 0, stream>>>(pts, knn_idx, w1a, b1a, w1b, b1b, w1c, b1c, f1);
  gconv1_kernel<<<256, 512, 0, stream>>>(f1, knn_idx, lin1_w, lin1_b, conv1_w, conv1_b, f2);
  gconv2_kernel<<<256, 512, 0, stream>>>(f2, knn_idx, lin2_w, lin2_b, f3);
  conv2max_kernel<<<256, 256, 0, stream>>>(f3, whi, wlo, pm);
  head_kernel  <<<8, 256, 0, stream>>>(pm, conv2_b, w2a, b2a, w2b, b2b, (float*)d_out);
}

// Round 8
// 277.386 us; speedup vs baseline: 4.5458x; 1.3056x over previous
//
#include <hip/hip_runtime.h>

#define BB 8
#define NN 2048
#define KK 16
#define QT 32      // kNN queries per block
#define NSLICE 8
#define SLEN 256   // NN / NSLICE
#define KP 18      // packed keep-depth per slice (pool safety margin)

typedef short bf16x8 __attribute__((ext_vector_type(8)));
typedef float f32x4 __attribute__((ext_vector_type(4)));
typedef unsigned short ushort8v __attribute__((ext_vector_type(8)));

__device__ __forceinline__ float4 f4max(float4 a, float4 b) {
  return make_float4(fmaxf(a.x, b.x), fmaxf(a.y, b.y), fmaxf(a.z, b.z), fmaxf(a.w, b.w));
}

__device__ __forceinline__ unsigned short f2bf(float x) {  // f32 -> bf16 bits, RNE
  union { float f; unsigned u; } v; v.f = x;
  unsigned r = v.u + 0x7fffu + ((v.u >> 16) & 1u);
  return (unsigned short)(r >> 16);
}
__device__ __forceinline__ float bf2f(unsigned short h) {
  union { unsigned u; float f; } v; v.u = ((unsigned)h) << 16;
  return v.f;
}

// ---------------------------------------------------------------- kNN top-16
__global__ __launch_bounds__(256) void knn_kernel(const float* __restrict__ pts,
                                                  int* __restrict__ knn_idx) {
  __shared__ float4 sp[NN];                         // 32 KB (x,y,z,|p|^2)
  __shared__ unsigned pk[NSLICE][QT][KP];           // 18 KB packed lists
  __shared__ float          s1v[4][QT][16];         // 8 KB stage-1 vals
  __shared__ unsigned short s1i[4][QT][16];         // 4 KB stage-1 ids
  const int b = blockIdx.x & 7;
  const int tile = blockIdx.x >> 3;
  const int tid = threadIdx.x;
  const int q = tid & 31;
  const int s = tid >> 5;

  for (int i = tid; i < NN; i += 256) {
    float x = pts[(size_t)(b * NN + i) * 3 + 0];
    float y = pts[(size_t)(b * NN + i) * 3 + 1];
    float z = pts[(size_t)(b * NN + i) * 3 + 2];
    sp[i] = make_float4(x, y, z, x * x + y * y + z * z);
  }
  __syncthreads();

  {
    const float4 pq = sp[tile * QT + q];
    unsigned qk[KP];
#pragma unroll
    for (int j = 0; j < KP; ++j) qk[j] = 0u;
    const int m0 = s * SLEN;
    for (int mb = 0; mb < SLEN; mb += 8) {
      float4 c[8];
#pragma unroll
      for (int u = 0; u < 8; ++u) c[u] = sp[m0 + mb + u];
#pragma unroll
      for (int u = 0; u < 8; ++u) {
        const float v = 2.0f * (pq.x * c[u].x + pq.y * c[u].y + pq.z * c[u].z)
                        - pq.w - c[u].w;
        unsigned uu = __float_as_uint(v);
        unsigned key = uu ^ ((unsigned)(((int)uu) >> 31) | 0x80000000u);
        unsigned run = (key & 0xFFFFFF00u) | (unsigned)(255 - (mb + u));
#pragma unroll
        for (int j = 0; j < KP; ++j) {          // branchless sorted insert
          const unsigned hi = max(qk[j], run);
          const unsigned lo = min(qk[j], run);
          qk[j] = hi; run = lo;
        }
      }
    }
#pragma unroll
    for (int j = 0; j < KP; ++j) pk[s][q][j] = qk[j];
  }
  __syncthreads();

  if (tid < 128) {
    const int q2 = tid & 31, pr = tid >> 5;
    const float4 pm = sp[tile * QT + q2];
    float mv[16]; int mi[16];
#pragma unroll
    for (int j = 0; j < 16; ++j) { mv[j] = -3.0e38f; mi[j] = 0; }
#pragma unroll 1
    for (int ss = 2 * pr; ss <= 2 * pr + 1; ++ss) {
      const int base = ss * SLEN;
#pragma unroll 1
      for (int j = 0; j < KP; ++j) {
        const unsigned pkd = pk[ss][q2][j];
        const int id = base + 255 - (int)(pkd & 0xFFu);
        const float4 c = sp[id];
        const float v = 2.0f * (pm.x * c.x + pm.y * c.y + pm.z * c.z) - pm.w - c.w;
        if (v > mv[15]) {
          mv[15] = v; mi[15] = id;
#pragma unroll
          for (int t = 15; t > 0; --t) {
            if (mv[t] > mv[t - 1]) {
              float tv = mv[t]; mv[t] = mv[t - 1]; mv[t - 1] = tv;
              int ti = mi[t]; mi[t] = mi[t - 1]; mi[t - 1] = ti;
            }
          }
        }
      }
    }
#pragma unroll
    for (int j = 0; j < 16; ++j) {
      s1v[pr][q2][j] = mv[j];
      s1i[pr][q2][j] = (unsigned short)mi[j];
    }
  }
  __syncthreads();

  if (tid < QT) {
    float mv[16]; int mi[16];
#pragma unroll
    for (int j = 0; j < 16; ++j) { mv[j] = -3.0e38f; mi[j] = 0; }
#pragma unroll 1
    for (int pr = 0; pr < 4; ++pr) {
#pragma unroll 1
      for (int j = 0; j < 16; ++j) {
        const float v = s1v[pr][tid][j];
        if (v <= mv[15]) break;
        const int id = s1i[pr][tid][j];
        mv[15] = v; mi[15] = id;
#pragma unroll
        for (int t = 15; t > 0; --t) {
          if (mv[t] > mv[t - 1]) {
            float tv = mv[t]; mv[t] = mv[t - 1]; mv[t - 1] = tv;
            int ti = mi[t]; mi[t] = mi[t - 1]; mi[t - 1] = ti;
          }
        }
      }
    }
    const int nq = tile * QT + tid;
#pragma unroll
    for (int j = 0; j < 16; ++j) knn_idx[(size_t)(b * NN + nq) * KK + j] = mi[j];
  }
}

// -------------- composite weights: W1' = conv1_w(128x64) @ lin1_w(64x64)
__global__ __launch_bounds__(64) void wcomp1_kernel(
    const float* __restrict__ lin1_w, const float* __restrict__ lin1_b,
    const float* __restrict__ conv1_w, const float* __restrict__ conv1_b,
    unsigned short* __restrict__ w1hi, unsigned short* __restrict__ w1lo,
    float* __restrict__ b1p) {
  const int o = blockIdx.x;      // 128
  const int c = threadIdx.x;     // 64
  float acc = 0.f;
#pragma unroll 8
  for (int k = 0; k < 64; ++k) acc += conv1_w[o * 64 + k] * lin1_w[k * 64 + c];
  const unsigned short h = f2bf(acc);
  w1hi[o * 64 + c] = h;
  w1lo[o * 64 + c] = f2bf(acc - bf2f(h));
  if (c == 0) {
    float bb = conv1_b[o];
    for (int k = 0; k < 64; ++k) bb += conv1_w[o * 64 + k] * lin1_b[k];
    b1p[o] = bb;
  }
}

// -------------- composite weights: W2' = conv2_w(1024x128) @ lin2_w(128x128)
__global__ __launch_bounds__(128) void wcomp2_kernel(
    const float* __restrict__ lin2_w, const float* __restrict__ lin2_b,
    const float* __restrict__ conv2_w, const float* __restrict__ conv2_b,
    unsigned short* __restrict__ w2hi, unsigned short* __restrict__ w2lo,
    float* __restrict__ b2p) {
  const int o = blockIdx.x;      // 1024
  const int c = threadIdx.x;     // 128
  float acc = 0.f;
#pragma unroll 8
  for (int k = 0; k < 128; ++k) acc += conv2_w[o * 128 + k] * lin2_w[k * 128 + c];
  const unsigned short h = f2bf(acc);
  w2hi[o * 128 + c] = h;
  w2lo[o * 128 + c] = f2bf(acc - bf2f(h));
  if (c == 0) {
    float bb = conv2_b[o];
    for (int k = 0; k < 128; ++k) bb += conv2_w[o * 128 + k] * lin2_b[k];
    b2p[o] = bb;
  }
}

// ------------------------------------------- features (pts + cov) + mlp1 x3
// chunk loops unroll 1 (full unroll let LLVM hoist all ds_reads -> 100MB spill)
__global__ __launch_bounds__(512, 2) void mlp1_kernel(
    const float* __restrict__ pts, const int* __restrict__ knn_idx,
    const float* __restrict__ w1a, const float* __restrict__ b1a,
    const float* __restrict__ w1b, const float* __restrict__ b1b,
    const float* __restrict__ w1c, const float* __restrict__ b1c,
    float* __restrict__ f1) {
  __shared__ float h1[64][64];
  __shared__ float h2[64][64];
  const int tid = threadIdx.x;
  const int p = tid & 63;
  const int ch = tid >> 6;
  const int b = blockIdx.x & 7;
  const int nc = blockIdx.x >> 3;
  const int bn = b * NN + nc * 64 + p;

  const int n0 = knn_idx[(size_t)bn * KK + 0];
  const int n1 = knn_idx[(size_t)bn * KK + 1];
  const float* pp = &pts[(size_t)bn * 3];
  const float* p0 = &pts[((size_t)(b << 11) + n0) * 3];
  const float* p1 = &pts[((size_t)(b << 11) + n1) * 3];
  float in[12];
  in[0] = pp[0]; in[1] = pp[1]; in[2] = pp[2];
  {
    float a0 = p0[0], a1 = p0[1], a2 = p0[2];
    float c0 = p1[0], c1 = p1[1], c2 = p1[2];
    in[3] = a0 * c0; in[4]  = a0 * c1; in[5]  = a0 * c2;
    in[6] = a1 * c0; in[7]  = a1 * c1; in[8]  = a1 * c2;
    in[9] = a2 * c0; in[10] = a2 * c1; in[11] = a2 * c2;
  }

#pragma unroll
  for (int oi = 0; oi < 8; ++oi) {
    const int o = ch * 8 + oi;
    float a = b1a[o];
#pragma unroll
    for (int c = 0; c < 12; ++c) a += w1a[o * 12 + c] * in[c];
    h1[o][p] = fmaxf(a, 0.f);
  }
  __syncthreads();

  {
    float acc[8];
#pragma unroll
    for (int oi = 0; oi < 8; ++oi) acc[oi] = b1b[ch * 8 + oi];
#pragma unroll 1
    for (int cc = 0; cc < 64; cc += 32) {
      float xr[32];
#pragma unroll
      for (int c = 0; c < 32; ++c) xr[c] = h1[cc + c][p];
#pragma unroll
      for (int oi = 0; oi < 8; ++oi) {
        const int o = ch * 8 + oi;
#pragma unroll
        for (int c = 0; c < 32; ++c) acc[oi] += w1b[o * 64 + cc + c] * xr[c];
      }
    }
    __syncthreads();
#pragma unroll
    for (int oi = 0; oi < 8; ++oi) h2[ch * 8 + oi][p] = fmaxf(acc[oi], 0.f);
  }
  __syncthreads();

  {
    float acc[8];
#pragma unroll
    for (int oi = 0; oi < 8; ++oi) acc[oi] = b1c[ch * 8 + oi];
#pragma unroll 1
    for (int cc = 0; cc < 64; cc += 32) {
      float xr[32];
#pragma unroll
      for (int c = 0; c < 32; ++c) xr[c] = h2[cc + c][p];
#pragma unroll
      for (int oi = 0; oi < 8; ++oi) {
        const int o = ch * 8 + oi;
#pragma unroll
        for (int c = 0; c < 32; ++c) acc[oi] += w1c[o * 64 + cc + c] * xr[c];
      }
    }
#pragma unroll
    for (int oi = 0; oi < 8; ++oi)
      f1[(size_t)bn * 64 + ch * 8 + oi] = fmaxf(acc[oi], 0.f);
  }
}

// ------------- maxpool(f1) + composite lin1+conv1 (W1', MFMA) + relu -> f2
__global__ __launch_bounds__(256, 2) void gconv1_kernel(
    const float* __restrict__ f1, const int* __restrict__ knn_idx,
    const unsigned short* __restrict__ w1hi, const unsigned short* __restrict__ w1lo,
    const float* __restrict__ b1p, float* __restrict__ f2) {
  __shared__ __align__(16) unsigned short xls[2][64][64];   // 16 KB hi|lo
  const int b = blockIdx.x & 7, nc = blockIdx.x >> 3;
  const int tid = threadIdx.x;
  const int lane = tid & 63, wv = tid >> 6;

  // phase 1: gather-maxpool 16 channels/thread -> bf16 split -> swizzled LDS
  {
    const int p = tid & 63, ch = tid >> 6;   // ch in 0..3: channels [ch*16,+16)
    const int bn = b * NN + nc * 64 + p;
    const int4* idr = (const int4*)&knn_idx[(size_t)bn * KK];
    int4 nb4[4];
#pragma unroll
    for (int q = 0; q < 4; ++q) nb4[q] = idr[q];
    float4 mx[4];
#pragma unroll
    for (int q = 0; q < 4; ++q) mx[q] = make_float4(-3e38f, -3e38f, -3e38f, -3e38f);
#pragma unroll
    for (int j = 0; j < KK; ++j) {
      const int nb = (j & 3) == 0 ? nb4[j >> 2].x : (j & 3) == 1 ? nb4[j >> 2].y
                   : (j & 3) == 2 ? nb4[j >> 2].z : nb4[j >> 2].w;
      const float4* v = (const float4*)&f1[((size_t)(b << 11) + nb) * 64 + ch * 16];
#pragma unroll
      for (int q = 0; q < 4; ++q) mx[q] = f4max(mx[q], v[q]);
    }
    char* basep = (char*)&xls[0][0][0];
#pragma unroll
    for (int s = 0; s < 2; ++s) {
      float xv[8] = {mx[2 * s].x, mx[2 * s].y, mx[2 * s].z, mx[2 * s].w,
                     mx[2 * s + 1].x, mx[2 * s + 1].y, mx[2 * s + 1].z, mx[2 * s + 1].w};
      ushort8v hw, lw;
#pragma unroll
      for (int j = 0; j < 8; ++j) {
        unsigned short h = f2bf(xv[j]);
        hw[j] = h;
        lw[j] = f2bf(xv[j] - bf2f(h));
      }
      const int slot = ch * 2 + s;
      const int swz = slot ^ (p & 7);
      char* dst = basep + p * 128 + swz * 16;
      *(ushort8v*)dst = hw;
      *(ushort8v*)(dst + 8192) = lw;
    }
  }
  __syncthreads();

  const int g = lane >> 4, r = lane & 15;
  const char* basep = (const char*)&xls[0][0][0];
  // A-frags: 4 m-tiles x 2 k-steps
  bf16x8 ah[4][2], al[4][2];
#pragma unroll
  for (int m = 0; m < 4; ++m) {
    const int row = m * 16 + r;
#pragma unroll
    for (int kt = 0; kt < 2; ++kt) {
      const int swz = (kt * 4 + g) ^ (row & 7);
      const char* p = basep + row * 128 + swz * 16;
      ah[m][kt] = *(const bf16x8*)p;
      al[m][kt] = *(const bf16x8*)(p + 8192);
    }
  }
  f32x4 acc[4][2];
#pragma unroll
  for (int m = 0; m < 4; ++m)
#pragma unroll
    for (int nt = 0; nt < 2; ++nt) acc[m][nt] = (f32x4){0.f, 0.f, 0.f, 0.f};

#pragma unroll
  for (int nt = 0; nt < 2; ++nt) {
    const int o = (wv * 2 + nt) * 16 + r;
    const char* wb = (const char*)w1hi + (size_t)o * 128 + g * 16;
    const char* lb = (const char*)w1lo + (size_t)o * 128 + g * 16;
    bf16x8 bh[2], bl[2];
#pragma unroll
    for (int kt = 0; kt < 2; ++kt) {
      bh[kt] = *(const bf16x8*)(wb + kt * 64);
      bl[kt] = *(const bf16x8*)(lb + kt * 64);
    }
#pragma unroll
    for (int kt = 0; kt < 2; ++kt) {
#pragma unroll
      for (int m = 0; m < 4; ++m) {
        acc[m][nt] = __builtin_amdgcn_mfma_f32_16x16x32_bf16(ah[m][kt], bh[kt], acc[m][nt], 0, 0, 0);
        acc[m][nt] = __builtin_amdgcn_mfma_f32_16x16x32_bf16(ah[m][kt], bl[kt], acc[m][nt], 0, 0, 0);
        acc[m][nt] = __builtin_amdgcn_mfma_f32_16x16x32_bf16(al[m][kt], bh[kt], acc[m][nt], 0, 0, 0);
      }
    }
  }
  // epilogue: + b1' , relu, write f2 (D: col=lane&15 -> o, row=g*4+j)
#pragma unroll
  for (int nt = 0; nt < 2; ++nt) {
    const int o = (wv * 2 + nt) * 16 + r;
    const float bias = b1p[o];
#pragma unroll
    for (int m = 0; m < 4; ++m) {
#pragma unroll
      for (int j = 0; j < 4; ++j) {
        const int row = m * 16 + g * 4 + j;
        f2[((size_t)(b * NN + nc * 64 + row)) * 128 + o] = fmaxf(acc[m][nt][j] + bias, 0.f);
      }
    }
  }
}

// ---- maxpool(f2) + composite lin2+conv2 (W2', MFMA) + fused global max(n)
__global__ __launch_bounds__(256, 2) void gconv2max_kernel(
    const float* __restrict__ f2, const int* __restrict__ knn_idx,
    const unsigned short* __restrict__ w2hi, const unsigned short* __restrict__ w2lo,
    float* __restrict__ pmax) {
  __shared__ __align__(16) unsigned short xls[2][64][128];   // 32 KB hi|lo
  const int b = blockIdx.x & 7, nc = blockIdx.x >> 3;
  const int tid = threadIdx.x;
  const int lane = tid & 63, wv = tid >> 6;

  // phase 1: gather-maxpool 32 channels/thread -> bf16 split -> swizzled LDS
  {
    const int p = tid & 63, ch = tid >> 6;   // ch in 0..3: channels [ch*32,+32)
    const int bn = b * NN + nc * 64 + p;
    const int4* idr = (const int4*)&knn_idx[(size_t)bn * KK];
    int4 nb4[4];
#pragma unroll
    for (int q = 0; q < 4; ++q) nb4[q] = idr[q];
    float4 mx[8];
#pragma unroll
    for (int q = 0; q < 8; ++q) mx[q] = make_float4(-3e38f, -3e38f, -3e38f, -3e38f);
#pragma unroll
    for (int j = 0; j < KK; ++j) {
      const int nb = (j & 3) == 0 ? nb4[j >> 2].x : (j & 3) == 1 ? nb4[j >> 2].y
                   : (j & 3) == 2 ? nb4[j >> 2].z : nb4[j >> 2].w;
      const float4* v = (const float4*)&f2[((size_t)(b << 11) + nb) * 128 + ch * 32];
#pragma unroll
      for (int q = 0; q < 8; ++q) mx[q] = f4max(mx[q], v[q]);
    }
    char* basep = (char*)&xls[0][0][0];
#pragma unroll
    for (int s = 0; s < 4; ++s) {
      float xv[8] = {mx[2 * s].x, mx[2 * s].y, mx[2 * s].z, mx[2 * s].w,
                     mx[2 * s + 1].x, mx[2 * s + 1].y, mx[2 * s + 1].z, mx[2 * s + 1].w};
      ushort8v hw, lw;
#pragma unroll
      for (int j = 0; j < 8; ++j) {
        unsigned short h = f2bf(xv[j]);
        hw[j] = h;
        lw[j] = f2bf(xv[j] - bf2f(h));
      }
      const int slot = ch * 4 + s;
      const int swz = slot ^ (p & 15);
      char* dst = basep + p * 256 + swz * 16;
      *(ushort8v*)dst = hw;
      *(ushort8v*)(dst + 16384) = lw;
    }
  }
  __syncthreads();

  const int g = lane >> 4, r = lane & 15;
  const char* basep = (const char*)&xls[0][0][0];
  float omax[16];
#pragma unroll
  for (int ot = 0; ot < 16; ++ot) omax[ot] = -3e38f;

#pragma unroll
  for (int mg = 0; mg < 2; ++mg) {
    bf16x8 ah[2][4], al[2][4];
#pragma unroll
    for (int m = 0; m < 2; ++m) {
      const int row = (mg * 2 + m) * 16 + r;
#pragma unroll
      for (int kt = 0; kt < 4; ++kt) {
        const int swz = (kt * 4 + g) ^ (row & 15);
        const char* p = basep + row * 256 + swz * 16;
        ah[m][kt] = *(const bf16x8*)p;
        al[m][kt] = *(const bf16x8*)(p + 16384);
      }
    }
#pragma unroll 1
    for (int ot = 0; ot < 16; ++ot) {
      const int o = wv * 256 + ot * 16 + r;
      const char* wb = (const char*)w2hi + (size_t)o * 256 + g * 16;
      const char* lb = (const char*)w2lo + (size_t)o * 256 + g * 16;
      bf16x8 bh[4], bl[4];
#pragma unroll
      for (int kt = 0; kt < 4; ++kt) {
        bh[kt] = *(const bf16x8*)(wb + kt * 64);
        bl[kt] = *(const bf16x8*)(lb + kt * 64);
      }
      f32x4 acc0 = {0.f, 0.f, 0.f, 0.f}, acc1 = {0.f, 0.f, 0.f, 0.f};
#pragma unroll
      for (int kt = 0; kt < 4; ++kt) {
        acc0 = __builtin_amdgcn_mfma_f32_16x16x32_bf16(ah[0][kt], bh[kt], acc0, 0, 0, 0);
        acc1 = __builtin_amdgcn_mfma_f32_16x16x32_bf16(ah[1][kt], bh[kt], acc1, 0, 0, 0);
        acc0 = __builtin_amdgcn_mfma_f32_16x16x32_bf16(ah[0][kt], bl[kt], acc0, 0, 0, 0);
        acc1 = __builtin_amdgcn_mfma_f32_16x16x32_bf16(ah[1][kt], bl[kt], acc1, 0, 0, 0);
        acc0 = __builtin_amdgcn_mfma_f32_16x16x32_bf16(al[0][kt], bh[kt], acc0, 0, 0, 0);
        acc1 = __builtin_amdgcn_mfma_f32_16x16x32_bf16(al[1][kt], bh[kt], acc1, 0, 0, 0);
      }
      float mx = fmaxf(fmaxf(fmaxf(acc0[0], acc0[1]), fmaxf(acc0[2], acc0[3])),
                       fmaxf(fmaxf(acc1[0], acc1[1]), fmaxf(acc1[2], acc1[3])));
      omax[ot] = fmaxf(omax[ot], mx);
    }
  }
#pragma unroll
  for (int ot = 0; ot < 16; ++ot) {
    float v = omax[ot];
    v = fmaxf(v, __shfl_xor(v, 16, 64));
    v = fmaxf(v, __shfl_xor(v, 32, 64));
    omax[ot] = v;
  }
  if (lane < 16) {
#pragma unroll
    for (int ot = 0; ot < 16; ++ot) {
      const int o = wv * 256 + ot * 16 + lane;
      pmax[((size_t)b * 1024 + o) * 32 + nc] = omax[ot];
    }
  }
}

// ----------------------------------------- reduce partials + b2' + mlp2 head
__global__ __launch_bounds__(256) void head_kernel(
    const float* __restrict__ pmax, const float* __restrict__ b2p,
    const float* __restrict__ w2a, const float* __restrict__ b2a,
    const float* __restrict__ w2b, const float* __restrict__ b2b,
    float* __restrict__ out) {
  const int b = blockIdx.x;
  const int tid = threadIdx.x;
  __shared__ __align__(16) float g[1024];
  __shared__ __align__(16) float h[512];
  for (int o = tid; o < 1024; o += 256) {
    const float4* p = (const float4*)&pmax[((size_t)b * 1024 + o) * 32];
    float4 a4 = p[0];
#pragma unroll
    for (int gi = 1; gi < 8; ++gi) a4 = f4max(a4, p[gi]);
    g[o] = fmaxf(fmaxf(a4.x, a4.y), fmaxf(a4.z, a4.w)) + b2p[o];
  }
  __syncthreads();
#pragma unroll
  for (int r = 0; r < 2; ++r) {
    const int k = r * 256 + tid;
    float a = b2a[k];
    const float4* wr = (const float4*)&w2a[(size_t)k * 1024];
    const float4* gv = (const float4*)g;
    for (int c = 0; c < 256; ++c) {
      float4 w = wr[c], xx = gv[c];
      a += w.x * xx.x + w.y * xx.y + w.z * xx.z + w.w * xx.w;
    }
    h[k] = fmaxf(a, 0.f);
  }
  __syncthreads();
#pragma unroll
  for (int r = 0; r < 2; ++r) {
    const int j = r * 256 + tid;
    float a = b2b[j];
    const float4* wr = (const float4*)&w2b[(size_t)j * 512];
    const float4* hv = (const float4*)h;
    for (int c = 0; c < 128; ++c) {
      float4 w = wr[c], xx = hv[c];
      a += w.x * xx.x + w.y * xx.y + w.z * xx.z + w.w * xx.w;
    }
    out[(size_t)b * 512 + j] = a;
  }
}

extern "C" void kernel_launch(void* const* d_in, const int* in_sizes, int n_in,
                              void* d_out, int out_size, void* d_ws, size_t ws_size,
                              hipStream_t stream) {
  const float* pts     = (const float*)d_in[0];
  const float* w1a     = (const float*)d_in[1];
  const float* b1a     = (const float*)d_in[2];
  const float* w1b     = (const float*)d_in[3];
  const float* b1b     = (const float*)d_in[4];
  const float* w1c     = (const float*)d_in[5];
  const float* b1c     = (const float*)d_in[6];
  const float* lin1_w  = (const float*)d_in[7];
  const float* lin1_b  = (const float*)d_in[8];
  const float* conv1_w = (const float*)d_in[9];
  const float* conv1_b = (const float*)d_in[10];
  const float* lin2_w  = (const float*)d_in[11];
  const float* lin2_b  = (const float*)d_in[12];
  const float* conv2_w = (const float*)d_in[13];
  const float* conv2_b = (const float*)d_in[14];
  const float* w2a     = (const float*)d_in[15];
  const float* b2a     = (const float*)d_in[16];
  const float* w2b     = (const float*)d_in[17];
  const float* b2b     = (const float*)d_in[18];

  char* ws = (char*)d_ws;
  int*   knn_idx = (int*)ws;                              // 0 .. 1M
  float* f1  = (float*)(ws + (1u << 20));                 // 1M .. 5M
  float* pm  = (float*)(ws + (5u << 20));                 // 5M .. 6M
  unsigned short* w2hi = (unsigned short*)(ws + (6u << 20));               // 256K
  unsigned short* w2lo = (unsigned short*)(ws + (6u << 20) + (1u << 18));  // 256K
  unsigned short* w1hi = (unsigned short*)(ws + (6u << 20) + (2u << 18));  // 16K
  unsigned short* w1lo = (unsigned short*)(ws + (6u << 20) + (2u << 18) + (1u << 14));
  float* b1p = (float*)(ws + (6u << 20) + (2u << 18) + (2u << 14));        // 512B
  float* b2p = (float*)(ws + (6u << 20) + (2u << 18) + (3u << 14));        // 4K
  float* f2  = (float*)(ws + (9u << 20));                 // 9M .. 17M

  wcomp1_kernel<<<128, 64, 0, stream>>>(lin1_w, lin1_b, conv1_w, conv1_b, w1hi, w1lo, b1p);
  wcomp2_kernel<<<1024, 128, 0, stream>>>(lin2_w, lin2_b, conv2_w, conv2_b, w2hi, w2lo, b2p);
  knn_kernel   <<<512, 256, 0, stream>>>(pts, knn_idx);
  mlp1_kernel  <<<256, 512, 0, stream>>>(pts, knn_idx, w1a, b1a, w1b, b1b, w1c, b1c, f1);
  gconv1_kernel<<<256, 256, 0, stream>>>(f1, knn_idx, w1hi, w1lo, b1p, f2);
  gconv2max_kernel<<<256, 256, 0, stream>>>(f2, knn_idx, w2hi, w2lo, pm);
  head_kernel  <<<8, 256, 0, stream>>>(pm, b2p, w2a, b2a, w2b, b2b, (float*)d_out);
}

// Round 9
// 196.107 us; speedup vs baseline: 6.4299x; 1.4145x over previous
//
#include <hip/hip_runtime.h>

#define BB 8
#define NN 2048
#define KK 16
#define QT 32      // kNN queries per block
#define NSLICE 8
#define SLEN 256   // NN / NSLICE
#define KP 18      // packed keep-depth per slice (pool safety margin)

typedef short bf16x8 __attribute__((ext_vector_type(8)));
typedef float f32x4 __attribute__((ext_vector_type(4)));
typedef unsigned short ushort8v __attribute__((ext_vector_type(8)));

__device__ __forceinline__ float4 f4max(float4 a, float4 b) {
  return make_float4(fmaxf(a.x, b.x), fmaxf(a.y, b.y), fmaxf(a.z, b.z), fmaxf(a.w, b.w));
}

__device__ __forceinline__ unsigned short f2bf(float x) {  // f32 -> bf16 bits, RNE
  union { float f; unsigned u; } v; v.f = x;
  unsigned r = v.u + 0x7fffu + ((v.u >> 16) & 1u);
  return (unsigned short)(r >> 16);
}
__device__ __forceinline__ float bf2f(unsigned short h) {
  union { unsigned u; float f; } v; v.u = ((unsigned)h) << 16;
  return v.f;
}

// ---------------------------------------------------------------- kNN top-16
__global__ __launch_bounds__(256) void knn_kernel(const float* __restrict__ pts,
                                                  int* __restrict__ knn_idx) {
  __shared__ float4 sp[NN];                         // 32 KB (x,y,z,|p|^2)
  __shared__ unsigned pk[NSLICE][QT][KP];           // 18 KB packed lists
  __shared__ float          s1v[4][QT][16];         // 8 KB stage-1 vals
  __shared__ unsigned short s1i[4][QT][16];         // 4 KB stage-1 ids
  const int b = blockIdx.x & 7;
  const int tile = blockIdx.x >> 3;
  const int tid = threadIdx.x;
  const int q = tid & 31;
  const int s = tid >> 5;

  for (int i = tid; i < NN; i += 256) {
    float x = pts[(size_t)(b * NN + i) * 3 + 0];
    float y = pts[(size_t)(b * NN + i) * 3 + 1];
    float z = pts[(size_t)(b * NN + i) * 3 + 2];
    sp[i] = make_float4(x, y, z, x * x + y * y + z * z);
  }
  __syncthreads();

  {
    const float4 pq = sp[tile * QT + q];
    unsigned qk[KP];
#pragma unroll
    for (int j = 0; j < KP; ++j) qk[j] = 0u;
    const int m0 = s * SLEN;
    for (int mb = 0; mb < SLEN; mb += 8) {
      float4 c[8];
#pragma unroll
      for (int u = 0; u < 8; ++u) c[u] = sp[m0 + mb + u];
#pragma unroll
      for (int u = 0; u < 8; ++u) {
        const float v = 2.0f * (pq.x * c[u].x + pq.y * c[u].y + pq.z * c[u].z)
                        - pq.w - c[u].w;
        unsigned uu = __float_as_uint(v);
        unsigned key = uu ^ ((unsigned)(((int)uu) >> 31) | 0x80000000u);
        unsigned run = (key & 0xFFFFFF00u) | (unsigned)(255 - (mb + u));
#pragma unroll
        for (int j = 0; j < KP; ++j) {          // branchless sorted insert
          const unsigned hi = max(qk[j], run);
          const unsigned lo = min(qk[j], run);
          qk[j] = hi; run = lo;
        }
      }
    }
#pragma unroll
    for (int j = 0; j < KP; ++j) pk[s][q][j] = qk[j];
  }
  __syncthreads();

  if (tid < 128) {
    const int q2 = tid & 31, pr = tid >> 5;
    const float4 pm = sp[tile * QT + q2];
    float mv[16]; int mi[16];
#pragma unroll
    for (int j = 0; j < 16; ++j) { mv[j] = -3.0e38f; mi[j] = 0; }
#pragma unroll 1
    for (int ss = 2 * pr; ss <= 2 * pr + 1; ++ss) {
      const int base = ss * SLEN;
#pragma unroll 1
      for (int j = 0; j < KP; ++j) {
        const unsigned pkd = pk[ss][q2][j];
        const int id = base + 255 - (int)(pkd & 0xFFu);
        const float4 c = sp[id];
        const float v = 2.0f * (pm.x * c.x + pm.y * c.y + pm.z * c.z) - pm.w - c.w;
        if (v > mv[15]) {
          mv[15] = v; mi[15] = id;
#pragma unroll
          for (int t = 15; t > 0; --t) {
            if (mv[t] > mv[t - 1]) {
              float tv = mv[t]; mv[t] = mv[t - 1]; mv[t - 1] = tv;
              int ti = mi[t]; mi[t] = mi[t - 1]; mi[t - 1] = ti;
            }
          }
        }
      }
    }
#pragma unroll
    for (int j = 0; j < 16; ++j) {
      s1v[pr][q2][j] = mv[j];
      s1i[pr][q2][j] = (unsigned short)mi[j];
    }
  }
  __syncthreads();

  if (tid < QT) {
    float mv[16]; int mi[16];
#pragma unroll
    for (int j = 0; j < 16; ++j) { mv[j] = -3.0e38f; mi[j] = 0; }
#pragma unroll 1
    for (int pr = 0; pr < 4; ++pr) {
#pragma unroll 1
      for (int j = 0; j < 16; ++j) {
        const float v = s1v[pr][tid][j];
        if (v <= mv[15]) break;
        const int id = s1i[pr][tid][j];
        mv[15] = v; mi[15] = id;
#pragma unroll
        for (int t = 15; t > 0; --t) {
          if (mv[t] > mv[t - 1]) {
            float tv = mv[t]; mv[t] = mv[t - 1]; mv[t - 1] = tv;
            int ti = mi[t]; mi[t] = mi[t - 1]; mi[t - 1] = ti;
          }
        }
      }
    }
    const int nq = tile * QT + tid;
#pragma unroll
    for (int j = 0; j < 16; ++j) knn_idx[(size_t)(b * NN + nq) * KK + j] = mi[j];
  }
}

// -------------- composite weights: W1' = conv1_w(128x64) @ lin1_w(64x64)
__global__ __launch_bounds__(64) void wcomp1_kernel(
    const float* __restrict__ lin1_w, const float* __restrict__ lin1_b,
    const float* __restrict__ conv1_w, const float* __restrict__ conv1_b,
    unsigned short* __restrict__ w1hi, unsigned short* __restrict__ w1lo,
    float* __restrict__ b1p) {
  const int o = blockIdx.x;      // 128
  const int c = threadIdx.x;     // 64
  float acc = 0.f;
#pragma unroll 8
  for (int k = 0; k < 64; ++k) acc += conv1_w[o * 64 + k] * lin1_w[k * 64 + c];
  const unsigned short h = f2bf(acc);
  w1hi[o * 64 + c] = h;
  w1lo[o * 64 + c] = f2bf(acc - bf2f(h));
  if (c == 0) {
    float bb = conv1_b[o];
    for (int k = 0; k < 64; ++k) bb += conv1_w[o * 64 + k] * lin1_b[k];
    b1p[o] = bb;
  }
}

// -------------- composite weights: W2' = conv2_w(1024x128) @ lin2_w(128x128)
__global__ __launch_bounds__(128) void wcomp2_kernel(
    const float* __restrict__ lin2_w, const float* __restrict__ lin2_b,
    const float* __restrict__ conv2_w, const float* __restrict__ conv2_b,
    unsigned short* __restrict__ w2hi, unsigned short* __restrict__ w2lo,
    float* __restrict__ b2p) {
  const int o = blockIdx.x;      // 1024
  const int c = threadIdx.x;     // 128
  float acc = 0.f;
#pragma unroll 8
  for (int k = 0; k < 128; ++k) acc += conv2_w[o * 128 + k] * lin2_w[k * 128 + c];
  const unsigned short h = f2bf(acc);
  w2hi[o * 128 + c] = h;
  w2lo[o * 128 + c] = f2bf(acc - bf2f(h));
  if (c == 0) {
    float bb = conv2_b[o];
    for (int k = 0; k < 128; ++k) bb += conv2_w[o * 128 + k] * lin2_b[k];
    b2p[o] = bb;
  }
}

// ------------------------------------------- features (pts + cov) + mlp1 x3
__global__ __launch_bounds__(512, 2) void mlp1_kernel(
    const float* __restrict__ pts, const int* __restrict__ knn_idx,
    const float* __restrict__ w1a, const float* __restrict__ b1a,
    const float* __restrict__ w1b, const float* __restrict__ b1b,
    const float* __restrict__ w1c, const float* __restrict__ b1c,
    float* __restrict__ f1) {
  __shared__ float h1[64][64];
  __shared__ float h2[64][64];
  const int tid = threadIdx.x;
  const int p = tid & 63;
  const int ch = tid >> 6;
  const int b = blockIdx.x & 7;
  const int nc = blockIdx.x >> 3;
  const int bn = b * NN + nc * 64 + p;

  const int n0 = knn_idx[(size_t)bn * KK + 0];
  const int n1 = knn_idx[(size_t)bn * KK + 1];
  const float* pp = &pts[(size_t)bn * 3];
  const float* p0 = &pts[((size_t)(b << 11) + n0) * 3];
  const float* p1 = &pts[((size_t)(b << 11) + n1) * 3];
  float in[12];
  in[0] = pp[0]; in[1] = pp[1]; in[2] = pp[2];
  {
    float a0 = p0[0], a1 = p0[1], a2 = p0[2];
    float c0 = p1[0], c1 = p1[1], c2 = p1[2];
    in[3] = a0 * c0; in[4]  = a0 * c1; in[5]  = a0 * c2;
    in[6] = a1 * c0; in[7]  = a1 * c1; in[8]  = a1 * c2;
    in[9] = a2 * c0; in[10] = a2 * c1; in[11] = a2 * c2;
  }

#pragma unroll
  for (int oi = 0; oi < 8; ++oi) {
    const int o = ch * 8 + oi;
    float a = b1a[o];
#pragma unroll
    for (int c = 0; c < 12; ++c) a += w1a[o * 12 + c] * in[c];
    h1[o][p] = fmaxf(a, 0.f);
  }
  __syncthreads();

  {
    float acc[8];
#pragma unroll
    for (int oi = 0; oi < 8; ++oi) acc[oi] = b1b[ch * 8 + oi];
#pragma unroll 1
    for (int cc = 0; cc < 64; cc += 32) {
      float xr[32];
#pragma unroll
      for (int c = 0; c < 32; ++c) xr[c] = h1[cc + c][p];
#pragma unroll
      for (int oi = 0; oi < 8; ++oi) {
        const int o = ch * 8 + oi;
#pragma unroll
        for (int c = 0; c < 32; ++c) acc[oi] += w1b[o * 64 + cc + c] * xr[c];
      }
    }
    __syncthreads();
#pragma unroll
    for (int oi = 0; oi < 8; ++oi) h2[ch * 8 + oi][p] = fmaxf(acc[oi], 0.f);
  }
  __syncthreads();

  {
    float acc[8];
#pragma unroll
    for (int oi = 0; oi < 8; ++oi) acc[oi] = b1c[ch * 8 + oi];
#pragma unroll 1
    for (int cc = 0; cc < 64; cc += 32) {
      float xr[32];
#pragma unroll
      for (int c = 0; c < 32; ++c) xr[c] = h2[cc + c][p];
#pragma unroll
      for (int oi = 0; oi < 8; ++oi) {
        const int o = ch * 8 + oi;
#pragma unroll
        for (int c = 0; c < 32; ++c) acc[oi] += w1c[o * 64 + cc + c] * xr[c];
      }
    }
#pragma unroll
    for (int oi = 0; oi < 8; ++oi)
      f1[(size_t)bn * 64 + ch * 8 + oi] = fmaxf(acc[oi], 0.f);
  }
}

// ------------- maxpool(f1) + composite lin1+conv1 (W1', MFMA) + relu -> f2
__global__ __launch_bounds__(256, 2) void gconv1_kernel(
    const float* __restrict__ f1, const int* __restrict__ knn_idx,
    const unsigned short* __restrict__ w1hi, const unsigned short* __restrict__ w1lo,
    const float* __restrict__ b1p, float* __restrict__ f2) {
  __shared__ __align__(16) unsigned short xls[2][64][64];   // 16 KB hi|lo
  const int b = blockIdx.x & 7, nc = blockIdx.x >> 3;
  const int tid = threadIdx.x;
  const int lane = tid & 63, wv = tid >> 6;

  {
    const int p = tid & 63, ch = tid >> 6;   // ch in 0..3: channels [ch*16,+16)
    const int bn = b * NN + nc * 64 + p;
    const int4* idr = (const int4*)&knn_idx[(size_t)bn * KK];
    int4 nb4[4];
#pragma unroll
    for (int q = 0; q < 4; ++q) nb4[q] = idr[q];
    float4 mx[4];
#pragma unroll
    for (int q = 0; q < 4; ++q) mx[q] = make_float4(-3e38f, -3e38f, -3e38f, -3e38f);
#pragma unroll
    for (int j = 0; j < KK; ++j) {
      const int nb = (j & 3) == 0 ? nb4[j >> 2].x : (j & 3) == 1 ? nb4[j >> 2].y
                   : (j & 3) == 2 ? nb4[j >> 2].z : nb4[j >> 2].w;
      const float4* v = (const float4*)&f1[((size_t)(b << 11) + nb) * 64 + ch * 16];
#pragma unroll
      for (int q = 0; q < 4; ++q) mx[q] = f4max(mx[q], v[q]);
    }
    char* basep = (char*)&xls[0][0][0];
#pragma unroll
    for (int s = 0; s < 2; ++s) {
      float xv[8] = {mx[2 * s].x, mx[2 * s].y, mx[2 * s].z, mx[2 * s].w,
                     mx[2 * s + 1].x, mx[2 * s + 1].y, mx[2 * s + 1].z, mx[2 * s + 1].w};
      ushort8v hw, lw;
#pragma unroll
      for (int j = 0; j < 8; ++j) {
        unsigned short h = f2bf(xv[j]);
        hw[j] = h;
        lw[j] = f2bf(xv[j] - bf2f(h));
      }
      const int slot = ch * 2 + s;
      const int swz = slot ^ (p & 7);
      char* dst = basep + p * 128 + swz * 16;
      *(ushort8v*)dst = hw;
      *(ushort8v*)(dst + 8192) = lw;
    }
  }
  __syncthreads();

  const int g = lane >> 4, r = lane & 15;
  const char* basep = (const char*)&xls[0][0][0];
  bf16x8 ah[4][2], al[4][2];
#pragma unroll
  for (int m = 0; m < 4; ++m) {
    const int row = m * 16 + r;
#pragma unroll
    for (int kt = 0; kt < 2; ++kt) {
      const int swz = (kt * 4 + g) ^ (row & 7);
      const char* p = basep + row * 128 + swz * 16;
      ah[m][kt] = *(const bf16x8*)p;
      al[m][kt] = *(const bf16x8*)(p + 8192);
    }
  }
  f32x4 acc[4][2];
#pragma unroll
  for (int m = 0; m < 4; ++m)
#pragma unroll
    for (int nt = 0; nt < 2; ++nt) acc[m][nt] = (f32x4){0.f, 0.f, 0.f, 0.f};

#pragma unroll
  for (int nt = 0; nt < 2; ++nt) {
    const int o = (wv * 2 + nt) * 16 + r;
    const char* wb = (const char*)w1hi + (size_t)o * 128 + g * 16;
    const char* lb = (const char*)w1lo + (size_t)o * 128 + g * 16;
    bf16x8 bh[2], bl[2];
#pragma unroll
    for (int kt = 0; kt < 2; ++kt) {
      bh[kt] = *(const bf16x8*)(wb + kt * 64);
      bl[kt] = *(const bf16x8*)(lb + kt * 64);
    }
#pragma unroll
    for (int kt = 0; kt < 2; ++kt) {
#pragma unroll
      for (int m = 0; m < 4; ++m) {
        acc[m][nt] = __builtin_amdgcn_mfma_f32_16x16x32_bf16(ah[m][kt], bh[kt], acc[m][nt], 0, 0, 0);
        acc[m][nt] = __builtin_amdgcn_mfma_f32_16x16x32_bf16(ah[m][kt], bl[kt], acc[m][nt], 0, 0, 0);
        acc[m][nt] = __builtin_amdgcn_mfma_f32_16x16x32_bf16(al[m][kt], bh[kt], acc[m][nt], 0, 0, 0);
      }
    }
  }
#pragma unroll
  for (int nt = 0; nt < 2; ++nt) {
    const int o = (wv * 2 + nt) * 16 + r;
    const float bias = b1p[o];
#pragma unroll
    for (int m = 0; m < 4; ++m) {
#pragma unroll
      for (int j = 0; j < 4; ++j) {
        const int row = m * 16 + g * 4 + j;
        f2[((size_t)(b * NN + nc * 64 + row)) * 128 + o] = fmaxf(acc[m][nt][j] + bias, 0.f);
      }
    }
  }
}

// ---- maxpool(f2) + composite lin2+conv2 (W2', MFMA) + fused global max(n)
__global__ __launch_bounds__(256, 2) void gconv2max_kernel(
    const float* __restrict__ f2, const int* __restrict__ knn_idx,
    const unsigned short* __restrict__ w2hi, const unsigned short* __restrict__ w2lo,
    float* __restrict__ pmax) {
  __shared__ __align__(16) unsigned short xls[2][64][128];   // 32 KB hi|lo
  const int b = blockIdx.x & 7, nc = blockIdx.x >> 3;
  const int tid = threadIdx.x;
  const int lane = tid & 63, wv = tid >> 6;

  {
    const int p = tid & 63, ch = tid >> 6;   // ch in 0..3: channels [ch*32,+32)
    const int bn = b * NN + nc * 64 + p;
    const int4* idr = (const int4*)&knn_idx[(size_t)bn * KK];
    int4 nb4[4];
#pragma unroll
    for (int q = 0; q < 4; ++q) nb4[q] = idr[q];
    float4 mx[8];
#pragma unroll
    for (int q = 0; q < 8; ++q) mx[q] = make_float4(-3e38f, -3e38f, -3e38f, -3e38f);
#pragma unroll
    for (int j = 0; j < KK; ++j) {
      const int nb = (j & 3) == 0 ? nb4[j >> 2].x : (j & 3) == 1 ? nb4[j >> 2].y
                   : (j & 3) == 2 ? nb4[j >> 2].z : nb4[j >> 2].w;
      const float4* v = (const float4*)&f2[((size_t)(b << 11) + nb) * 128 + ch * 32];
#pragma unroll
      for (int q = 0; q < 8; ++q) mx[q] = f4max(mx[q], v[q]);
    }
    char* basep = (char*)&xls[0][0][0];
#pragma unroll
    for (int s = 0; s < 4; ++s) {
      float xv[8] = {mx[2 * s].x, mx[2 * s].y, mx[2 * s].z, mx[2 * s].w,
                     mx[2 * s + 1].x, mx[2 * s + 1].y, mx[2 * s + 1].z, mx[2 * s + 1].w};
      ushort8v hw, lw;
#pragma unroll
      for (int j = 0; j < 8; ++j) {
        unsigned short h = f2bf(xv[j]);
        hw[j] = h;
        lw[j] = f2bf(xv[j] - bf2f(h));
      }
      const int slot = ch * 4 + s;
      const int swz = slot ^ (p & 15);
      char* dst = basep + p * 256 + swz * 16;
      *(ushort8v*)dst = hw;
      *(ushort8v*)(dst + 16384) = lw;
    }
  }
  __syncthreads();

  const int g = lane >> 4, r = lane & 15;
  const char* basep = (const char*)&xls[0][0][0];
  float omax[16];
#pragma unroll
  for (int ot = 0; ot < 16; ++ot) omax[ot] = -3e38f;

#pragma unroll
  for (int mg = 0; mg < 2; ++mg) {
    bf16x8 ah[2][4], al[2][4];
#pragma unroll
    for (int m = 0; m < 2; ++m) {
      const int row = (mg * 2 + m) * 16 + r;
#pragma unroll
      for (int kt = 0; kt < 4; ++kt) {
        const int swz = (kt * 4 + g) ^ (row & 15);
        const char* p = basep + row * 256 + swz * 16;
        ah[m][kt] = *(const bf16x8*)p;
        al[m][kt] = *(const bf16x8*)(p + 16384);
      }
    }
#pragma unroll 1
    for (int ot = 0; ot < 16; ++ot) {
      const int o = wv * 256 + ot * 16 + r;
      const char* wb = (const char*)w2hi + (size_t)o * 256 + g * 16;
      const char* lb = (const char*)w2lo + (size_t)o * 256 + g * 16;
      bf16x8 bh[4], bl[4];
#pragma unroll
      for (int kt = 0; kt < 4; ++kt) {
        bh[kt] = *(const bf16x8*)(wb + kt * 64);
        bl[kt] = *(const bf16x8*)(lb + kt * 64);
      }
      f32x4 acc0 = {0.f, 0.f, 0.f, 0.f}, acc1 = {0.f, 0.f, 0.f, 0.f};
#pragma unroll
      for (int kt = 0; kt < 4; ++kt) {
        acc0 = __builtin_amdgcn_mfma_f32_16x16x32_bf16(ah[0][kt], bh[kt], acc0, 0, 0, 0);
        acc1 = __builtin_amdgcn_mfma_f32_16x16x32_bf16(ah[1][kt], bh[kt], acc1, 0, 0, 0);
        acc0 = __builtin_amdgcn_mfma_f32_16x16x32_bf16(ah[0][kt], bl[kt], acc0, 0, 0, 0);
        acc1 = __builtin_amdgcn_mfma_f32_16x16x32_bf16(ah[1][kt], bl[kt], acc1, 0, 0, 0);
        acc0 = __builtin_amdgcn_mfma_f32_16x16x32_bf16(al[0][kt], bh[kt], acc0, 0, 0, 0);
        acc1 = __builtin_amdgcn_mfma_f32_16x16x32_bf16(al[1][kt], bh[kt], acc1, 0, 0, 0);
      }
      float mx = fmaxf(fmaxf(fmaxf(acc0[0], acc0[1]), fmaxf(acc0[2], acc0[3])),
                       fmaxf(fmaxf(acc1[0], acc1[1]), fmaxf(acc1[2], acc1[3])));
      omax[ot] = fmaxf(omax[ot], mx);
    }
  }
#pragma unroll
  for (int ot = 0; ot < 16; ++ot) {
    float v = omax[ot];
    v = fmaxf(v, __shfl_xor(v, 16, 64));
    v = fmaxf(v, __shfl_xor(v, 32, 64));
    omax[ot] = v;
  }
  if (lane < 16) {
#pragma unroll
    for (int ot = 0; ot < 16; ++ot) {
      const int o = wv * 256 + ot * 16 + lane;
      pmax[((size_t)b * 1024 + o) * 32 + nc] = omax[ot];
    }
  }
}

// ------------------- head stage 0: reduce pmax chunks + b2' -> g[8][1024]
__global__ __launch_bounds__(256) void head_g_kernel(
    const float* __restrict__ pmax, const float* __restrict__ b2p,
    float* __restrict__ gbuf) {
  const int b = blockIdx.x & 7;
  const int o = (blockIdx.x >> 3) * 256 + threadIdx.x;
  const float4* p = (const float4*)&pmax[((size_t)b * 1024 + o) * 32];
  float4 a4 = p[0];
#pragma unroll
  for (int gi = 1; gi < 8; ++gi) a4 = f4max(a4, p[gi]);
  gbuf[b * 1024 + o] = fmaxf(fmaxf(a4.x, a4.y), fmaxf(a4.z, a4.w)) + b2p[o];
}

// ------------------- head stage 1: h = relu(w2a @ g + b2a), wave-per-output
__global__ __launch_bounds__(256) void head_a_kernel(
    const float* __restrict__ gbuf, const float* __restrict__ w2a,
    const float* __restrict__ b2a, float* __restrict__ hbuf) {
  const int b = blockIdx.x & 7;
  const int k = (blockIdx.x >> 3) * 4 + (threadIdx.x >> 6);   // wave-per-output
  const int lane = threadIdx.x & 63;
  const float4* wr = (const float4*)&w2a[(size_t)k * 1024];
  const float4* gv = (const float4*)&gbuf[b * 1024];
  float a = 0.f;
#pragma unroll
  for (int i = 0; i < 4; ++i) {               // coalesced: f4 idx lane + i*64
    float4 w = wr[lane + i * 64], xx = gv[lane + i * 64];
    a += w.x * xx.x + w.y * xx.y + w.z * xx.z + w.w * xx.w;
  }
#pragma unroll
  for (int s = 32; s >= 1; s >>= 1) a += __shfl_xor(a, s, 64);
  if (lane == 0) hbuf[b * 512 + k] = fmaxf(a + b2a[k], 0.f);
}

// ------------------- head stage 2: out = w2b @ h + b2b, wave-per-output
__global__ __launch_bounds__(256) void head_b_kernel(
    const float* __restrict__ hbuf, const float* __restrict__ w2b,
    const float* __restrict__ b2b, float* __restrict__ out) {
  const int b = blockIdx.x & 7;
  const int k = (blockIdx.x >> 3) * 4 + (threadIdx.x >> 6);
  const int lane = threadIdx.x & 63;
  const float4* wr = (const float4*)&w2b[(size_t)k * 512];
  const float4* hv = (const float4*)&hbuf[b * 512];
  float a = 0.f;
#pragma unroll
  for (int i = 0; i < 2; ++i) {
    float4 w = wr[lane + i * 64], xx = hv[lane + i * 64];
    a += w.x * xx.x + w.y * xx.y + w.z * xx.z + w.w * xx.w;
  }
#pragma unroll
  for (int s = 32; s >= 1; s >>= 1) a += __shfl_xor(a, s, 64);
  if (lane == 0) out[b * 512 + k] = a + b2b[k];
}

extern "C" void kernel_launch(void* const* d_in, const int* in_sizes, int n_in,
                              void* d_out, int out_size, void* d_ws, size_t ws_size,
                              hipStream_t stream) {
  const float* pts     = (const float*)d_in[0];
  const float* w1a     = (const float*)d_in[1];
  const float* b1a     = (const float*)d_in[2];
  const float* w1b     = (const float*)d_in[3];
  const float* b1b     = (const float*)d_in[4];
  const float* w1c     = (const float*)d_in[5];
  const float* b1c     = (const float*)d_in[6];
  const float* lin1_w  = (const float*)d_in[7];
  const float* lin1_b  = (const float*)d_in[8];
  const float* conv1_w = (const float*)d_in[9];
  const float* conv1_b = (const float*)d_in[10];
  const float* lin2_w  = (const float*)d_in[11];
  const float* lin2_b  = (const float*)d_in[12];
  const float* conv2_w = (const float*)d_in[13];
  const float* conv2_b = (const float*)d_in[14];
  const float* w2a     = (const float*)d_in[15];
  const float* b2a     = (const float*)d_in[16];
  const float* w2b     = (const float*)d_in[17];
  const float* b2b     = (const float*)d_in[18];

  char* ws = (char*)d_ws;
  int*   knn_idx = (int*)ws;                              // 0 .. 1M
  float* f1  = (float*)(ws + (1u << 20));                 // 1M .. 5M
  float* pm  = (float*)(ws + (5u << 20));                 // 5M .. 6M
  unsigned short* w2hi = (unsigned short*)(ws + (6u << 20));               // 256K
  unsigned short* w2lo = (unsigned short*)(ws + (6u << 20) + (1u << 18));  // 256K
  unsigned short* w1hi = (unsigned short*)(ws + (6u << 20) + (2u << 18));  // 16K
  unsigned short* w1lo = (unsigned short*)(ws + (6u << 20) + (2u << 18) + (1u << 14));
  float* b1p = (float*)(ws + (6u << 20) + (2u << 18) + (2u << 14));        // 512B
  float* b2p = (float*)(ws + (6u << 20) + (2u << 18) + (3u << 14));        // 4K
  float* gbuf = (float*)(ws + (7u << 20));                // 32K
  float* hbuf = (float*)(ws + (7u << 20) + (1u << 16));   // 16K
  float* f2  = (float*)(ws + (9u << 20));                 // 9M .. 17M

  wcomp1_kernel<<<128, 64, 0, stream>>>(lin1_w, lin1_b, conv1_w, conv1_b, w1hi, w1lo, b1p);
  wcomp2_kernel<<<1024, 128, 0, stream>>>(lin2_w, lin2_b, conv2_w, conv2_b, w2hi, w2lo, b2p);
  knn_kernel   <<<512, 256, 0, stream>>>(pts, knn_idx);
  mlp1_kernel  <<<256, 512, 0, stream>>>(pts, knn_idx, w1a, b1a, w1b, b1b, w1c, b1c, f1);
  gconv1_kernel<<<256, 256, 0, stream>>>(f1, knn_idx, w1hi, w1lo, b1p, f2);
  gconv2max_kernel<<<256, 256, 0, stream>>>(f2, knn_idx, w2hi, w2lo, pm);
  head_g_kernel<<<32, 256, 0, stream>>>(pm, b2p, gbuf);
  head_a_kernel<<<1024, 256, 0, stream>>>(gbuf, w2a, b2a, hbuf);
  head_b_kernel<<<1024, 256, 0, stream>>>(hbuf, w2b, b2b, (float*)d_out);
}